// Round 2
// baseline (439.817 us; speedup 1.0000x reference)
//
#include <hip/hip_runtime.h>

typedef unsigned short u16;
typedef __attribute__((ext_vector_type(8))) short bf16x8;
typedef __attribute__((ext_vector_type(4))) float f32x4;

#define MFMA(a,b,c) __builtin_amdgcn_mfma_f32_16x16x32_bf16(a,b,c,0,0,0)

__device__ __forceinline__ float b2f(u16 u){
  union { unsigned int i; float f; } v; v.i = ((unsigned int)u)<<16; return v.f;
}
__device__ __forceinline__ u16 f2b(float f){
  union { float f; unsigned int i; } v; v.f = f;
  unsigned int r = (v.i + 0x7FFFu + ((v.i>>16)&1u))>>16;
  return (u16)r;
}

// ---------------- prep: time-shift first half of channels, f32 -> bf16 ----------------
__global__ __launch_bounds__(256) void k_prep(const float* __restrict__ x, u16* __restrict__ xs)
{
  int idx = blockIdx.x*256 + threadIdx.x;     // one thread per 8 elements
  size_t e = (size_t)idx*8;
  int c = (int)(e & 1023);
  int t = (int)((e>>10)&1023);
  float4 f0 = {0.f,0.f,0.f,0.f}, f1 = {0.f,0.f,0.f,0.f};
  const float* src = nullptr;
  if (c < 512){ if (t > 0) src = x + e - 1024; }
  else        { src = x + e; }
  if (src){ f0 = *(const float4*)src; f1 = *(const float4*)(src+4); }
  u16 o[8];
  o[0]=f2b(f0.x); o[1]=f2b(f0.y); o[2]=f2b(f0.z); o[3]=f2b(f0.w);
  o[4]=f2b(f1.x); o[5]=f2b(f1.y); o[6]=f2b(f1.z); o[7]=f2b(f1.w);
  *(uint4*)(xs + e) = *(const uint4*)o;
}

// ---------------- 1024x1024 transpose, f32 in -> bf16 out ----------------
__global__ __launch_bounds__(256) void k_tr(const float* __restrict__ src, u16* __restrict__ dst)
{
  int c0 = blockIdx.x*64, r0 = blockIdx.y*64;
  __shared__ u16 tile[64][72];
  int tid = threadIdx.x;
  int r = tid>>2, cc = (tid&3)*16;
  const float* sp = src + (size_t)(r0+r)*1024 + c0+cc;
  float4 a0 = *(const float4*)(sp);
  float4 a1 = *(const float4*)(sp+4);
  float4 a2 = *(const float4*)(sp+8);
  float4 a3 = *(const float4*)(sp+12);
  tile[r][cc+0]=f2b(a0.x); tile[r][cc+1]=f2b(a0.y); tile[r][cc+2]=f2b(a0.z); tile[r][cc+3]=f2b(a0.w);
  tile[r][cc+4]=f2b(a1.x); tile[r][cc+5]=f2b(a1.y); tile[r][cc+6]=f2b(a1.z); tile[r][cc+7]=f2b(a1.w);
  tile[r][cc+8]=f2b(a2.x); tile[r][cc+9]=f2b(a2.y); tile[r][cc+10]=f2b(a2.z); tile[r][cc+11]=f2b(a2.w);
  tile[r][cc+12]=f2b(a3.x); tile[r][cc+13]=f2b(a3.y); tile[r][cc+14]=f2b(a3.z); tile[r][cc+15]=f2b(a3.w);
  __syncthreads();
  int c = tid>>2, rr = (tid&3)*16;
  uint4 o0,o1; u16* p0=(u16*)&o0; u16* p1=(u16*)&o1;
  #pragma unroll
  for (int i=0;i<8;i++){ p0[i]=tile[rr+i][c]; p1[i]=tile[rr+8+i][c]; }
  *(uint4*)(dst + (size_t)(c0+c)*1024 + r0+rr)   = o0;
  *(uint4*)(dst + (size_t)(c0+c)*1024 + r0+rr+8) = o1;
}

// ---------------- v transpose: (bh,t,d) -> (bh,d,t), bf16 ----------------
__global__ __launch_bounds__(256) void k_vt(const u16* __restrict__ v, u16* __restrict__ vT)
{
  int bh = blockIdx.x, t0 = blockIdx.y*64;
  __shared__ u16 tile[64][72];
  const u16* src = v + (size_t)bh*65536;
  int tid = threadIdx.x;
  int r = tid>>2, c0 = (tid&3)*16;
  *(uint4*)&tile[r][c0]   = *(const uint4*)(src + (size_t)(t0+r)*64 + c0);
  *(uint4*)&tile[r][c0+8] = *(const uint4*)(src + (size_t)(t0+r)*64 + c0+8);
  __syncthreads();
  int d = tid>>2, tc0 = (tid&3)*16;
  uint4 o0,o1; u16* p0=(u16*)&o0; u16* p1=(u16*)&o1;
  #pragma unroll
  for (int i=0;i<8;i++){ p0[i]=tile[tc0+i][d]; p1[i]=tile[tc0+8+i][d]; }
  u16* dst = vT + (size_t)bh*65536 + (size_t)d*1024 + t0 + tc0;
  *(uint4*)(dst)   = o0;
  *(uint4*)(dst+8) = o1;
}

// ---------------- QKV GEMM: xs[2048x1024] @ WT^T -> q(hi/lo),k(hi/lo),v ----------------
__global__ __launch_bounds__(256) void k_gemm_qkv(
    const u16* __restrict__ A, const u16* __restrict__ Bt,
    const float* __restrict__ bq, const float* __restrict__ bk, const float* __restrict__ bv,
    u16* __restrict__ qhi, u16* __restrict__ qlo,
    u16* __restrict__ khi, u16* __restrict__ klo, u16* __restrict__ v)
{
  __shared__ u16 As[128*40];
  __shared__ u16 Bs[128*40];
  const int n0 = blockIdx.x*128, m0 = blockIdx.y*128;
  const int tid = threadIdx.x, lane = tid&63, wave = tid>>6;
  const int quad = lane>>4, l16 = lane&15;
  const int wm = (wave>>1)*64, wn = (wave&1)*64;
  f32x4 zero = {0.f,0.f,0.f,0.f};
  f32x4 acc[4][4];
  #pragma unroll
  for (int i=0;i<4;i++)
    #pragma unroll
    for (int j=0;j<4;j++) acc[i][j] = zero;
  const int row = tid>>1, kk = (tid&1)*16;
  const u16* pa = A  + (size_t)(m0+row)*1024 + kk;
  const u16* pb = Bt + (size_t)(n0+row)*1024 + kk;
  for (int k0=0;k0<1024;k0+=32){
    __syncthreads();
    uint4 a0 = *(const uint4*)(pa); uint4 a1 = *(const uint4*)(pa+8);
    uint4 b0 = *(const uint4*)(pb); uint4 b1 = *(const uint4*)(pb+8);
    pa += 32; pb += 32;
    *(uint4*)&As[row*40+kk] = a0; *(uint4*)&As[row*40+kk+8] = a1;
    *(uint4*)&Bs[row*40+kk] = b0; *(uint4*)&Bs[row*40+kk+8] = b1;
    __syncthreads();
    bf16x8 af[4], bfr[4];
    #pragma unroll
    for (int mt=0;mt<4;mt++) af[mt]  = *(const bf16x8*)&As[(wm+mt*16+l16)*40 + quad*8];
    #pragma unroll
    for (int nt=0;nt<4;nt++) bfr[nt] = *(const bf16x8*)&Bs[(wn+nt*16+l16)*40 + quad*8];
    #pragma unroll
    for (int mt=0;mt<4;mt++)
      #pragma unroll
      for (int nt=0;nt<4;nt++)
        acc[mt][nt] = MFMA(af[mt], bfr[nt], acc[mt][nt]);
  }
  #pragma unroll
  for (int mt=0;mt<4;mt++)
    #pragma unroll
    for (int nt=0;nt<4;nt++){
      int colg = n0 + wn + nt*16 + l16;
      int which = colg>>10, nn = colg&1023;
      int h = nn>>6, d = nn&63;
      float bias = (which==0?bq[nn]:(which==1?bk[nn]:bv[nn]));
      float scale = (which==0)?0.125f:1.0f;
      #pragma unroll
      for (int r=0;r<4;r++){
        int m = m0 + wm + mt*16 + quad*4 + r;
        int bb = m>>10, t = m&1023;
        size_t o = (((size_t)(bb*16+h))*1024 + (size_t)t)*64 + d;
        float val = (acc[mt][nt][r] + bias)*scale;
        if (which==2){ v[o] = f2b(val); }
        else {
          u16 hi = f2b(val); float rem = val - b2f(hi); u16 lo = f2b(rem);
          if (which==0){ qhi[o]=hi; qlo[o]=lo; }
          else         { khi[o]=hi; klo[o]=lo; }
        }
      }
    }
}

// ---------------- output GEMM: y[2048x1024] @ WoT^T + bo, x gamma[t], f32 out ----------------
__global__ __launch_bounds__(256) void k_gemm_out(
    const u16* __restrict__ A, const u16* __restrict__ Bt,
    const float* __restrict__ bo, const float* __restrict__ gamma, float* __restrict__ out)
{
  __shared__ u16 As[128*40];
  __shared__ u16 Bs[128*40];
  const int n0 = blockIdx.x*128, m0 = blockIdx.y*128;
  const int tid = threadIdx.x, lane = tid&63, wave = tid>>6;
  const int quad = lane>>4, l16 = lane&15;
  const int wm = (wave>>1)*64, wn = (wave&1)*64;
  f32x4 zero = {0.f,0.f,0.f,0.f};
  f32x4 acc[4][4];
  #pragma unroll
  for (int i=0;i<4;i++)
    #pragma unroll
    for (int j=0;j<4;j++) acc[i][j] = zero;
  const int row = tid>>1, kk = (tid&1)*16;
  const u16* pa = A  + (size_t)(m0+row)*1024 + kk;
  const u16* pb = Bt + (size_t)(n0+row)*1024 + kk;
  for (int k0=0;k0<1024;k0+=32){
    __syncthreads();
    uint4 a0 = *(const uint4*)(pa); uint4 a1 = *(const uint4*)(pa+8);
    uint4 b0 = *(const uint4*)(pb); uint4 b1 = *(const uint4*)(pb+8);
    pa += 32; pb += 32;
    *(uint4*)&As[row*40+kk] = a0; *(uint4*)&As[row*40+kk+8] = a1;
    *(uint4*)&Bs[row*40+kk] = b0; *(uint4*)&Bs[row*40+kk+8] = b1;
    __syncthreads();
    bf16x8 af[4], bfr[4];
    #pragma unroll
    for (int mt=0;mt<4;mt++) af[mt]  = *(const bf16x8*)&As[(wm+mt*16+l16)*40 + quad*8];
    #pragma unroll
    for (int nt=0;nt<4;nt++) bfr[nt] = *(const bf16x8*)&Bs[(wn+nt*16+l16)*40 + quad*8];
    #pragma unroll
    for (int mt=0;mt<4;mt++)
      #pragma unroll
      for (int nt=0;nt<4;nt++)
        acc[mt][nt] = MFMA(af[mt], bfr[nt], acc[mt][nt]);
  }
  #pragma unroll
  for (int mt=0;mt<4;mt++)
    #pragma unroll
    for (int nt=0;nt<4;nt++){
      int colg = n0 + wn + nt*16 + l16;
      float bias = bo[colg];
      #pragma unroll
      for (int r=0;r<4;r++){
        int m = m0 + wm + mt*16 + quad*4 + r;
        int t = m&1023;
        float val = (acc[mt][nt][r] + bias)*gamma[t];
        out[(size_t)m*1024 + colg] = val;
      }
    }
}

// ---------------- RoPE on q,k (hi/lo pairs), first 32 dims of each head ----------------
__global__ __launch_bounds__(256) void k_rope(u16* __restrict__ qh, u16* __restrict__ ql,
                                              u16* __restrict__ kh, u16* __restrict__ kl)
{
  int idx = blockIdx.x*256 + threadIdx.x;      // B*H*T*16 = 524288
  int i = idx&15; int t = (idx>>4)&1023; int bh = idx>>14;
  float f = (float)t * exp2f(-0.625f*(float)i);
  float cs = cosf(f), sn = sinf(f);
  size_t base = (size_t)bh*65536 + (size_t)t*64;
  {
    float x1 = b2f(qh[base+i])    + b2f(ql[base+i]);
    float x2 = b2f(qh[base+16+i]) + b2f(ql[base+16+i]);
    float r1 = x1*cs - x2*sn, r2 = x2*cs + x1*sn;
    u16 h1 = f2b(r1); qh[base+i]   =h1; ql[base+i]   =f2b(r1-b2f(h1));
    u16 h2 = f2b(r2); qh[base+16+i]=h2; ql[base+16+i]=f2b(r2-b2f(h2));
  }
  {
    float x1 = b2f(kh[base+i])    + b2f(kl[base+i]);
    float x2 = b2f(kh[base+16+i]) + b2f(kl[base+16+i]);
    float r1 = x1*cs - x2*sn, r2 = x2*cs + x1*sn;
    u16 h1 = f2b(r1); kh[base+i]   =h1; kl[base+i]   =f2b(r1-b2f(h1));
    u16 h2 = f2b(r2); kh[base+16+i]=h2; kl[base+16+i]=f2b(r2-b2f(h2));
  }
}

// ---------------- softmax stats: full-row max & 1/sum, one wave per 16 rows ----------------
__global__ __launch_bounds__(256) void k_stats(
    const u16* __restrict__ qh, const u16* __restrict__ ql,
    const u16* __restrict__ kh, const u16* __restrict__ kl,
    float* __restrict__ mo, float* __restrict__ lo)
{
  int gw = blockIdx.x*4 + (threadIdx.x>>6);    // 0..2047 = b*1024 + h*64 + tt
  int lane = threadIdx.x&63, quad = lane>>4, l16 = lane&15;
  int b = gw>>10, rem = gw&1023, h = rem>>6, tt = rem&63;
  int t0 = tt*16;
  size_t pb = (size_t)(b*16+h)*65536;
  const u16* qhp = qh+pb; const u16* qlp = ql+pb;
  const u16* khp = kh+pb; const u16* klp = kl+pb;
  size_t ro = (size_t)(t0+l16)*64 + quad*8;
  bf16x8 ah0 = *(const bf16x8*)(qhp+ro);
  bf16x8 ah1 = *(const bf16x8*)(qhp+ro+32);
  bf16x8 al0 = *(const bf16x8*)(qlp+ro);
  bf16x8 al1 = *(const bf16x8*)(qlp+ro+32);
  float mc[4], lc[4];
  #pragma unroll
  for (int r=0;r<4;r++){ mc[r]=-1e30f; lc[r]=0.f; }
  for (int s0=0;s0<1024;s0+=16){
    size_t so = (size_t)(s0+l16)*64 + quad*8;
    bf16x8 bh0 = *(const bf16x8*)(khp+so);
    bf16x8 bh1 = *(const bf16x8*)(khp+so+32);
    bf16x8 bl0 = *(const bf16x8*)(klp+so);
    bf16x8 bl1 = *(const bf16x8*)(klp+so+32);
    f32x4 c = {0.f,0.f,0.f,0.f};
    c = MFMA(ah0,bh0,c); c = MFMA(ah1,bh1,c);
    c = MFMA(ah0,bl0,c); c = MFMA(ah1,bl1,c);
    c = MFMA(al0,bh0,c); c = MFMA(al1,bh1,c);
    #pragma unroll
    for (int r=0;r<4;r++){
      float sv = c[r];
      float mn = fmaxf(mc[r], sv);
      lc[r] = lc[r]*__expf(mc[r]-mn) + __expf(sv-mn);
      mc[r] = mn;
    }
  }
  #pragma unroll
  for (int r=0;r<4;r++){
    #pragma unroll
    for (int off=1; off<16; off<<=1){
      float mo2 = __shfl_xor(mc[r], off);
      float lo2 = __shfl_xor(lc[r], off);
      float mn = fmaxf(mc[r], mo2);
      lc[r] = lc[r]*__expf(mc[r]-mn) + lo2*__expf(mo2-mn);
      mc[r] = mn;
    }
  }
  if (l16==0){
    #pragma unroll
    for (int r=0;r<4;r++){
      int t = t0 + quad*4 + r;
      mo[(size_t)(b*16+h)*1024 + t] = mc[r];
      lo[(size_t)(b*16+h)*1024 + t] = 1.0f/lc[r];
    }
  }
}

// ---------------- P = softmax * w (causal), per-batch ----------------
__global__ __launch_bounds__(256) void k_pw(
    const u16* __restrict__ qh, const u16* __restrict__ ql,
    const u16* __restrict__ kh, const u16* __restrict__ kl,
    const float* __restrict__ mo, const float* __restrict__ lo,
    const float* __restrict__ tw, const float* __restrict__ alpha, const float* __restrict__ beta,
    u16* __restrict__ P, int b)
{
  int gw = blockIdx.x*4 + (threadIdx.x>>6);    // 0..1023 = h*64 + tt
  int lane = threadIdx.x&63, quad = lane>>4, l16 = lane&15;
  int h = gw>>6, tt = gw&63;
  int t0 = tt*16;
  size_t pb = (size_t)(b*16+h)*65536;
  const u16* qhp = qh+pb; const u16* qlp = ql+pb;
  const u16* khp = kh+pb; const u16* klp = kl+pb;
  size_t ro = (size_t)(t0+l16)*64 + quad*8;
  bf16x8 ah0 = *(const bf16x8*)(qhp+ro);
  bf16x8 ah1 = *(const bf16x8*)(qhp+ro+32);
  bf16x8 al0 = *(const bf16x8*)(qlp+ro);
  bf16x8 al1 = *(const bf16x8*)(qlp+ro+32);
  float mr[4], lr[4], br[4]; int trow[4];
  #pragma unroll
  for (int r=0;r<4;r++){
    int t = t0 + quad*4 + r; trow[r]=t;
    mr[r] = mo[(size_t)(b*16+h)*1024 + t];
    lr[r] = lo[(size_t)(b*16+h)*1024 + t];
    br[r] = beta[h*1024 + t];
  }
  u16* Pp = P + ((size_t)h<<20);
  const float* twp = tw + h*1024;
  for (int s0=0;s0<=t0;s0+=16){
    int s = s0 + l16;
    size_t so = (size_t)s*64 + quad*8;
    bf16x8 bh0 = *(const bf16x8*)(khp+so);
    bf16x8 bh1 = *(const bf16x8*)(khp+so+32);
    bf16x8 bl0 = *(const bf16x8*)(klp+so);
    bf16x8 bl1 = *(const bf16x8*)(klp+so+32);
    f32x4 c = {0.f,0.f,0.f,0.f};
    c = MFMA(ah0,bh0,c); c = MFMA(ah1,bh1,c);
    c = MFMA(ah0,bl0,c); c = MFMA(ah1,bl1,c);
    c = MFMA(al0,bh0,c); c = MFMA(al1,bh1,c);
    float av = alpha[h*1024 + s];
    #pragma unroll
    for (int r=0;r<4;r++){
      int t = trow[r];
      float p = 0.f;
      if (s <= t)
        p = __expf(c[r]-mr[r])*lr[r]*twp[1023+s-t]*av*br[r];
      Pp[((size_t)t<<10) + s] = f2b(p);
    }
  }
}

// ---------------- head-mix: A[g][t][s] = sum_h Wmix[g][h] P[h][t][s] ----------------
__global__ __launch_bounds__(256) void k_mix(const u16* __restrict__ P, const float* __restrict__ Wm,
                                             u16* __restrict__ Ab)
{
  int t = blockIdx.x, sc = blockIdx.y;
  int tmaxw = t|31;        // range PV will read (K=32 tiles)
  int tmaxr = t|15;        // range where P is defined
  int s0 = sc*64;
  if (s0 > tmaxw) return;
  __shared__ float Pl[16][64];
  __shared__ float Wl[16][16];
  int tid = threadIdx.x, g = tid>>4, j = tid&15;
  Wl[g][j] = Wm[g*16+j];
  int sb = s0 + j*4;
  {
    float v0=0.f,v1=0.f,v2=0.f,v3=0.f;
    if (sb <= tmaxr){
      const u16* pp = P + (((size_t)g)<<20) + (((size_t)t)<<10) + sb;
      ushort4 u = *(const ushort4*)pp;
      v0=b2f(u.x); v1=b2f(u.y); v2=b2f(u.z); v3=b2f(u.w);
    }
    Pl[g][j*4+0]=v0; Pl[g][j*4+1]=v1; Pl[g][j*4+2]=v2; Pl[g][j*4+3]=v3;
  }
  __syncthreads();
  float a0=0.f,a1=0.f,a2=0.f,a3=0.f;
  #pragma unroll
  for (int h=0;h<16;h++){
    float w = Wl[g][h];
    a0 += w*Pl[h][j*4+0]; a1 += w*Pl[h][j*4+1];
    a2 += w*Pl[h][j*4+2]; a3 += w*Pl[h][j*4+3];
  }
  if (sb <= tmaxw){
    ushort4 o; o.x=f2b(a0); o.y=f2b(a1); o.z=f2b(a2); o.w=f2b(a3);
    *(ushort4*)(Ab + (((size_t)g)<<20) + (((size_t)t)<<10) + sb) = o;
  }
}

// ---------------- PV: y[b,t,g,d] = sum_s A[g][t][s] v[g][s][d] ----------------
__global__ __launch_bounds__(256) void k_pv(const u16* __restrict__ Ab, const u16* __restrict__ vT,
                                            u16* __restrict__ y, int b)
{
  int gw = blockIdx.x*4 + (threadIdx.x>>6);   // 0..1023 = g*64 + tt
  int lane = threadIdx.x&63, quad = lane>>4, l16 = lane&15;
  int g = gw>>6, tt = gw&63;
  int t0 = tt*16;
  const u16* ap = Ab + ((size_t)g<<20);
  const u16* vp = vT + (size_t)(b*16+g)*65536;   // [d][s]
  f32x4 zero = {0.f,0.f,0.f,0.f};
  f32x4 acc[4];
  #pragma unroll
  for (int dt=0;dt<4;dt++) acc[dt]=zero;
  int nst = (t0+15)/32 + 1;
  for (int st=0; st<nst; st++){
    int s0 = st*32;
    bf16x8 af = *(const bf16x8*)(ap + (((size_t)(t0+l16))<<10) + s0 + quad*8);
    #pragma unroll
    for (int dt=0;dt<4;dt++){
      bf16x8 bfv = *(const bf16x8*)(vp + (size_t)(dt*16+l16)*1024 + s0 + quad*8);
      acc[dt] = MFMA(af, bfv, acc[dt]);
    }
  }
  #pragma unroll
  for (int dt=0;dt<4;dt++)
    #pragma unroll
    for (int r=0;r<4;r++){
      int t = t0 + quad*4 + r;
      y[(size_t)(b*1024+t)*1024 + g*64 + dt*16 + l16] = f2b(acc[dt][r]);
    }
}

__global__ void k_fail(float* out){ if (threadIdx.x==0) out[0] = 1e30f; } // ws-too-small marker

extern "C" void kernel_launch(void* const* d_in, const int* in_sizes, int n_in,
                              void* d_out, int out_size, void* d_ws, size_t ws_size,
                              hipStream_t stream)
{
  const float* x     = (const float*)d_in[0];
  const float* tw    = (const float*)d_in[1];
  const float* alpha = (const float*)d_in[2];
  const float* beta  = (const float*)d_in[3];
  const float* gamma = (const float*)d_in[4];
  const float* Wq    = (const float*)d_in[5];
  const float* bq    = (const float*)d_in[6];
  const float* Wk    = (const float*)d_in[7];
  const float* bk    = (const float*)d_in[8];
  const float* Wv    = (const float*)d_in[9];
  const float* bv    = (const float*)d_in[10];
  const float* Wmix  = (const float*)d_in[11];
  const float* Wo    = (const float*)d_in[12];
  const float* bo    = (const float*)d_in[13];
  float* out = (float*)d_out;

  char* ws = (char*)d_ws;
  size_t off = 0;
  auto take = [&](size_t bytes)->char*{
    char* p = ws + off; off += (bytes + 255) & ~(size_t)255; return p;
  };
  u16*   xs  = (u16*)take((size_t)2097152*2);   // xs (B*T, C) bf16
  u16*   WT  = (u16*)take((size_t)3145728*2);   // [3072][1024] = Wq^T|Wk^T|Wv^T bf16
  u16*   WoT = (u16*)take((size_t)1048576*2);
  u16*   qhi = (u16*)take((size_t)2097152*2);   // (b,h,t,d)
  u16*   qlo = (u16*)take((size_t)2097152*2);
  u16*   khi = (u16*)take((size_t)2097152*2);
  u16*   klo = (u16*)take((size_t)2097152*2);
  u16*   v   = (u16*)take((size_t)2097152*2);
  u16*   vTb = (u16*)take((size_t)2097152*2);   // (b,h,d,t)
  float* mb  = (float*)take((size_t)32768*4);
  float* lb  = (float*)take((size_t)32768*4);
  u16*   yb  = (u16*)take((size_t)2097152*2);   // (b,t,g,d)
  u16*   P   = (u16*)take((size_t)16777216*2);  // per-batch [h][t][s]
  u16*   A   = (u16*)take((size_t)16777216*2);  // per-batch [g][t][s]
  if (off > ws_size){
    hipLaunchKernelGGL(k_fail, dim3(1), dim3(64), 0, stream, out);
    return;
  }

  hipLaunchKernelGGL(k_prep, dim3(1024), dim3(256), 0, stream, x, xs);
  hipLaunchKernelGGL(k_tr, dim3(16,16), dim3(256), 0, stream, Wq, WT);
  hipLaunchKernelGGL(k_tr, dim3(16,16), dim3(256), 0, stream, Wk, WT + 1048576);
  hipLaunchKernelGGL(k_tr, dim3(16,16), dim3(256), 0, stream, Wv, WT + 2097152);
  hipLaunchKernelGGL(k_tr, dim3(16,16), dim3(256), 0, stream, Wo, WoT);
  hipLaunchKernelGGL(k_gemm_qkv, dim3(24,16), dim3(256), 0, stream,
                     xs, WT, bq, bk, bv, qhi, qlo, khi, klo, v);
  hipLaunchKernelGGL(k_rope, dim3(2048), dim3(256), 0, stream, qhi, qlo, khi, klo);
  hipLaunchKernelGGL(k_vt, dim3(32,16), dim3(256), 0, stream, v, vTb);
  hipLaunchKernelGGL(k_stats, dim3(512), dim3(256), 0, stream, qhi, qlo, khi, klo, mb, lb);
  for (int b=0;b<2;b++){
    hipLaunchKernelGGL(k_pw, dim3(256), dim3(256), 0, stream,
                       qhi, qlo, khi, klo, mb, lb, tw, alpha, beta, P, b);
    hipLaunchKernelGGL(k_mix, dim3(1024,16), dim3(256), 0, stream, P, Wmix, A);
    hipLaunchKernelGGL(k_pv, dim3(256), dim3(256), 0, stream, A, vTb, yb, b);
  }
  hipLaunchKernelGGL(k_gemm_out, dim3(8,16), dim3(256), 0, stream, yb, WoT, bo, gamma, out);
}

// Round 3
// 417.194 us; speedup vs baseline: 1.0542x; 1.0542x over previous
//
#include <hip/hip_runtime.h>

typedef unsigned short u16;
typedef __attribute__((ext_vector_type(8))) short bf16x8;
typedef __attribute__((ext_vector_type(4))) float f32x4;

#define MFMA(a,b,c) __builtin_amdgcn_mfma_f32_16x16x32_bf16(a,b,c,0,0,0)

__device__ __forceinline__ float b2f(u16 u){
  union { unsigned int i; float f; } v; v.i = ((unsigned int)u)<<16; return v.f;
}
__device__ __forceinline__ u16 f2b(float f){
  union { float f; unsigned int i; } v; v.f = f;
  unsigned int r = (v.i + 0x7FFFu + ((v.i>>16)&1u))>>16;
  return (u16)r;
}

// ---------------- prep: time-shift first half of channels, f32 -> bf16 ----------------
__global__ __launch_bounds__(256) void k_prep(const float* __restrict__ x, u16* __restrict__ xs)
{
  int idx = blockIdx.x*256 + threadIdx.x;     // one thread per 8 elements
  size_t e = (size_t)idx*8;
  int c = (int)(e & 1023);
  int t = (int)((e>>10)&1023);
  float4 f0 = {0.f,0.f,0.f,0.f}, f1 = {0.f,0.f,0.f,0.f};
  const float* src = nullptr;
  if (c < 512){ if (t > 0) src = x + e - 1024; }
  else        { src = x + e; }
  if (src){ f0 = *(const float4*)src; f1 = *(const float4*)(src+4); }
  u16 o[8];
  o[0]=f2b(f0.x); o[1]=f2b(f0.y); o[2]=f2b(f0.z); o[3]=f2b(f0.w);
  o[4]=f2b(f1.x); o[5]=f2b(f1.y); o[6]=f2b(f1.z); o[7]=f2b(f1.w);
  *(uint4*)(xs + e) = *(const uint4*)o;
}

// ---------------- 1024x1024 transpose, f32 in -> bf16 out ----------------
__global__ __launch_bounds__(256) void k_tr(const float* __restrict__ src, u16* __restrict__ dst)
{
  int c0 = blockIdx.x*64, r0 = blockIdx.y*64;
  __shared__ u16 tile[64][72];
  int tid = threadIdx.x;
  int r = tid>>2, cc = (tid&3)*16;
  const float* sp = src + (size_t)(r0+r)*1024 + c0+cc;
  float4 a0 = *(const float4*)(sp);
  float4 a1 = *(const float4*)(sp+4);
  float4 a2 = *(const float4*)(sp+8);
  float4 a3 = *(const float4*)(sp+12);
  tile[r][cc+0]=f2b(a0.x); tile[r][cc+1]=f2b(a0.y); tile[r][cc+2]=f2b(a0.z); tile[r][cc+3]=f2b(a0.w);
  tile[r][cc+4]=f2b(a1.x); tile[r][cc+5]=f2b(a1.y); tile[r][cc+6]=f2b(a1.z); tile[r][cc+7]=f2b(a1.w);
  tile[r][cc+8]=f2b(a2.x); tile[r][cc+9]=f2b(a2.y); tile[r][cc+10]=f2b(a2.z); tile[r][cc+11]=f2b(a2.w);
  tile[r][cc+12]=f2b(a3.x); tile[r][cc+13]=f2b(a3.y); tile[r][cc+14]=f2b(a3.z); tile[r][cc+15]=f2b(a3.w);
  __syncthreads();
  int c = tid>>2, rr = (tid&3)*16;
  uint4 o0,o1; u16* p0=(u16*)&o0; u16* p1=(u16*)&o1;
  #pragma unroll
  for (int i=0;i<8;i++){ p0[i]=tile[rr+i][c]; p1[i]=tile[rr+8+i][c]; }
  *(uint4*)(dst + (size_t)(c0+c)*1024 + r0+rr)   = o0;
  *(uint4*)(dst + (size_t)(c0+c)*1024 + r0+rr+8) = o1;
}

// ---------------- v transpose: (bh,t,d) -> (bh,d,t), bf16 ----------------
__global__ __launch_bounds__(256) void k_vt(const u16* __restrict__ v, u16* __restrict__ vT)
{
  int bh = blockIdx.x, t0 = blockIdx.y*64;
  __shared__ u16 tile[64][72];
  const u16* src = v + (size_t)bh*65536;
  int tid = threadIdx.x;
  int r = tid>>2, c0 = (tid&3)*16;
  *(uint4*)&tile[r][c0]   = *(const uint4*)(src + (size_t)(t0+r)*64 + c0);
  *(uint4*)&tile[r][c0+8] = *(const uint4*)(src + (size_t)(t0+r)*64 + c0+8);
  __syncthreads();
  int d = tid>>2, tc0 = (tid&3)*16;
  uint4 o0,o1; u16* p0=(u16*)&o0; u16* p1=(u16*)&o1;
  #pragma unroll
  for (int i=0;i<8;i++){ p0[i]=tile[tc0+i][d]; p1[i]=tile[tc0+8+i][d]; }
  u16* dst = vT + (size_t)bh*65536 + (size_t)d*1024 + t0 + tc0;
  *(uint4*)(dst)   = o0;
  *(uint4*)(dst+8) = o1;
}

// ---------------- QKV GEMM + fused RoPE epilogue ----------------
__global__ __launch_bounds__(256) void k_gemm_qkv(
    const u16* __restrict__ A, const u16* __restrict__ Bt,
    const float* __restrict__ bq, const float* __restrict__ bk, const float* __restrict__ bv,
    u16* __restrict__ qhi, u16* __restrict__ qlo,
    u16* __restrict__ khi, u16* __restrict__ klo, u16* __restrict__ v)
{
  __shared__ u16 As[128*40];
  __shared__ u16 Bs[128*40];
  const int n0 = blockIdx.x*128, m0 = blockIdx.y*128;
  const int tid = threadIdx.x, lane = tid&63, wave = tid>>6;
  const int quad = lane>>4, l16 = lane&15;
  const int wm = (wave>>1)*64, wn = (wave&1)*64;
  f32x4 zero = {0.f,0.f,0.f,0.f};
  f32x4 acc[4][4];
  #pragma unroll
  for (int i=0;i<4;i++)
    #pragma unroll
    for (int j=0;j<4;j++) acc[i][j] = zero;
  const int row = tid>>1, kk = (tid&1)*16;
  const u16* pa = A  + (size_t)(m0+row)*1024 + kk;
  const u16* pb = Bt + (size_t)(n0+row)*1024 + kk;
  for (int k0=0;k0<1024;k0+=32){
    __syncthreads();
    uint4 a0 = *(const uint4*)(pa); uint4 a1 = *(const uint4*)(pa+8);
    uint4 b0 = *(const uint4*)(pb); uint4 b1 = *(const uint4*)(pb+8);
    pa += 32; pb += 32;
    *(uint4*)&As[row*40+kk] = a0; *(uint4*)&As[row*40+kk+8] = a1;
    *(uint4*)&Bs[row*40+kk] = b0; *(uint4*)&Bs[row*40+kk+8] = b1;
    __syncthreads();
    bf16x8 af[4], bfr[4];
    #pragma unroll
    for (int mt=0;mt<4;mt++) af[mt]  = *(const bf16x8*)&As[(wm+mt*16+l16)*40 + quad*8];
    #pragma unroll
    for (int nt=0;nt<4;nt++) bfr[nt] = *(const bf16x8*)&Bs[(wn+nt*16+l16)*40 + quad*8];
    #pragma unroll
    for (int mt=0;mt<4;mt++)
      #pragma unroll
      for (int nt=0;nt<4;nt++)
        acc[mt][nt] = MFMA(af[mt], bfr[nt], acc[mt][nt]);
  }
  const int colbase = n0 + wn;          // 64-aligned -> which,h uniform per wave
  const int which = colbase>>10;
  const int nn0 = colbase & 1023;
  const int h = nn0>>6;
  const float* barr = (which==0)?bq:((which==1)?bk:bv);
  float bias[4];
  #pragma unroll
  for (int nt=0;nt<4;nt++) bias[nt] = barr[nn0 + nt*16 + l16];
  if (which == 2){
    #pragma unroll
    for (int mt=0;mt<4;mt++)
      #pragma unroll
      for (int r=0;r<4;r++){
        int m = m0 + wm + mt*16 + quad*4 + r;
        int bb = m>>10, t = m&1023;
        size_t ob = (((size_t)(bb*16+h))*1024 + (size_t)t)*64 + l16;
        #pragma unroll
        for (int nt=0;nt<4;nt++)
          v[ob + nt*16] = f2b(acc[mt][nt][r] + bias[nt]);
      }
  } else {
    const float scale = (which==0)?0.125f:1.0f;
    u16* hib = (which==0)? qhi : khi;
    u16* lob = (which==0)? qlo : klo;
    const float e = exp2f(-0.625f*(float)l16);
    #pragma unroll
    for (int mt=0;mt<4;mt++)
      #pragma unroll
      for (int r=0;r<4;r++){
        int m = m0 + wm + mt*16 + quad*4 + r;
        int bb = m>>10, t = m&1023;
        float f = (float)t * e;
        float cs = cosf(f), sn = sinf(f);
        float x0 = acc[mt][0][r] + bias[0];
        float x1 = acc[mt][1][r] + bias[1];
        float v0 = (x0*cs - x1*sn)*scale;
        float v1 = (x1*cs + x0*sn)*scale;
        float v2 = (acc[mt][2][r] + bias[2])*scale;
        float v3 = (acc[mt][3][r] + bias[3])*scale;
        size_t ob = (((size_t)(bb*16+h))*1024 + (size_t)t)*64 + l16;
        u16 h0=f2b(v0); hib[ob]=h0;    lob[ob]   =f2b(v0-b2f(h0));
        u16 h1=f2b(v1); hib[ob+16]=h1; lob[ob+16]=f2b(v1-b2f(h1));
        u16 h2=f2b(v2); hib[ob+32]=h2; lob[ob+32]=f2b(v2-b2f(h2));
        u16 h3=f2b(v3); hib[ob+48]=h3; lob[ob+48]=f2b(v3-b2f(h3));
      }
  }
}

// ---------------- output GEMM: y[2048x1024] @ WoT^T + bo, x gamma[t], f32 out ----------------
__global__ __launch_bounds__(256) void k_gemm_out(
    const u16* __restrict__ A, const u16* __restrict__ Bt,
    const float* __restrict__ bo, const float* __restrict__ gamma, float* __restrict__ out)
{
  __shared__ u16 As[128*40];
  __shared__ u16 Bs[128*40];
  const int n0 = blockIdx.x*128, m0 = blockIdx.y*128;
  const int tid = threadIdx.x, lane = tid&63, wave = tid>>6;
  const int quad = lane>>4, l16 = lane&15;
  const int wm = (wave>>1)*64, wn = (wave&1)*64;
  f32x4 zero = {0.f,0.f,0.f,0.f};
  f32x4 acc[4][4];
  #pragma unroll
  for (int i=0;i<4;i++)
    #pragma unroll
    for (int j=0;j<4;j++) acc[i][j] = zero;
  const int row = tid>>1, kk = (tid&1)*16;
  const u16* pa = A  + (size_t)(m0+row)*1024 + kk;
  const u16* pb = Bt + (size_t)(n0+row)*1024 + kk;
  for (int k0=0;k0<1024;k0+=32){
    __syncthreads();
    uint4 a0 = *(const uint4*)(pa); uint4 a1 = *(const uint4*)(pa+8);
    uint4 b0 = *(const uint4*)(pb); uint4 b1 = *(const uint4*)(pb+8);
    pa += 32; pb += 32;
    *(uint4*)&As[row*40+kk] = a0; *(uint4*)&As[row*40+kk+8] = a1;
    *(uint4*)&Bs[row*40+kk] = b0; *(uint4*)&Bs[row*40+kk+8] = b1;
    __syncthreads();
    bf16x8 af[4], bfr[4];
    #pragma unroll
    for (int mt=0;mt<4;mt++) af[mt]  = *(const bf16x8*)&As[(wm+mt*16+l16)*40 + quad*8];
    #pragma unroll
    for (int nt=0;nt<4;nt++) bfr[nt] = *(const bf16x8*)&Bs[(wn+nt*16+l16)*40 + quad*8];
    #pragma unroll
    for (int mt=0;mt<4;mt++)
      #pragma unroll
      for (int nt=0;nt<4;nt++)
        acc[mt][nt] = MFMA(af[mt], bfr[nt], acc[mt][nt]);
  }
  #pragma unroll
  for (int mt=0;mt<4;mt++)
    #pragma unroll
    for (int nt=0;nt<4;nt++){
      int colg = n0 + wn + nt*16 + l16;
      float bias = bo[colg];
      #pragma unroll
      for (int r=0;r<4;r++){
        int m = m0 + wm + mt*16 + quad*4 + r;
        int t = m&1023;
        float val = (acc[mt][nt][r] + bias)*gamma[t];
        out[(size_t)m*1024 + colg] = val;
      }
    }
}

// ---------------- softmax stats: block per (b,h,tt); 4-way s-split + LDS merge ----------------
__global__ __launch_bounds__(256) void k_stats(
    const u16* __restrict__ qh, const u16* __restrict__ ql,
    const u16* __restrict__ kh, const u16* __restrict__ kl,
    float* __restrict__ mo, float* __restrict__ lo)
{
  int bx = blockIdx.x;                       // 2048 = b*1024 + h*64 + tt
  int b = bx>>10, h = (bx>>6)&15, tt = bx&63;
  int tid = threadIdx.x, wave = tid>>6, lane = tid&63, quad = lane>>4, l16 = lane&15;
  int t0 = tt*16;
  size_t pb = (size_t)(b*16+h)*65536;
  const u16* qhp = qh+pb; const u16* qlp = ql+pb;
  const u16* khp = kh+pb; const u16* klp = kl+pb;
  size_t ro = (size_t)(t0+l16)*64 + quad*8;
  bf16x8 ah0 = *(const bf16x8*)(qhp+ro);
  bf16x8 ah1 = *(const bf16x8*)(qhp+ro+32);
  bf16x8 al0 = *(const bf16x8*)(qlp+ro);
  bf16x8 al1 = *(const bf16x8*)(qlp+ro+32);
  float mc[4], lc[4];
  #pragma unroll
  for (int r=0;r<4;r++){ mc[r]=-1e30f; lc[r]=0.f; }
  for (int j=wave; j<64; j+=4){
    size_t so = (size_t)(j*16+l16)*64 + quad*8;
    bf16x8 bh0 = *(const bf16x8*)(khp+so);
    bf16x8 bh1 = *(const bf16x8*)(khp+so+32);
    bf16x8 bl0 = *(const bf16x8*)(klp+so);
    bf16x8 bl1 = *(const bf16x8*)(klp+so+32);
    f32x4 c = {0.f,0.f,0.f,0.f};
    c = MFMA(ah0,bh0,c); c = MFMA(ah1,bh1,c);
    c = MFMA(ah0,bl0,c); c = MFMA(ah1,bl1,c);
    c = MFMA(al0,bh0,c); c = MFMA(al1,bh1,c);
    #pragma unroll
    for (int r=0;r<4;r++){
      float sv = c[r];
      float mn = fmaxf(mc[r], sv);
      lc[r] = lc[r]*__expf(mc[r]-mn) + __expf(sv-mn);
      mc[r] = mn;
    }
  }
  __shared__ float4 sM[4][64];
  __shared__ float4 sL[4][64];
  float4 m4; m4.x=mc[0]; m4.y=mc[1]; m4.z=mc[2]; m4.w=mc[3];
  float4 l4; l4.x=lc[0]; l4.y=lc[1]; l4.z=lc[2]; l4.w=lc[3];
  sM[wave][lane] = m4; sL[wave][lane] = l4;
  __syncthreads();
  if (wave==0){
    float mm[4], ll[4];
    #pragma unroll
    for (int w=0; w<4; w++){
      float4 wm4 = sM[w][lane], wl4 = sL[w][lane];
      float m2[4] = {wm4.x,wm4.y,wm4.z,wm4.w};
      float l2[4] = {wl4.x,wl4.y,wl4.z,wl4.w};
      if (w==0){
        #pragma unroll
        for (int r=0;r<4;r++){ mm[r]=m2[r]; ll[r]=l2[r]; }
      } else {
        #pragma unroll
        for (int r=0;r<4;r++){
          float mn = fmaxf(mm[r], m2[r]);
          ll[r] = ll[r]*__expf(mm[r]-mn) + l2[r]*__expf(m2[r]-mn);
          mm[r] = mn;
        }
      }
    }
    #pragma unroll
    for (int r=0;r<4;r++){
      #pragma unroll
      for (int off=1; off<16; off<<=1){
        float mo2 = __shfl_xor(mm[r], off);
        float lo2 = __shfl_xor(ll[r], off);
        float mn = fmaxf(mm[r], mo2);
        ll[r] = ll[r]*__expf(mm[r]-mn) + lo2*__expf(mo2-mn);
        mm[r] = mn;
      }
    }
    if (l16==0){
      #pragma unroll
      for (int r=0;r<4;r++){
        int t = t0 + quad*4 + r;
        mo[(size_t)(b*16+h)*1024 + t] = mm[r];
        lo[(size_t)(b*16+h)*1024 + t] = 1.0f/ll[r];
      }
    }
  }
}

// ---------------- P = softmax * w (causal): block per (h,tt), waves split s ----------------
__global__ __launch_bounds__(256) void k_pw(
    const u16* __restrict__ qh, const u16* __restrict__ ql,
    const u16* __restrict__ kh, const u16* __restrict__ kl,
    const float* __restrict__ mo, const float* __restrict__ lo,
    const float* __restrict__ tw, const float* __restrict__ alpha, const float* __restrict__ beta,
    u16* __restrict__ P, int b)
{
  int bx = blockIdx.x;                       // 1024 = h*64 + tt
  int h = bx>>6, tt = bx&63;
  int tid = threadIdx.x, wave = tid>>6, lane = tid&63, quad = lane>>4, l16 = lane&15;
  int t0 = tt*16;
  size_t pb = (size_t)(b*16+h)*65536;
  const u16* qhp = qh+pb; const u16* qlp = ql+pb;
  const u16* khp = kh+pb; const u16* klp = kl+pb;
  size_t ro = (size_t)(t0+l16)*64 + quad*8;
  bf16x8 ah0 = *(const bf16x8*)(qhp+ro);
  bf16x8 ah1 = *(const bf16x8*)(qhp+ro+32);
  bf16x8 al0 = *(const bf16x8*)(qlp+ro);
  bf16x8 al1 = *(const bf16x8*)(qlp+ro+32);
  float mr[4], lr[4], br[4]; int trow[4];
  #pragma unroll
  for (int r=0;r<4;r++){
    int t = t0 + quad*4 + r; trow[r]=t;
    mr[r] = mo[(size_t)(b*16+h)*1024 + t];
    lr[r] = lo[(size_t)(b*16+h)*1024 + t];
    br[r] = beta[h*1024 + t];
  }
  u16* Pp = P + ((size_t)h<<20);
  const float* twp = tw + h*1024;
  for (int j=wave; j*16<=t0; j+=4){
    int s = j*16 + l16;
    size_t so = (size_t)s*64 + quad*8;
    bf16x8 bh0 = *(const bf16x8*)(khp+so);
    bf16x8 bh1 = *(const bf16x8*)(khp+so+32);
    bf16x8 bl0 = *(const bf16x8*)(klp+so);
    bf16x8 bl1 = *(const bf16x8*)(klp+so+32);
    f32x4 c = {0.f,0.f,0.f,0.f};
    c = MFMA(ah0,bh0,c); c = MFMA(ah1,bh1,c);
    c = MFMA(ah0,bl0,c); c = MFMA(ah1,bl1,c);
    c = MFMA(al0,bh0,c); c = MFMA(al1,bh1,c);
    float av = alpha[h*1024 + s];
    #pragma unroll
    for (int r=0;r<4;r++){
      int t = trow[r];
      float p = 0.f;
      if (s <= t)
        p = __expf(c[r]-mr[r])*lr[r]*twp[1023+s-t]*av*br[r];
      Pp[((size_t)t<<10) + s] = f2b(p);
    }
  }
}

// ---------------- head-mix: A[g][t][s] = sum_h Wmix[g][h] P[h][t][s] ----------------
// block: 4 t-rows x 256 s (ushort4 per thread)
__global__ __launch_bounds__(256) void k_mix(const u16* __restrict__ P, const float* __restrict__ Wm,
                                             u16* __restrict__ Ab)
{
  int tid = threadIdx.x;
  int t = blockIdx.x*4 + (tid>>6);
  int sb = blockIdx.y*256 + (tid&63)*4;
  int tmaxw = t|31, tmaxr = t|15;
  if ((int)(blockIdx.y*256) > tmaxw) return;
  __shared__ float Wl[16][16];
  Wl[tid>>4 & 15][tid&15] = Wm[tid & 255];
  __syncthreads();
  float a[16][4];
  #pragma unroll
  for (int g=0;g<16;g++){ a[g][0]=0.f; a[g][1]=0.f; a[g][2]=0.f; a[g][3]=0.f; }
  #pragma unroll
  for (int h=0;h<16;h++){
    float p0=0.f,p1=0.f,p2=0.f,p3=0.f;
    if (sb <= tmaxr){
      ushort4 u = *(const ushort4*)(P + (((size_t)h)<<20) + (((size_t)t)<<10) + sb);
      p0=b2f(u.x); p1=b2f(u.y); p2=b2f(u.z); p3=b2f(u.w);
    }
    #pragma unroll
    for (int g=0;g<16;g++){
      float w = Wl[g][h];
      a[g][0]+=w*p0; a[g][1]+=w*p1; a[g][2]+=w*p2; a[g][3]+=w*p3;
    }
  }
  if (sb <= tmaxw){
    #pragma unroll
    for (int g=0;g<16;g++){
      ushort4 o; o.x=f2b(a[g][0]); o.y=f2b(a[g][1]); o.z=f2b(a[g][2]); o.w=f2b(a[g][3]);
      *(ushort4*)(Ab + (((size_t)g)<<20) + (((size_t)t)<<10) + sb) = o;
    }
  }
}

// ---------------- PV: block per (g,tt); wave per 16-d slab ----------------
__global__ __launch_bounds__(256) void k_pv(const u16* __restrict__ Ab, const u16* __restrict__ vT,
                                            u16* __restrict__ y, int b)
{
  int bx = blockIdx.x;                       // 1024 = g*64 + tt
  int g = bx>>6, tt = bx&63;
  int tid = threadIdx.x, dt = tid>>6, lane = tid&63, quad = lane>>4, l16 = lane&15;
  int t0 = tt*16;
  const u16* ap = Ab + ((size_t)g<<20);
  const u16* vp = vT + (size_t)(b*16+g)*65536;   // [d][s]
  f32x4 acc = {0.f,0.f,0.f,0.f};
  int nst = t0/32 + 1;
  const u16* arow = ap + (((size_t)(t0+l16))<<10) + quad*8;
  const u16* vrow = vp + (size_t)(dt*16+l16)*1024 + quad*8;
  for (int st=0; st<nst; st++){
    bf16x8 af  = *(const bf16x8*)(arow + st*32);
    bf16x8 bfv = *(const bf16x8*)(vrow + st*32);
    acc = MFMA(af, bfv, acc);
  }
  #pragma unroll
  for (int r=0;r<4;r++){
    int t = t0 + quad*4 + r;
    y[(size_t)(b*1024+t)*1024 + g*64 + dt*16 + l16] = f2b(acc[r]);
  }
}

__global__ void k_fail(float* out){ if (threadIdx.x==0) out[0] = 1e30f; } // ws-too-small marker

extern "C" void kernel_launch(void* const* d_in, const int* in_sizes, int n_in,
                              void* d_out, int out_size, void* d_ws, size_t ws_size,
                              hipStream_t stream)
{
  const float* x     = (const float*)d_in[0];
  const float* tw    = (const float*)d_in[1];
  const float* alpha = (const float*)d_in[2];
  const float* beta  = (const float*)d_in[3];
  const float* gamma = (const float*)d_in[4];
  const float* Wq    = (const float*)d_in[5];
  const float* bq    = (const float*)d_in[6];
  const float* Wk    = (const float*)d_in[7];
  const float* bk    = (const float*)d_in[8];
  const float* Wv    = (const float*)d_in[9];
  const float* bv    = (const float*)d_in[10];
  const float* Wmix  = (const float*)d_in[11];
  const float* Wo    = (const float*)d_in[12];
  const float* bo    = (const float*)d_in[13];
  float* out = (float*)d_out;

  char* ws = (char*)d_ws;
  size_t off = 0;
  auto take = [&](size_t bytes)->char*{
    char* p = ws + off; off += (bytes + 255) & ~(size_t)255; return p;
  };
  u16*   xs  = (u16*)take((size_t)2097152*2);   // xs (B*T, C) bf16
  u16*   WT  = (u16*)take((size_t)3145728*2);   // [3072][1024] = Wq^T|Wk^T|Wv^T bf16
  u16*   WoT = (u16*)take((size_t)1048576*2);
  u16*   qhi = (u16*)take((size_t)2097152*2);   // (b,h,t,d)
  u16*   qlo = (u16*)take((size_t)2097152*2);
  u16*   khi = (u16*)take((size_t)2097152*2);
  u16*   klo = (u16*)take((size_t)2097152*2);
  u16*   v   = (u16*)take((size_t)2097152*2);
  u16*   vTb = (u16*)take((size_t)2097152*2);   // (b,h,d,t)
  float* mb  = (float*)take((size_t)32768*4);
  float* lb  = (float*)take((size_t)32768*4);
  u16*   yb  = (u16*)take((size_t)2097152*2);   // (b,t,g,d)
  u16*   P   = (u16*)take((size_t)16777216*2);  // per-batch [h][t][s]
  u16*   A   = (u16*)take((size_t)16777216*2);  // per-batch [g][t][s]
  if (off > ws_size){
    hipLaunchKernelGGL(k_fail, dim3(1), dim3(64), 0, stream, out);
    return;
  }

  hipLaunchKernelGGL(k_prep, dim3(1024), dim3(256), 0, stream, x, xs);
  hipLaunchKernelGGL(k_tr, dim3(16,16), dim3(256), 0, stream, Wq, WT);
  hipLaunchKernelGGL(k_tr, dim3(16,16), dim3(256), 0, stream, Wk, WT + 1048576);
  hipLaunchKernelGGL(k_tr, dim3(16,16), dim3(256), 0, stream, Wv, WT + 2097152);
  hipLaunchKernelGGL(k_tr, dim3(16,16), dim3(256), 0, stream, Wo, WoT);
  hipLaunchKernelGGL(k_gemm_qkv, dim3(24,16), dim3(256), 0, stream,
                     xs, WT, bq, bk, bv, qhi, qlo, khi, klo, v);
  hipLaunchKernelGGL(k_vt, dim3(32,16), dim3(256), 0, stream, v, vTb);
  hipLaunchKernelGGL(k_stats, dim3(2048), dim3(256), 0, stream, qhi, qlo, khi, klo, mb, lb);
  for (int b=0;b<2;b++){
    hipLaunchKernelGGL(k_pw, dim3(1024), dim3(256), 0, stream,
                       qhi, qlo, khi, klo, mb, lb, tw, alpha, beta, P, b);
    hipLaunchKernelGGL(k_mix, dim3(256,4), dim3(256), 0, stream, P, Wmix, A);
    hipLaunchKernelGGL(k_pv, dim3(1024), dim3(256), 0, stream, A, vTb, yb, b);
  }
  hipLaunchKernelGGL(k_gemm_out, dim3(8,16), dim3(256), 0, stream, yb, WoT, bo, gamma, out);
}

// Round 4
// 309.592 us; speedup vs baseline: 1.4206x; 1.3476x over previous
//
#include <hip/hip_runtime.h>

typedef unsigned short u16;
typedef __attribute__((ext_vector_type(8))) short bf16x8;
typedef __attribute__((ext_vector_type(4))) float f32x4;

#define MFMA(a,b,c) __builtin_amdgcn_mfma_f32_16x16x32_bf16(a,b,c,0,0,0)

__device__ __forceinline__ float b2f(u16 u){
  union { unsigned int i; float f; } v; v.i = ((unsigned int)u)<<16; return v.f;
}
__device__ __forceinline__ u16 f2b(float f){
  union { float f; unsigned int i; } v; v.f = f;
  unsigned int r = (v.i + 0x7FFFu + ((v.i>>16)&1u))>>16;
  return (u16)r;
}

// ---------------- prep: time-shift first half of channels, f32 -> bf16 ----------------
__global__ __launch_bounds__(256) void k_prep(const float* __restrict__ x, u16* __restrict__ xs)
{
  int idx = blockIdx.x*256 + threadIdx.x;     // one thread per 8 elements
  size_t e = (size_t)idx*8;
  int c = (int)(e & 1023);
  int t = (int)((e>>10)&1023);
  float4 f0 = {0.f,0.f,0.f,0.f}, f1 = {0.f,0.f,0.f,0.f};
  const float* src = nullptr;
  if (c < 512){ if (t > 0) src = x + e - 1024; }
  else        { src = x + e; }
  if (src){ f0 = *(const float4*)src; f1 = *(const float4*)(src+4); }
  u16 o[8];
  o[0]=f2b(f0.x); o[1]=f2b(f0.y); o[2]=f2b(f0.z); o[3]=f2b(f0.w);
  o[4]=f2b(f1.x); o[5]=f2b(f1.y); o[6]=f2b(f1.z); o[7]=f2b(f1.w);
  *(uint4*)(xs + e) = *(const uint4*)o;
}

// ---------------- 1024x1024 transpose, f32 in -> bf16 out ----------------
__global__ __launch_bounds__(256) void k_tr(const float* __restrict__ src, u16* __restrict__ dst)
{
  int c0 = blockIdx.x*64, r0 = blockIdx.y*64;
  __shared__ u16 tile[64][72];
  int tid = threadIdx.x;
  int r = tid>>2, cc = (tid&3)*16;
  const float* sp = src + (size_t)(r0+r)*1024 + c0+cc;
  float4 a0 = *(const float4*)(sp);
  float4 a1 = *(const float4*)(sp+4);
  float4 a2 = *(const float4*)(sp+8);
  float4 a3 = *(const float4*)(sp+12);
  tile[r][cc+0]=f2b(a0.x); tile[r][cc+1]=f2b(a0.y); tile[r][cc+2]=f2b(a0.z); tile[r][cc+3]=f2b(a0.w);
  tile[r][cc+4]=f2b(a1.x); tile[r][cc+5]=f2b(a1.y); tile[r][cc+6]=f2b(a1.z); tile[r][cc+7]=f2b(a1.w);
  tile[r][cc+8]=f2b(a2.x); tile[r][cc+9]=f2b(a2.y); tile[r][cc+10]=f2b(a2.z); tile[r][cc+11]=f2b(a2.w);
  tile[r][cc+12]=f2b(a3.x); tile[r][cc+13]=f2b(a3.y); tile[r][cc+14]=f2b(a3.z); tile[r][cc+15]=f2b(a3.w);
  __syncthreads();
  int c = tid>>2, rr = (tid&3)*16;
  uint4 o0,o1; u16* p0=(u16*)&o0; u16* p1=(u16*)&o1;
  #pragma unroll
  for (int i=0;i<8;i++){ p0[i]=tile[rr+i][c]; p1[i]=tile[rr+8+i][c]; }
  *(uint4*)(dst + (size_t)(c0+c)*1024 + r0+rr)   = o0;
  *(uint4*)(dst + (size_t)(c0+c)*1024 + r0+rr+8) = o1;
}

// ---------------- v transpose: (bh,t,d) -> (bh,d,t), bf16 ----------------
__global__ __launch_bounds__(256) void k_vt(const u16* __restrict__ v, u16* __restrict__ vT)
{
  int bh = blockIdx.x, t0 = blockIdx.y*64;
  __shared__ u16 tile[64][72];
  const u16* src = v + (size_t)bh*65536;
  int tid = threadIdx.x;
  int r = tid>>2, c0 = (tid&3)*16;
  *(uint4*)&tile[r][c0]   = *(const uint4*)(src + (size_t)(t0+r)*64 + c0);
  *(uint4*)&tile[r][c0+8] = *(const uint4*)(src + (size_t)(t0+r)*64 + c0+8);
  __syncthreads();
  int d = tid>>2, tc0 = (tid&3)*16;
  uint4 o0,o1; u16* p0=(u16*)&o0; u16* p1=(u16*)&o1;
  #pragma unroll
  for (int i=0;i<8;i++){ p0[i]=tile[tc0+i][d]; p1[i]=tile[tc0+8+i][d]; }
  u16* dst = vT + (size_t)bh*65536 + (size_t)d*1024 + t0 + tc0;
  *(uint4*)(dst)   = o0;
  *(uint4*)(dst+8) = o1;
}

// ---------------- QKV GEMM + fused RoPE epilogue (plain bf16 q,k) ----------------
__global__ __launch_bounds__(256) void k_gemm_qkv(
    const u16* __restrict__ A, const u16* __restrict__ Bt,
    const float* __restrict__ bq, const float* __restrict__ bk, const float* __restrict__ bv,
    u16* __restrict__ qb, u16* __restrict__ kb, u16* __restrict__ v)
{
  __shared__ u16 As[128*40];
  __shared__ u16 Bs[128*40];
  const int n0 = blockIdx.x*128, m0 = blockIdx.y*128;
  const int tid = threadIdx.x, lane = tid&63, wave = tid>>6;
  const int quad = lane>>4, l16 = lane&15;
  const int wm = (wave>>1)*64, wn = (wave&1)*64;
  f32x4 zero = {0.f,0.f,0.f,0.f};
  f32x4 acc[4][4];
  #pragma unroll
  for (int i=0;i<4;i++)
    #pragma unroll
    for (int j=0;j<4;j++) acc[i][j] = zero;
  const int row = tid>>1, kk = (tid&1)*16;
  const u16* pa = A  + (size_t)(m0+row)*1024 + kk;
  const u16* pb = Bt + (size_t)(n0+row)*1024 + kk;
  for (int k0=0;k0<1024;k0+=32){
    __syncthreads();
    uint4 a0 = *(const uint4*)(pa); uint4 a1 = *(const uint4*)(pa+8);
    uint4 b0 = *(const uint4*)(pb); uint4 b1 = *(const uint4*)(pb+8);
    pa += 32; pb += 32;
    *(uint4*)&As[row*40+kk] = a0; *(uint4*)&As[row*40+kk+8] = a1;
    *(uint4*)&Bs[row*40+kk] = b0; *(uint4*)&Bs[row*40+kk+8] = b1;
    __syncthreads();
    bf16x8 af[4], bfr[4];
    #pragma unroll
    for (int mt=0;mt<4;mt++) af[mt]  = *(const bf16x8*)&As[(wm+mt*16+l16)*40 + quad*8];
    #pragma unroll
    for (int nt=0;nt<4;nt++) bfr[nt] = *(const bf16x8*)&Bs[(wn+nt*16+l16)*40 + quad*8];
    #pragma unroll
    for (int mt=0;mt<4;mt++)
      #pragma unroll
      for (int nt=0;nt<4;nt++)
        acc[mt][nt] = MFMA(af[mt], bfr[nt], acc[mt][nt]);
  }
  const int colbase = n0 + wn;          // 64-aligned -> which,h uniform per wave
  const int which = colbase>>10;
  const int nn0 = colbase & 1023;
  const int h = nn0>>6;
  const float* barr = (which==0)?bq:((which==1)?bk:bv);
  float bias[4];
  #pragma unroll
  for (int nt=0;nt<4;nt++) bias[nt] = barr[nn0 + nt*16 + l16];
  if (which == 2){
    #pragma unroll
    for (int mt=0;mt<4;mt++)
      #pragma unroll
      for (int r=0;r<4;r++){
        int m = m0 + wm + mt*16 + quad*4 + r;
        int bb = m>>10, t = m&1023;
        size_t ob = (((size_t)(bb*16+h))*1024 + (size_t)t)*64 + l16;
        #pragma unroll
        for (int nt=0;nt<4;nt++)
          v[ob + nt*16] = f2b(acc[mt][nt][r] + bias[nt]);
      }
  } else {
    const float scale = (which==0)?0.125f:1.0f;
    u16* dst = (which==0)? qb : kb;
    const float e = exp2f(-0.625f*(float)l16);
    #pragma unroll
    for (int mt=0;mt<4;mt++)
      #pragma unroll
      for (int r=0;r<4;r++){
        int m = m0 + wm + mt*16 + quad*4 + r;
        int bb = m>>10, t = m&1023;
        float f = (float)t * e;
        float cs = cosf(f), sn = sinf(f);
        float x0 = acc[mt][0][r] + bias[0];
        float x1 = acc[mt][1][r] + bias[1];
        float v0 = (x0*cs - x1*sn)*scale;
        float v1 = (x1*cs + x0*sn)*scale;
        float v2 = (acc[mt][2][r] + bias[2])*scale;
        float v3 = (acc[mt][3][r] + bias[3])*scale;
        size_t ob = (((size_t)(bb*16+h))*1024 + (size_t)t)*64 + l16;
        dst[ob]    = f2b(v0);
        dst[ob+16] = f2b(v1);
        dst[ob+32] = f2b(v2);
        dst[ob+48] = f2b(v3);
      }
  }
}

// ---------------- output GEMM: y[2048x1024] @ WoT^T + bo, x gamma[t], f32 out ----------------
__global__ __launch_bounds__(256) void k_gemm_out(
    const u16* __restrict__ A, const u16* __restrict__ Bt,
    const float* __restrict__ bo, const float* __restrict__ gamma, float* __restrict__ out)
{
  __shared__ u16 As[128*40];
  __shared__ u16 Bs[128*40];
  const int n0 = blockIdx.x*128, m0 = blockIdx.y*128;
  const int tid = threadIdx.x, lane = tid&63, wave = tid>>6;
  const int quad = lane>>4, l16 = lane&15;
  const int wm = (wave>>1)*64, wn = (wave&1)*64;
  f32x4 zero = {0.f,0.f,0.f,0.f};
  f32x4 acc[4][4];
  #pragma unroll
  for (int i=0;i<4;i++)
    #pragma unroll
    for (int j=0;j<4;j++) acc[i][j] = zero;
  const int row = tid>>1, kk = (tid&1)*16;
  const u16* pa = A  + (size_t)(m0+row)*1024 + kk;
  const u16* pb = Bt + (size_t)(n0+row)*1024 + kk;
  for (int k0=0;k0<1024;k0+=32){
    __syncthreads();
    uint4 a0 = *(const uint4*)(pa); uint4 a1 = *(const uint4*)(pa+8);
    uint4 b0 = *(const uint4*)(pb); uint4 b1 = *(const uint4*)(pb+8);
    pa += 32; pb += 32;
    *(uint4*)&As[row*40+kk] = a0; *(uint4*)&As[row*40+kk+8] = a1;
    *(uint4*)&Bs[row*40+kk] = b0; *(uint4*)&Bs[row*40+kk+8] = b1;
    __syncthreads();
    bf16x8 af[4], bfr[4];
    #pragma unroll
    for (int mt=0;mt<4;mt++) af[mt]  = *(const bf16x8*)&As[(wm+mt*16+l16)*40 + quad*8];
    #pragma unroll
    for (int nt=0;nt<4;nt++) bfr[nt] = *(const bf16x8*)&Bs[(wn+nt*16+l16)*40 + quad*8];
    #pragma unroll
    for (int mt=0;mt<4;mt++)
      #pragma unroll
      for (int nt=0;nt<4;nt++)
        acc[mt][nt] = MFMA(af[mt], bfr[nt], acc[mt][nt]);
  }
  #pragma unroll
  for (int mt=0;mt<4;mt++)
    #pragma unroll
    for (int nt=0;nt<4;nt++){
      int colg = n0 + wn + nt*16 + l16;
      float bias = bo[colg];
      #pragma unroll
      for (int r=0;r<4;r++){
        int m = m0 + wm + mt*16 + quad*4 + r;
        int t = m&1023;
        float val = (acc[mt][nt][r] + bias)*gamma[t];
        out[(size_t)m*1024 + colg] = val;
      }
    }
}

// ---------------- fused softmax+weight: S in registers, stats in LDS, write P ----------------
// block = (tb, h), 1024 threads = 16 waves = 4 wt x 4 ws; full 64t x 1024s S tile in regs
__global__ __launch_bounds__(1024) void k_sm(
    const u16* __restrict__ q, const u16* __restrict__ k,
    const float* __restrict__ tw, const float* __restrict__ alpha, const float* __restrict__ beta,
    u16* __restrict__ P, int b)
{
  const int tb = blockIdx.x, h = blockIdx.y;
  const int t0b = tb*64;
  const int tid = threadIdx.x;
  const int wave = tid>>6, lane = tid&63, quad = lane>>4, l16 = lane&15;
  const int wt = wave>>2, ws = wave&3;

  __shared__ u16 qs[64*76];      // q tile, padded rows
  __shared__ u16 ks[256*76];     // K chunk, padded rows
  __shared__ float tws[1024];
  __shared__ float als[1024];
  __shared__ float pm[4][64];
  __shared__ float pl[4][64];
  __shared__ float fm[64];
  __shared__ float fr[64];

  const size_t bh = (size_t)(b*16+h)*65536;
  const u16* qp = q + bh;
  const u16* kp = k + bh;

  if (tid < 512){
    int row = tid>>3, g = tid&7;
    *(uint4*)&qs[row*76 + g*8] = *(const uint4*)(qp + (size_t)(t0b+row)*64 + g*8);
  }
  tws[tid] = tw[h*1024 + tid];
  als[tid] = alpha[h*1024 + tid];
  __syncthreads();

  bf16x8 qf0 = *(const bf16x8*)&qs[(wt*16+l16)*76 + quad*8];
  bf16x8 qf1 = *(const bf16x8*)&qs[(wt*16+l16)*76 + quad*8 + 32];

  f32x4 acc[16];
  #pragma unroll
  for (int i=0;i<16;i++){ acc[i][0]=0.f; acc[i][1]=0.f; acc[i][2]=0.f; acc[i][3]=0.f; }

  #pragma unroll
  for (int c=0;c<4;c++){
    if (c) __syncthreads();
    {
      int row = tid>>3, g = tid&7;
      *(uint4*)&ks[row*76 + g*8]       = *(const uint4*)(kp + (size_t)(c*256+row)*64 + g*8);
      *(uint4*)&ks[(row+128)*76 + g*8] = *(const uint4*)(kp + (size_t)(c*256+row+128)*64 + g*8);
    }
    __syncthreads();
    #pragma unroll
    for (int j=0;j<4;j++){
      int lt = j*4 + ws;
      bf16x8 kf0 = *(const bf16x8*)&ks[(lt*16+l16)*76 + quad*8];
      bf16x8 kf1 = *(const bf16x8*)&ks[(lt*16+l16)*76 + quad*8 + 32];
      acc[c*4+j] = MFMA(qf0, kf0, acc[c*4+j]);
      acc[c*4+j] = MFMA(qf1, kf1, acc[c*4+j]);
    }
  }

  // per-wave partial stats over its 256 s-columns
  float mrow[4], lrow[4];
  #pragma unroll
  for (int r=0;r<4;r++){
    float m = acc[0][r];
    #pragma unroll
    for (int a=1;a<16;a++) m = fmaxf(m, acc[a][r]);
    #pragma unroll
    for (int off=1; off<16; off<<=1) m = fmaxf(m, __shfl_xor(m, off));
    float l = 0.f;
    #pragma unroll
    for (int a=0;a<16;a++) l += __expf(acc[a][r]-m);
    #pragma unroll
    for (int off=1; off<16; off<<=1) l += __shfl_xor(l, off);
    mrow[r]=m; lrow[r]=l;
  }
  if (l16==0){
    #pragma unroll
    for (int r=0;r<4;r++){
      pm[ws][wt*16+quad*4+r] = mrow[r];
      pl[ws][wt*16+quad*4+r] = lrow[r];
    }
  }
  __syncthreads();
  if (tid < 64){
    float m0s = pm[0][tid], m1s = pm[1][tid], m2s = pm[2][tid], m3s = pm[3][tid];
    float m = fmaxf(fmaxf(m0s,m1s), fmaxf(m2s,m3s));
    float l = pl[0][tid]*__expf(m0s-m) + pl[1][tid]*__expf(m1s-m)
            + pl[2][tid]*__expf(m2s-m) + pl[3][tid]*__expf(m3s-m);
    fm[tid] = m;
    fr[tid] = beta[h*1024 + t0b + tid] / l;
  }
  __syncthreads();

  u16* Pp = P + ((size_t)h<<20);
  float m_f[4], r_f[4]; int trow[4];
  #pragma unroll
  for (int r=0;r<4;r++){
    int rg = wt*16+quad*4+r;
    m_f[r] = fm[rg]; r_f[r] = fr[rg]; trow[r] = t0b + rg;
  }
  const int slim = tb*4 + wt;   // last s-tile with any s<=t
  #pragma unroll
  for (int c=0;c<4;c++)
    #pragma unroll
    for (int j=0;j<4;j++){
      int st = c*16 + j*4 + ws;
      if (st > slim) continue;
      int s = st*16 + l16;
      float av = als[s];
      #pragma unroll
      for (int r=0;r<4;r++){
        int t = trow[r];
        float p = 0.f;
        if (s <= t)
          p = __expf(acc[c*4+j][r]-m_f[r])*r_f[r]*tws[1023+s-t]*av;
        Pp[((size_t)t<<10) + s] = f2b(p);
      }
    }
}

// ---------------- head-mix: A[g][t][s] = sum_h Wmix[g][h] P[h][t][s] ----------------
__global__ __launch_bounds__(256) void k_mix(const u16* __restrict__ P, const float* __restrict__ Wm,
                                             u16* __restrict__ Ab)
{
  int tid = threadIdx.x;
  int t = blockIdx.x*4 + (tid>>6);
  int sb = blockIdx.y*256 + (tid&63)*4;
  int tmaxw = t|31, tmaxr = t|15;
  if ((int)(blockIdx.y*256) > tmaxw) return;
  __shared__ float Wl[16][16];
  Wl[tid>>4 & 15][tid&15] = Wm[tid & 255];
  __syncthreads();
  float a[16][4];
  #pragma unroll
  for (int g=0;g<16;g++){ a[g][0]=0.f; a[g][1]=0.f; a[g][2]=0.f; a[g][3]=0.f; }
  #pragma unroll
  for (int h=0;h<16;h++){
    float p0=0.f,p1=0.f,p2=0.f,p3=0.f;
    if (sb <= tmaxr){
      ushort4 u = *(const ushort4*)(P + (((size_t)h)<<20) + (((size_t)t)<<10) + sb);
      p0=b2f(u.x); p1=b2f(u.y); p2=b2f(u.z); p3=b2f(u.w);
    }
    #pragma unroll
    for (int g=0;g<16;g++){
      float w = Wl[g][h];
      a[g][0]+=w*p0; a[g][1]+=w*p1; a[g][2]+=w*p2; a[g][3]+=w*p3;
    }
  }
  if (sb <= tmaxw){
    #pragma unroll
    for (int g=0;g<16;g++){
      ushort4 o; o.x=f2b(a[g][0]); o.y=f2b(a[g][1]); o.z=f2b(a[g][2]); o.w=f2b(a[g][3]);
      *(ushort4*)(Ab + (((size_t)g)<<20) + (((size_t)t)<<10) + sb) = o;
    }
  }
}

// ---------------- PV: block per (g,tt); wave per 16-d slab ----------------
__global__ __launch_bounds__(256) void k_pv(const u16* __restrict__ Ab, const u16* __restrict__ vT,
                                            u16* __restrict__ y, int b)
{
  int bx = blockIdx.x;                       // 1024 = g*64 + tt
  int g = bx>>6, tt = bx&63;
  int tid = threadIdx.x, dt = tid>>6, lane = tid&63, quad = lane>>4, l16 = lane&15;
  int t0 = tt*16;
  const u16* ap = Ab + ((size_t)g<<20);
  const u16* vp = vT + (size_t)(b*16+g)*65536;   // [d][s]
  f32x4 acc = {0.f,0.f,0.f,0.f};
  int nst = t0/32 + 1;
  const u16* arow = ap + (((size_t)(t0+l16))<<10) + quad*8;
  const u16* vrow = vp + (size_t)(dt*16+l16)*1024 + quad*8;
  for (int st=0; st<nst; st++){
    bf16x8 af  = *(const bf16x8*)(arow + st*32);
    bf16x8 bfv = *(const bf16x8*)(vrow + st*32);
    acc = MFMA(af, bfv, acc);
  }
  #pragma unroll
  for (int r=0;r<4;r++){
    int t = t0 + quad*4 + r;
    y[(size_t)(b*1024+t)*1024 + g*64 + dt*16 + l16] = f2b(acc[r]);
  }
}

__global__ void k_fail(float* out){ if (threadIdx.x==0) out[0] = 1e30f; } // ws-too-small marker

extern "C" void kernel_launch(void* const* d_in, const int* in_sizes, int n_in,
                              void* d_out, int out_size, void* d_ws, size_t ws_size,
                              hipStream_t stream)
{
  const float* x     = (const float*)d_in[0];
  const float* tw    = (const float*)d_in[1];
  const float* alpha = (const float*)d_in[2];
  const float* beta  = (const float*)d_in[3];
  const float* gamma = (const float*)d_in[4];
  const float* Wq    = (const float*)d_in[5];
  const float* bq    = (const float*)d_in[6];
  const float* Wk    = (const float*)d_in[7];
  const float* bk    = (const float*)d_in[8];
  const float* Wv    = (const float*)d_in[9];
  const float* bv    = (const float*)d_in[10];
  const float* Wmix  = (const float*)d_in[11];
  const float* Wo    = (const float*)d_in[12];
  const float* bo    = (const float*)d_in[13];
  float* out = (float*)d_out;

  char* ws = (char*)d_ws;
  size_t off = 0;
  auto take = [&](size_t bytes)->char*{
    char* p = ws + off; off += (bytes + 255) & ~(size_t)255; return p;
  };
  u16*   xs  = (u16*)take((size_t)2097152*2);   // xs (B*T, C) bf16
  u16*   WT  = (u16*)take((size_t)3145728*2);   // [3072][1024] = Wq^T|Wk^T|Wv^T bf16
  u16*   WoT = (u16*)take((size_t)1048576*2);
  u16*   qb  = (u16*)take((size_t)2097152*2);   // (b,h,t,d) rope'd, x1/8
  u16*   kb  = (u16*)take((size_t)2097152*2);   // (b,h,t,d) rope'd
  u16*   v   = (u16*)take((size_t)2097152*2);
  u16*   vTb = (u16*)take((size_t)2097152*2);   // (b,h,d,t)
  u16*   yb  = (u16*)take((size_t)2097152*2);   // (b,t,g,d)
  u16*   P   = (u16*)take((size_t)16777216*2);  // per-batch [h][t][s]
  u16*   A   = (u16*)take((size_t)16777216*2);  // per-batch [g][t][s]
  if (off > ws_size){
    hipLaunchKernelGGL(k_fail, dim3(1), dim3(64), 0, stream, out);
    return;
  }

  hipLaunchKernelGGL(k_prep, dim3(1024), dim3(256), 0, stream, x, xs);
  hipLaunchKernelGGL(k_tr, dim3(16,16), dim3(256), 0, stream, Wq, WT);
  hipLaunchKernelGGL(k_tr, dim3(16,16), dim3(256), 0, stream, Wk, WT + 1048576);
  hipLaunchKernelGGL(k_tr, dim3(16,16), dim3(256), 0, stream, Wv, WT + 2097152);
  hipLaunchKernelGGL(k_tr, dim3(16,16), dim3(256), 0, stream, Wo, WoT);
  hipLaunchKernelGGL(k_gemm_qkv, dim3(24,16), dim3(256), 0, stream,
                     xs, WT, bq, bk, bv, qb, kb, v);
  hipLaunchKernelGGL(k_vt, dim3(32,16), dim3(256), 0, stream, v, vTb);
  for (int b=0;b<2;b++){
    hipLaunchKernelGGL(k_sm, dim3(16,16), dim3(1024), 0, stream,
                       qb, kb, tw, alpha, beta, P, b);
    hipLaunchKernelGGL(k_mix, dim3(256,4), dim3(256), 0, stream, P, Wmix, A);
    hipLaunchKernelGGL(k_pv, dim3(1024), dim3(256), 0, stream, A, vTb, yb, b);
  }
  hipLaunchKernelGGL(k_gemm_out, dim3(8,16), dim3(256), 0, stream, yb, WoT, bo, gamma, out);
}

// Round 5
// 283.062 us; speedup vs baseline: 1.5538x; 1.0937x over previous
//
#include <hip/hip_runtime.h>

typedef unsigned short u16;
typedef __attribute__((ext_vector_type(8))) short bf16x8;
typedef __attribute__((ext_vector_type(4))) float f32x4;

#define MFMA(a,b,c) __builtin_amdgcn_mfma_f32_16x16x32_bf16(a,b,c,0,0,0)

__device__ __forceinline__ float b2f(u16 u){
  union { unsigned int i; float f; } v; v.i = ((unsigned int)u)<<16; return v.f;
}
__device__ __forceinline__ u16 f2b(float f){
  union { float f; unsigned int i; } v; v.f = f;
  unsigned int r = (v.i + 0x7FFFu + ((v.i>>16)&1u))>>16;
  return (u16)r;
}

// ---------------- combined: time-shift prep (blocks 0..1023) + 4 weight transposes ----------------
__global__ __launch_bounds__(256) void k_pre(
    const float* __restrict__ x,
    const float* __restrict__ Wq, const float* __restrict__ Wk,
    const float* __restrict__ Wv, const float* __restrict__ Wo,
    u16* __restrict__ xs, u16* __restrict__ WT, u16* __restrict__ WoT)
{
  int bid = blockIdx.x;
  int tid = threadIdx.x;
  if (bid < 1024){
    int idx = bid*256 + tid;                 // one thread per 8 elements
    size_t e = (size_t)idx*8;
    int c = (int)(e & 1023);
    int t = (int)((e>>10)&1023);
    float4 f0 = {0.f,0.f,0.f,0.f}, f1 = {0.f,0.f,0.f,0.f};
    const float* src = nullptr;
    if (c < 512){ if (t > 0) src = x + e - 1024; }
    else        { src = x + e; }
    if (src){ f0 = *(const float4*)src; f1 = *(const float4*)(src+4); }
    u16 o[8];
    o[0]=f2b(f0.x); o[1]=f2b(f0.y); o[2]=f2b(f0.z); o[3]=f2b(f0.w);
    o[4]=f2b(f1.x); o[5]=f2b(f1.y); o[6]=f2b(f1.z); o[7]=f2b(f1.w);
    *(uint4*)(xs + e) = *(const uint4*)o;
    return;
  }
  int z  = (bid-1024)>>8;                    // 0..3 : Wq,Wk,Wv,Wo
  int rc = (bid-1024)&255;
  const float* src = (z==0)?Wq:((z==1)?Wk:((z==2)?Wv:Wo));
  u16* dst = (z==3)? WoT : (WT + (size_t)z*1048576);
  int c0 = (rc&15)*64, r0 = (rc>>4)*64;
  __shared__ u16 tile[64][72];
  int r = tid>>2, cc = (tid&3)*16;
  const float* sp = src + (size_t)(r0+r)*1024 + c0+cc;
  float4 a0 = *(const float4*)(sp);
  float4 a1 = *(const float4*)(sp+4);
  float4 a2 = *(const float4*)(sp+8);
  float4 a3 = *(const float4*)(sp+12);
  tile[r][cc+0]=f2b(a0.x); tile[r][cc+1]=f2b(a0.y); tile[r][cc+2]=f2b(a0.z); tile[r][cc+3]=f2b(a0.w);
  tile[r][cc+4]=f2b(a1.x); tile[r][cc+5]=f2b(a1.y); tile[r][cc+6]=f2b(a1.z); tile[r][cc+7]=f2b(a1.w);
  tile[r][cc+8]=f2b(a2.x); tile[r][cc+9]=f2b(a2.y); tile[r][cc+10]=f2b(a2.z); tile[r][cc+11]=f2b(a2.w);
  tile[r][cc+12]=f2b(a3.x); tile[r][cc+13]=f2b(a3.y); tile[r][cc+14]=f2b(a3.z); tile[r][cc+15]=f2b(a3.w);
  __syncthreads();
  int c = tid>>2, rr = (tid&3)*16;
  uint4 o0,o1; u16* p0=(u16*)&o0; u16* p1=(u16*)&o1;
  #pragma unroll
  for (int i=0;i<8;i++){ p0[i]=tile[rr+i][c]; p1[i]=tile[rr+8+i][c]; }
  *(uint4*)(dst + (size_t)(c0+c)*1024 + r0+rr)   = o0;
  *(uint4*)(dst + (size_t)(c0+c)*1024 + r0+rr+8) = o1;
}

// ---------------- QKV GEMM + fused RoPE; v written transposed (b,h,d,t) ----------------
__global__ __launch_bounds__(256) void k_gemm_qkv(
    const u16* __restrict__ A, const u16* __restrict__ Bt,
    const float* __restrict__ bq, const float* __restrict__ bk, const float* __restrict__ bv,
    u16* __restrict__ qb, u16* __restrict__ kb, u16* __restrict__ vT)
{
  __shared__ u16 As[128*40];
  __shared__ u16 Bs[128*40];
  const int n0 = blockIdx.x*128, m0 = blockIdx.y*128;
  const int tid = threadIdx.x, lane = tid&63, wave = tid>>6;
  const int quad = lane>>4, l16 = lane&15;
  const int wm = (wave>>1)*64, wn = (wave&1)*64;
  f32x4 zero = {0.f,0.f,0.f,0.f};
  f32x4 acc[4][4];
  #pragma unroll
  for (int i=0;i<4;i++)
    #pragma unroll
    for (int j=0;j<4;j++) acc[i][j] = zero;
  const int row = tid>>1, kk = (tid&1)*16;
  const u16* pa = A  + (size_t)(m0+row)*1024 + kk;
  const u16* pb = Bt + (size_t)(n0+row)*1024 + kk;
  for (int k0=0;k0<1024;k0+=32){
    __syncthreads();
    uint4 a0 = *(const uint4*)(pa); uint4 a1 = *(const uint4*)(pa+8);
    uint4 b0 = *(const uint4*)(pb); uint4 b1 = *(const uint4*)(pb+8);
    pa += 32; pb += 32;
    *(uint4*)&As[row*40+kk] = a0; *(uint4*)&As[row*40+kk+8] = a1;
    *(uint4*)&Bs[row*40+kk] = b0; *(uint4*)&Bs[row*40+kk+8] = b1;
    __syncthreads();
    bf16x8 af[4], bfr[4];
    #pragma unroll
    for (int mt=0;mt<4;mt++) af[mt]  = *(const bf16x8*)&As[(wm+mt*16+l16)*40 + quad*8];
    #pragma unroll
    for (int nt=0;nt<4;nt++) bfr[nt] = *(const bf16x8*)&Bs[(wn+nt*16+l16)*40 + quad*8];
    #pragma unroll
    for (int mt=0;mt<4;mt++)
      #pragma unroll
      for (int nt=0;nt<4;nt++)
        acc[mt][nt] = MFMA(af[mt], bfr[nt], acc[mt][nt]);
  }
  const int colbase = n0 + wn;          // 64-aligned -> which,h uniform per wave
  const int which = colbase>>10;
  const int nn0 = colbase & 1023;
  const int h = nn0>>6;
  const float* barr = (which==0)?bq:((which==1)?bk:bv);
  float bias[4];
  #pragma unroll
  for (int nt=0;nt<4;nt++) bias[nt] = barr[nn0 + nt*16 + l16];
  if (which == 2){
    // v: write transposed (b,h,d,t): vT[bh*65536 + d*1024 + t]
    #pragma unroll
    for (int mt=0;mt<4;mt++)
      #pragma unroll
      for (int r=0;r<4;r++){
        int m = m0 + wm + mt*16 + quad*4 + r;
        int bb = m>>10, t = m&1023;
        size_t base = (size_t)(bb*16+h)*65536 + t;
        #pragma unroll
        for (int nt=0;nt<4;nt++){
          int d = nt*16 + l16;
          vT[base + (size_t)d*1024] = f2b(acc[mt][nt][r] + bias[nt]);
        }
      }
  } else {
    const float scale = (which==0)?0.125f:1.0f;
    u16* dst = (which==0)? qb : kb;
    const float e = exp2f(-0.625f*(float)l16);
    #pragma unroll
    for (int mt=0;mt<4;mt++)
      #pragma unroll
      for (int r=0;r<4;r++){
        int m = m0 + wm + mt*16 + quad*4 + r;
        int bb = m>>10, t = m&1023;
        float f = (float)t * e;
        float cs = cosf(f), sn = sinf(f);
        float x0 = acc[mt][0][r] + bias[0];
        float x1 = acc[mt][1][r] + bias[1];
        float v0 = (x0*cs - x1*sn)*scale;
        float v1 = (x1*cs + x0*sn)*scale;
        float v2 = (acc[mt][2][r] + bias[2])*scale;
        float v3 = (acc[mt][3][r] + bias[3])*scale;
        size_t ob = (((size_t)(bb*16+h))*1024 + (size_t)t)*64 + l16;
        dst[ob]    = f2b(v0);
        dst[ob+16] = f2b(v1);
        dst[ob+32] = f2b(v2);
        dst[ob+48] = f2b(v3);
      }
  }
}

// ---------------- output GEMM: y[2048x1024] @ WoT^T + bo, x gamma[t], f32 out ----------------
__global__ __launch_bounds__(256) void k_gemm_out(
    const u16* __restrict__ A, const u16* __restrict__ Bt,
    const float* __restrict__ bo, const float* __restrict__ gamma, float* __restrict__ out)
{
  __shared__ u16 As[128*40];
  __shared__ u16 Bs[128*40];
  const int n0 = blockIdx.x*128, m0 = blockIdx.y*128;
  const int tid = threadIdx.x, lane = tid&63, wave = tid>>6;
  const int quad = lane>>4, l16 = lane&15;
  const int wm = (wave>>1)*64, wn = (wave&1)*64;
  f32x4 zero = {0.f,0.f,0.f,0.f};
  f32x4 acc[4][4];
  #pragma unroll
  for (int i=0;i<4;i++)
    #pragma unroll
    for (int j=0;j<4;j++) acc[i][j] = zero;
  const int row = tid>>1, kk = (tid&1)*16;
  const u16* pa = A  + (size_t)(m0+row)*1024 + kk;
  const u16* pb = Bt + (size_t)(n0+row)*1024 + kk;
  for (int k0=0;k0<1024;k0+=32){
    __syncthreads();
    uint4 a0 = *(const uint4*)(pa); uint4 a1 = *(const uint4*)(pa+8);
    uint4 b0 = *(const uint4*)(pb); uint4 b1 = *(const uint4*)(pb+8);
    pa += 32; pb += 32;
    *(uint4*)&As[row*40+kk] = a0; *(uint4*)&As[row*40+kk+8] = a1;
    *(uint4*)&Bs[row*40+kk] = b0; *(uint4*)&Bs[row*40+kk+8] = b1;
    __syncthreads();
    bf16x8 af[4], bfr[4];
    #pragma unroll
    for (int mt=0;mt<4;mt++) af[mt]  = *(const bf16x8*)&As[(wm+mt*16+l16)*40 + quad*8];
    #pragma unroll
    for (int nt=0;nt<4;nt++) bfr[nt] = *(const bf16x8*)&Bs[(wn+nt*16+l16)*40 + quad*8];
    #pragma unroll
    for (int mt=0;mt<4;mt++)
      #pragma unroll
      for (int nt=0;nt<4;nt++)
        acc[mt][nt] = MFMA(af[mt], bfr[nt], acc[mt][nt]);
  }
  #pragma unroll
  for (int mt=0;mt<4;mt++)
    #pragma unroll
    for (int nt=0;nt<4;nt++){
      int colg = n0 + wn + nt*16 + l16;
      float bias = bo[colg];
      #pragma unroll
      for (int r=0;r<4;r++){
        int m = m0 + wm + mt*16 + quad*4 + r;
        int t = m&1023;
        float val = (acc[mt][nt][r] + bias)*gamma[t];
        out[(size_t)m*1024 + colg] = val;
      }
    }
}

// ---------------- fused softmax+weight: S in registers, stats in LDS, write P ----------------
// grid (tb=16, h=16, b=2); 1024 threads = 16 waves = 4 wt x 4 ws; full 64t x 1024s S tile in regs
__global__ __launch_bounds__(1024) void k_sm(
    const u16* __restrict__ q, const u16* __restrict__ k,
    const float* __restrict__ tw, const float* __restrict__ alpha, const float* __restrict__ beta,
    u16* __restrict__ P)
{
  const int tb = blockIdx.x, h = blockIdx.y, b = blockIdx.z;
  const int t0b = tb*64;
  const int tid = threadIdx.x;
  const int wave = tid>>6, lane = tid&63, quad = lane>>4, l16 = lane&15;
  const int wt = wave>>2, ws = wave&3;

  __shared__ u16 qs[64*76];      // q tile, padded rows
  __shared__ u16 ks[256*76];     // K chunk, padded rows
  __shared__ float tws[1024];
  __shared__ float als[1024];
  __shared__ float pm[4][64];
  __shared__ float pl[4][64];
  __shared__ float fm[64];
  __shared__ float fr[64];

  const size_t bh = (size_t)(b*16+h)*65536;
  const u16* qp = q + bh;
  const u16* kp = k + bh;

  if (tid < 512){
    int row = tid>>3, g = tid&7;
    *(uint4*)&qs[row*76 + g*8] = *(const uint4*)(qp + (size_t)(t0b+row)*64 + g*8);
  }
  tws[tid] = tw[h*1024 + tid];
  als[tid] = alpha[h*1024 + tid];
  __syncthreads();

  bf16x8 qf0 = *(const bf16x8*)&qs[(wt*16+l16)*76 + quad*8];
  bf16x8 qf1 = *(const bf16x8*)&qs[(wt*16+l16)*76 + quad*8 + 32];

  f32x4 acc[16];
  #pragma unroll
  for (int i=0;i<16;i++){ acc[i][0]=0.f; acc[i][1]=0.f; acc[i][2]=0.f; acc[i][3]=0.f; }

  #pragma unroll
  for (int c=0;c<4;c++){
    if (c) __syncthreads();
    {
      int row = tid>>3, g = tid&7;
      *(uint4*)&ks[row*76 + g*8]       = *(const uint4*)(kp + (size_t)(c*256+row)*64 + g*8);
      *(uint4*)&ks[(row+128)*76 + g*8] = *(const uint4*)(kp + (size_t)(c*256+row+128)*64 + g*8);
    }
    __syncthreads();
    #pragma unroll
    for (int j=0;j<4;j++){
      int lt = j*4 + ws;
      bf16x8 kf0 = *(const bf16x8*)&ks[(lt*16+l16)*76 + quad*8];
      bf16x8 kf1 = *(const bf16x8*)&ks[(lt*16+l16)*76 + quad*8 + 32];
      acc[c*4+j] = MFMA(qf0, kf0, acc[c*4+j]);
      acc[c*4+j] = MFMA(qf1, kf1, acc[c*4+j]);
    }
  }

  // per-wave partial stats over its 256 s-columns
  float mrow[4], lrow[4];
  #pragma unroll
  for (int r=0;r<4;r++){
    float m = acc[0][r];
    #pragma unroll
    for (int a=1;a<16;a++) m = fmaxf(m, acc[a][r]);
    #pragma unroll
    for (int off=1; off<16; off<<=1) m = fmaxf(m, __shfl_xor(m, off));
    float l = 0.f;
    #pragma unroll
    for (int a=0;a<16;a++) l += __expf(acc[a][r]-m);
    #pragma unroll
    for (int off=1; off<16; off<<=1) l += __shfl_xor(l, off);
    mrow[r]=m; lrow[r]=l;
  }
  if (l16==0){
    #pragma unroll
    for (int r=0;r<4;r++){
      pm[ws][wt*16+quad*4+r] = mrow[r];
      pl[ws][wt*16+quad*4+r] = lrow[r];
    }
  }
  __syncthreads();
  if (tid < 64){
    float m0s = pm[0][tid], m1s = pm[1][tid], m2s = pm[2][tid], m3s = pm[3][tid];
    float m = fmaxf(fmaxf(m0s,m1s), fmaxf(m2s,m3s));
    float l = pl[0][tid]*__expf(m0s-m) + pl[1][tid]*__expf(m1s-m)
            + pl[2][tid]*__expf(m2s-m) + pl[3][tid]*__expf(m3s-m);
    fm[tid] = m;
    fr[tid] = beta[h*1024 + t0b + tid] / l;
  }
  __syncthreads();

  u16* Pp = P + ((size_t)(b*16+h)<<20);
  float m_f[4], r_f[4]; int trow[4];
  #pragma unroll
  for (int r=0;r<4;r++){
    int rg = wt*16+quad*4+r;
    m_f[r] = fm[rg]; r_f[r] = fr[rg]; trow[r] = t0b + rg;
  }
  const int slim = tb*4 + wt;   // last s-tile with any s<=t
  #pragma unroll
  for (int c=0;c<4;c++)
    #pragma unroll
    for (int j=0;j<4;j++){
      int st = c*16 + j*4 + ws;
      if (st > slim) continue;
      int s = st*16 + l16;
      float av = als[s];
      #pragma unroll
      for (int r=0;r<4;r++){
        int t = trow[r];
        float p = 0.f;
        if (s <= t)
          p = __expf(acc[c*4+j][r]-m_f[r])*r_f[r]*tws[1023+s-t]*av;
        Pp[((size_t)t<<10) + s] = f2b(p);
      }
    }
}

// ---------------- head-mix: A[b][g][t][s] = sum_h Wmix[g][h] P[b][h][t][s] ----------------
// grid (256 t-blocks, 4 s-chunks, 2 b)
__global__ __launch_bounds__(256) void k_mix(const u16* __restrict__ P, const float* __restrict__ Wm,
                                             u16* __restrict__ Ab)
{
  int tid = threadIdx.x;
  int b = blockIdx.z;
  int t = blockIdx.x*4 + (tid>>6);
  int sb = blockIdx.y*256 + (tid&63)*4;
  int tmaxw = t|31, tmaxr = t|15;
  if ((int)(blockIdx.y*256) > tmaxw) return;
  __shared__ float Wl[16][16];
  Wl[tid>>4 & 15][tid&15] = Wm[tid & 255];
  __syncthreads();
  const u16* Pb = P  + ((size_t)(b*16)<<20);
  u16* Abb      = Ab + ((size_t)(b*16)<<20);
  float a[16][4];
  #pragma unroll
  for (int g=0;g<16;g++){ a[g][0]=0.f; a[g][1]=0.f; a[g][2]=0.f; a[g][3]=0.f; }
  #pragma unroll
  for (int h=0;h<16;h++){
    float p0=0.f,p1=0.f,p2=0.f,p3=0.f;
    if (sb <= tmaxr){
      ushort4 u = *(const ushort4*)(Pb + (((size_t)h)<<20) + (((size_t)t)<<10) + sb);
      p0=b2f(u.x); p1=b2f(u.y); p2=b2f(u.z); p3=b2f(u.w);
    }
    #pragma unroll
    for (int g=0;g<16;g++){
      float w = Wl[g][h];
      a[g][0]+=w*p0; a[g][1]+=w*p1; a[g][2]+=w*p2; a[g][3]+=w*p3;
    }
  }
  if (sb <= tmaxw){
    #pragma unroll
    for (int g=0;g<16;g++){
      ushort4 o; o.x=f2b(a[g][0]); o.y=f2b(a[g][1]); o.z=f2b(a[g][2]); o.w=f2b(a[g][3]);
      *(ushort4*)(Abb + (((size_t)g)<<20) + (((size_t)t)<<10) + sb) = o;
    }
  }
}

// ---------------- PV: grid (1024 = g*64+tt, 2 b); wave per 16-d slab ----------------
__global__ __launch_bounds__(256) void k_pv(const u16* __restrict__ Ab, const u16* __restrict__ vT,
                                            u16* __restrict__ y)
{
  int bx = blockIdx.x;                       // 1024 = g*64 + tt
  int b = blockIdx.y;
  int g = bx>>6, tt = bx&63;
  int tid = threadIdx.x, dt = tid>>6, lane = tid&63, quad = lane>>4, l16 = lane&15;
  int t0 = tt*16;
  const u16* ap = Ab + ((size_t)(b*16+g)<<20);
  const u16* vp = vT + (size_t)(b*16+g)*65536;   // [d][t]
  f32x4 acc = {0.f,0.f,0.f,0.f};
  int nst = t0/32 + 1;
  const u16* arow = ap + (((size_t)(t0+l16))<<10) + quad*8;
  const u16* vrow = vp + (size_t)(dt*16+l16)*1024 + quad*8;
  for (int st=0; st<nst; st++){
    bf16x8 af  = *(const bf16x8*)(arow + st*32);
    bf16x8 bfv = *(const bf16x8*)(vrow + st*32);
    acc = MFMA(af, bfv, acc);
  }
  #pragma unroll
  for (int r=0;r<4;r++){
    int t = t0 + quad*4 + r;
    y[(size_t)(b*1024+t)*1024 + g*64 + dt*16 + l16] = f2b(acc[r]);
  }
}

__global__ void k_fail(float* out){ if (threadIdx.x==0) out[0] = 1e30f; } // ws-too-small marker

extern "C" void kernel_launch(void* const* d_in, const int* in_sizes, int n_in,
                              void* d_out, int out_size, void* d_ws, size_t ws_size,
                              hipStream_t stream)
{
  const float* x     = (const float*)d_in[0];
  const float* tw    = (const float*)d_in[1];
  const float* alpha = (const float*)d_in[2];
  const float* beta  = (const float*)d_in[3];
  const float* gamma = (const float*)d_in[4];
  const float* Wq    = (const float*)d_in[5];
  const float* bq    = (const float*)d_in[6];
  const float* Wk    = (const float*)d_in[7];
  const float* bk    = (const float*)d_in[8];
  const float* Wv    = (const float*)d_in[9];
  const float* bv    = (const float*)d_in[10];
  const float* Wmix  = (const float*)d_in[11];
  const float* Wo    = (const float*)d_in[12];
  const float* bo    = (const float*)d_in[13];
  float* out = (float*)d_out;

  char* ws = (char*)d_ws;
  size_t off = 0;
  auto take = [&](size_t bytes)->char*{
    char* p = ws + off; off += (bytes + 255) & ~(size_t)255; return p;
  };
  u16*   xs  = (u16*)take((size_t)2097152*2);   // xs (B*T, C) bf16
  u16*   WT  = (u16*)take((size_t)3145728*2);   // [3072][1024] = Wq^T|Wk^T|Wv^T bf16
  u16*   WoT = (u16*)take((size_t)1048576*2);
  u16*   qb  = (u16*)take((size_t)2097152*2);   // (b,h,t,d) rope'd, x1/8
  u16*   kb  = (u16*)take((size_t)2097152*2);   // (b,h,t,d) rope'd
  u16*   vTb = (u16*)take((size_t)2097152*2);   // (b,h,d,t)
  u16*   yb  = (u16*)take((size_t)2097152*2);   // (b,t,g,d)
  u16*   P   = (u16*)take((size_t)33554432*2);  // [b][h][t][s]
  u16*   A   = (u16*)take((size_t)33554432*2);  // [b][g][t][s]
  if (off > ws_size){
    hipLaunchKernelGGL(k_fail, dim3(1), dim3(64), 0, stream, out);
    return;
  }

  hipLaunchKernelGGL(k_pre, dim3(2048), dim3(256), 0, stream,
                     x, Wq, Wk, Wv, Wo, xs, WT, WoT);
  hipLaunchKernelGGL(k_gemm_qkv, dim3(24,16), dim3(256), 0, stream,
                     xs, WT, bq, bk, bv, qb, kb, vTb);
  hipLaunchKernelGGL(k_sm, dim3(16,16,2), dim3(1024), 0, stream,
                     qb, kb, tw, alpha, beta, P);
  hipLaunchKernelGGL(k_mix, dim3(256,4,2), dim3(256), 0, stream, P, Wmix, A);
  hipLaunchKernelGGL(k_pv, dim3(1024,2), dim3(256), 0, stream, A, vTb, yb);
  hipLaunchKernelGGL(k_gemm_out, dim3(8,16), dim3(256), 0, stream, yb, WoT, bo, gamma, out);
}

// Round 6
// 243.074 us; speedup vs baseline: 1.8094x; 1.1645x over previous
//
#include <hip/hip_runtime.h>

typedef unsigned short u16;
typedef __attribute__((ext_vector_type(8))) short bf16x8;
typedef __attribute__((ext_vector_type(4))) float f32x4;

#define MFMA(a,b,c) __builtin_amdgcn_mfma_f32_16x16x32_bf16(a,b,c,0,0,0)

__device__ __forceinline__ float b2f(u16 u){
  union { unsigned int i; float f; } v; v.i = ((unsigned int)u)<<16; return v.f;
}
__device__ __forceinline__ u16 f2b(float f){
  union { float f; unsigned int i; } v; v.f = f;
  unsigned int r = (v.i + 0x7FFFu + ((v.i>>16)&1u))>>16;
  return (u16)r;
}

// ---------------- combined: time-shift prep (blocks 0..1023) + 4 weight transposes ----------------
__global__ __launch_bounds__(256) void k_pre(
    const float* __restrict__ x,
    const float* __restrict__ Wq, const float* __restrict__ Wk,
    const float* __restrict__ Wv, const float* __restrict__ Wo,
    u16* __restrict__ xs, u16* __restrict__ WT, u16* __restrict__ WoT)
{
  int bid = blockIdx.x;
  int tid = threadIdx.x;
  if (bid < 1024){
    int idx = bid*256 + tid;                 // one thread per 8 elements
    size_t e = (size_t)idx*8;
    int c = (int)(e & 1023);
    int t = (int)((e>>10)&1023);
    float4 f0 = {0.f,0.f,0.f,0.f}, f1 = {0.f,0.f,0.f,0.f};
    const float* src = nullptr;
    if (c < 512){ if (t > 0) src = x + e - 1024; }
    else        { src = x + e; }
    if (src){ f0 = *(const float4*)src; f1 = *(const float4*)(src+4); }
    u16 o[8];
    o[0]=f2b(f0.x); o[1]=f2b(f0.y); o[2]=f2b(f0.z); o[3]=f2b(f0.w);
    o[4]=f2b(f1.x); o[5]=f2b(f1.y); o[6]=f2b(f1.z); o[7]=f2b(f1.w);
    *(uint4*)(xs + e) = *(const uint4*)o;
    return;
  }
  int z  = (bid-1024)>>8;                    // 0..3 : Wq,Wk,Wv,Wo
  int rc = (bid-1024)&255;
  const float* src = (z==0)?Wq:((z==1)?Wk:((z==2)?Wv:Wo));
  u16* dst = (z==3)? WoT : (WT + (size_t)z*1048576);
  int c0 = (rc&15)*64, r0 = (rc>>4)*64;
  __shared__ u16 tile[64][72];
  int r = tid>>2, cc = (tid&3)*16;
  const float* sp = src + (size_t)(r0+r)*1024 + c0+cc;
  float4 a0 = *(const float4*)(sp);
  float4 a1 = *(const float4*)(sp+4);
  float4 a2 = *(const float4*)(sp+8);
  float4 a3 = *(const float4*)(sp+12);
  tile[r][cc+0]=f2b(a0.x); tile[r][cc+1]=f2b(a0.y); tile[r][cc+2]=f2b(a0.z); tile[r][cc+3]=f2b(a0.w);
  tile[r][cc+4]=f2b(a1.x); tile[r][cc+5]=f2b(a1.y); tile[r][cc+6]=f2b(a1.z); tile[r][cc+7]=f2b(a1.w);
  tile[r][cc+8]=f2b(a2.x); tile[r][cc+9]=f2b(a2.y); tile[r][cc+10]=f2b(a2.z); tile[r][cc+11]=f2b(a2.w);
  tile[r][cc+12]=f2b(a3.x); tile[r][cc+13]=f2b(a3.y); tile[r][cc+14]=f2b(a3.z); tile[r][cc+15]=f2b(a3.w);
  __syncthreads();
  int c = tid>>2, rr = (tid&3)*16;
  uint4 o0,o1; u16* p0=(u16*)&o0; u16* p1=(u16*)&o1;
  #pragma unroll
  for (int i=0;i<8;i++){ p0[i]=tile[rr+i][c]; p1[i]=tile[rr+8+i][c]; }
  *(uint4*)(dst + (size_t)(c0+c)*1024 + r0+rr)   = o0;
  *(uint4*)(dst + (size_t)(c0+c)*1024 + r0+rr+8) = o1;
}

// ---------------- QKV GEMM + fused RoPE; v written transposed (b,h,d,t) ----------------
__global__ __launch_bounds__(256) void k_gemm_qkv(
    const u16* __restrict__ A, const u16* __restrict__ Bt,
    const float* __restrict__ bq, const float* __restrict__ bk, const float* __restrict__ bv,
    u16* __restrict__ qb, u16* __restrict__ kb, u16* __restrict__ vT)
{
  __shared__ u16 As[128*40];
  __shared__ u16 Bs[128*40];
  const int n0 = blockIdx.x*128, m0 = blockIdx.y*128;
  const int tid = threadIdx.x, lane = tid&63, wave = tid>>6;
  const int quad = lane>>4, l16 = lane&15;
  const int wm = (wave>>1)*64, wn = (wave&1)*64;
  f32x4 zero = {0.f,0.f,0.f,0.f};
  f32x4 acc[4][4];
  #pragma unroll
  for (int i=0;i<4;i++)
    #pragma unroll
    for (int j=0;j<4;j++) acc[i][j] = zero;
  const int row = tid>>1, kk = (tid&1)*16;
  const u16* pa = A  + (size_t)(m0+row)*1024 + kk;
  const u16* pb = Bt + (size_t)(n0+row)*1024 + kk;
  for (int k0=0;k0<1024;k0+=32){
    __syncthreads();
    uint4 a0 = *(const uint4*)(pa); uint4 a1 = *(const uint4*)(pa+8);
    uint4 b0 = *(const uint4*)(pb); uint4 b1 = *(const uint4*)(pb+8);
    pa += 32; pb += 32;
    *(uint4*)&As[row*40+kk] = a0; *(uint4*)&As[row*40+kk+8] = a1;
    *(uint4*)&Bs[row*40+kk] = b0; *(uint4*)&Bs[row*40+kk+8] = b1;
    __syncthreads();
    bf16x8 af[4], bfr[4];
    #pragma unroll
    for (int mt=0;mt<4;mt++) af[mt]  = *(const bf16x8*)&As[(wm+mt*16+l16)*40 + quad*8];
    #pragma unroll
    for (int nt=0;nt<4;nt++) bfr[nt] = *(const bf16x8*)&Bs[(wn+nt*16+l16)*40 + quad*8];
    #pragma unroll
    for (int mt=0;mt<4;mt++)
      #pragma unroll
      for (int nt=0;nt<4;nt++)
        acc[mt][nt] = MFMA(af[mt], bfr[nt], acc[mt][nt]);
  }
  const int colbase = n0 + wn;          // 64-aligned -> which,h uniform per wave
  const int which = colbase>>10;
  const int nn0 = colbase & 1023;
  const int h = nn0>>6;
  const float* barr = (which==0)?bq:((which==1)?bk:bv);
  float bias[4];
  #pragma unroll
  for (int nt=0;nt<4;nt++) bias[nt] = barr[nn0 + nt*16 + l16];
  if (which == 2){
    // v: write transposed (b,h,d,t): vT[bh*65536 + d*1024 + t]
    #pragma unroll
    for (int mt=0;mt<4;mt++)
      #pragma unroll
      for (int r=0;r<4;r++){
        int m = m0 + wm + mt*16 + quad*4 + r;
        int bb = m>>10, t = m&1023;
        size_t base = (size_t)(bb*16+h)*65536 + t;
        #pragma unroll
        for (int nt=0;nt<4;nt++){
          int d = nt*16 + l16;
          vT[base + (size_t)d*1024] = f2b(acc[mt][nt][r] + bias[nt]);
        }
      }
  } else {
    const float scale = (which==0)?0.125f:1.0f;
    u16* dst = (which==0)? qb : kb;
    const float e = exp2f(-0.625f*(float)l16);
    #pragma unroll
    for (int mt=0;mt<4;mt++)
      #pragma unroll
      for (int r=0;r<4;r++){
        int m = m0 + wm + mt*16 + quad*4 + r;
        int bb = m>>10, t = m&1023;
        float f = (float)t * e;
        float cs = cosf(f), sn = sinf(f);
        float x0 = acc[mt][0][r] + bias[0];
        float x1 = acc[mt][1][r] + bias[1];
        float v0 = (x0*cs - x1*sn)*scale;
        float v1 = (x1*cs + x0*sn)*scale;
        float v2 = (acc[mt][2][r] + bias[2])*scale;
        float v3 = (acc[mt][3][r] + bias[3])*scale;
        size_t ob = (((size_t)(bb*16+h))*1024 + (size_t)t)*64 + l16;
        dst[ob]    = f2b(v0);
        dst[ob+16] = f2b(v1);
        dst[ob+32] = f2b(v2);
        dst[ob+48] = f2b(v3);
      }
  }
}

// ---------------- output GEMM: y[2048x1024] @ WoT^T + bo, x gamma[t], f32 out ----------------
__global__ __launch_bounds__(256) void k_gemm_out(
    const u16* __restrict__ A, const u16* __restrict__ Bt,
    const float* __restrict__ bo, const float* __restrict__ gamma, float* __restrict__ out)
{
  __shared__ u16 As[128*40];
  __shared__ u16 Bs[128*40];
  const int n0 = blockIdx.x*128, m0 = blockIdx.y*128;
  const int tid = threadIdx.x, lane = tid&63, wave = tid>>6;
  const int quad = lane>>4, l16 = lane&15;
  const int wm = (wave>>1)*64, wn = (wave&1)*64;
  f32x4 zero = {0.f,0.f,0.f,0.f};
  f32x4 acc[4][4];
  #pragma unroll
  for (int i=0;i<4;i++)
    #pragma unroll
    for (int j=0;j<4;j++) acc[i][j] = zero;
  const int row = tid>>1, kk = (tid&1)*16;
  const u16* pa = A  + (size_t)(m0+row)*1024 + kk;
  const u16* pb = Bt + (size_t)(n0+row)*1024 + kk;
  for (int k0=0;k0<1024;k0+=32){
    __syncthreads();
    uint4 a0 = *(const uint4*)(pa); uint4 a1 = *(const uint4*)(pa+8);
    uint4 b0 = *(const uint4*)(pb); uint4 b1 = *(const uint4*)(pb+8);
    pa += 32; pb += 32;
    *(uint4*)&As[row*40+kk] = a0; *(uint4*)&As[row*40+kk+8] = a1;
    *(uint4*)&Bs[row*40+kk] = b0; *(uint4*)&Bs[row*40+kk+8] = b1;
    __syncthreads();
    bf16x8 af[4], bfr[4];
    #pragma unroll
    for (int mt=0;mt<4;mt++) af[mt]  = *(const bf16x8*)&As[(wm+mt*16+l16)*40 + quad*8];
    #pragma unroll
    for (int nt=0;nt<4;nt++) bfr[nt] = *(const bf16x8*)&Bs[(wn+nt*16+l16)*40 + quad*8];
    #pragma unroll
    for (int mt=0;mt<4;mt++)
      #pragma unroll
      for (int nt=0;nt<4;nt++)
        acc[mt][nt] = MFMA(af[mt], bfr[nt], acc[mt][nt]);
  }
  #pragma unroll
  for (int mt=0;mt<4;mt++)
    #pragma unroll
    for (int nt=0;nt<4;nt++){
      int colg = n0 + wn + nt*16 + l16;
      float bias = bo[colg];
      #pragma unroll
      for (int r=0;r<4;r++){
        int m = m0 + wm + mt*16 + quad*4 + r;
        int t = m&1023;
        float val = (acc[mt][nt][r] + bias)*gamma[t];
        out[(size_t)m*1024 + colg] = val;
      }
    }
}

// ---------------- fused softmax+weight: S in registers, stats in LDS, write P ----------------
// grid (tb=16, h=16, b=2); 1024 threads = 16 waves = 4 wt x 4 ws; full 64t x 1024s S tile in regs
__global__ __launch_bounds__(1024) void k_sm(
    const u16* __restrict__ q, const u16* __restrict__ k,
    const float* __restrict__ tw, const float* __restrict__ alpha, const float* __restrict__ beta,
    u16* __restrict__ P)
{
  const int tb = blockIdx.x, h = blockIdx.y, b = blockIdx.z;
  const int t0b = tb*64;
  const int tid = threadIdx.x;
  const int wave = tid>>6, lane = tid&63, quad = lane>>4, l16 = lane&15;
  const int wt = wave>>2, ws = wave&3;

  __shared__ u16 qs[64*76];      // q tile, padded rows
  __shared__ u16 ks[256*76];     // K chunk, padded rows
  __shared__ float tws[1024];
  __shared__ float als[1024];
  __shared__ float pm[4][64];
  __shared__ float pl[4][64];
  __shared__ float fm[64];
  __shared__ float fr[64];

  const size_t bh = (size_t)(b*16+h)*65536;
  const u16* qp = q + bh;
  const u16* kp = k + bh;

  if (tid < 512){
    int row = tid>>3, g = tid&7;
    *(uint4*)&qs[row*76 + g*8] = *(const uint4*)(qp + (size_t)(t0b+row)*64 + g*8);
  }
  tws[tid] = tw[h*1024 + tid];
  als[tid] = alpha[h*1024 + tid];
  __syncthreads();

  bf16x8 qf0 = *(const bf16x8*)&qs[(wt*16+l16)*76 + quad*8];
  bf16x8 qf1 = *(const bf16x8*)&qs[(wt*16+l16)*76 + quad*8 + 32];

  f32x4 acc[16];
  #pragma unroll
  for (int i=0;i<16;i++){ acc[i][0]=0.f; acc[i][1]=0.f; acc[i][2]=0.f; acc[i][3]=0.f; }

  #pragma unroll
  for (int c=0;c<4;c++){
    if (c) __syncthreads();
    {
      int row = tid>>3, g = tid&7;
      *(uint4*)&ks[row*76 + g*8]       = *(const uint4*)(kp + (size_t)(c*256+row)*64 + g*8);
      *(uint4*)&ks[(row+128)*76 + g*8] = *(const uint4*)(kp + (size_t)(c*256+row+128)*64 + g*8);
    }
    __syncthreads();
    #pragma unroll
    for (int j=0;j<4;j++){
      int lt = j*4 + ws;
      bf16x8 kf0 = *(const bf16x8*)&ks[(lt*16+l16)*76 + quad*8];
      bf16x8 kf1 = *(const bf16x8*)&ks[(lt*16+l16)*76 + quad*8 + 32];
      acc[c*4+j] = MFMA(qf0, kf0, acc[c*4+j]);
      acc[c*4+j] = MFMA(qf1, kf1, acc[c*4+j]);
    }
  }

  // per-wave partial stats over its 256 s-columns
  float mrow[4], lrow[4];
  #pragma unroll
  for (int r=0;r<4;r++){
    float m = acc[0][r];
    #pragma unroll
    for (int a=1;a<16;a++) m = fmaxf(m, acc[a][r]);
    #pragma unroll
    for (int off=1; off<16; off<<=1) m = fmaxf(m, __shfl_xor(m, off));
    float l = 0.f;
    #pragma unroll
    for (int a=0;a<16;a++) l += __expf(acc[a][r]-m);
    #pragma unroll
    for (int off=1; off<16; off<<=1) l += __shfl_xor(l, off);
    mrow[r]=m; lrow[r]=l;
  }
  if (l16==0){
    #pragma unroll
    for (int r=0;r<4;r++){
      pm[ws][wt*16+quad*4+r] = mrow[r];
      pl[ws][wt*16+quad*4+r] = lrow[r];
    }
  }
  __syncthreads();
  if (tid < 64){
    float m0s = pm[0][tid], m1s = pm[1][tid], m2s = pm[2][tid], m3s = pm[3][tid];
    float m = fmaxf(fmaxf(m0s,m1s), fmaxf(m2s,m3s));
    float l = pl[0][tid]*__expf(m0s-m) + pl[1][tid]*__expf(m1s-m)
            + pl[2][tid]*__expf(m2s-m) + pl[3][tid]*__expf(m3s-m);
    fm[tid] = m;
    fr[tid] = beta[h*1024 + t0b + tid] / l;
  }
  __syncthreads();

  u16* Pp = P + ((size_t)(b*16+h)<<20);
  float m_f[4], r_f[4]; int trow[4];
  #pragma unroll
  for (int r=0;r<4;r++){
    int rg = wt*16+quad*4+r;
    m_f[r] = fm[rg]; r_f[r] = fr[rg]; trow[r] = t0b + rg;
  }
  const int slim = tb*4 + wt;   // last s-tile with any s<=t
  #pragma unroll
  for (int c=0;c<4;c++)
    #pragma unroll
    for (int j=0;j<4;j++){
      int st = c*16 + j*4 + ws;
      if (st > slim) continue;
      int s = st*16 + l16;
      float av = als[s];
      #pragma unroll
      for (int r=0;r<4;r++){
        int t = trow[r];
        float p = 0.f;
        if (s <= t)
          p = __expf(acc[c*4+j][r]-m_f[r])*r_f[r]*tws[1023+s-t]*av;
        Pp[((size_t)t<<10) + s] = f2b(p);
      }
    }
}

// ---------------- head-mix: A[b][g][t][s] = sum_h Wmix[g][h] P[b][h][t][s] ----------------
// grid (256 t-blocks, 4 s-chunks, 2 b)
__global__ __launch_bounds__(256) void k_mix(const u16* __restrict__ P, const float* __restrict__ Wm,
                                             u16* __restrict__ Ab)
{
  int tid = threadIdx.x;
  int b = blockIdx.z;
  int t = blockIdx.x*4 + (tid>>6);
  int sb = blockIdx.y*256 + (tid&63)*4;
  int tmaxw = t|31, tmaxr = t|15;
  if ((int)(blockIdx.y*256) > tmaxw) return;
  __shared__ float Wl[16][16];
  Wl[tid>>4 & 15][tid&15] = Wm[tid & 255];
  __syncthreads();
  const u16* Pb = P  + ((size_t)(b*16)<<20);
  u16* Abb      = Ab + ((size_t)(b*16)<<20);
  float a[16][4];
  #pragma unroll
  for (int g=0;g<16;g++){ a[g][0]=0.f; a[g][1]=0.f; a[g][2]=0.f; a[g][3]=0.f; }
  #pragma unroll
  for (int h=0;h<16;h++){
    float p0=0.f,p1=0.f,p2=0.f,p3=0.f;
    if (sb <= tmaxr){
      ushort4 u = *(const ushort4*)(Pb + (((size_t)h)<<20) + (((size_t)t)<<10) + sb);
      p0=b2f(u.x); p1=b2f(u.y); p2=b2f(u.z); p3=b2f(u.w);
    }
    #pragma unroll
    for (int g=0;g<16;g++){
      float w = Wl[g][h];
      a[g][0]+=w*p0; a[g][1]+=w*p1; a[g][2]+=w*p2; a[g][3]+=w*p3;
    }
  }
  if (sb <= tmaxw){
    #pragma unroll
    for (int g=0;g<16;g++){
      ushort4 o; o.x=f2b(a[g][0]); o.y=f2b(a[g][1]); o.z=f2b(a[g][2]); o.w=f2b(a[g][3]);
      *(ushort4*)(Abb + (((size_t)g)<<20) + (((size_t)t)<<10) + sb) = o;
    }
  }
}

// ---------------- PV: grid (tb=16, bg=32); 16 waves = 4 wt x 4 wd; LDS-staged s-chunks ----------------
__global__ __launch_bounds__(1024) void k_pv(const u16* __restrict__ Ab, const u16* __restrict__ vT,
                                             u16* __restrict__ y)
{
  const int tb = blockIdx.x;          // 0..15
  const int bg = blockIdx.y;          // 0..31 = b*16+g
  const int b = bg>>4, g = bg&15;
  const int t0b = tb*64;
  const int tid = threadIdx.x;
  const int wave = tid>>6, lane = tid&63, quad = lane>>4, l16 = lane&15;
  const int wt = wave>>2, wd = wave&3;
  __shared__ u16 As[64*264];
  __shared__ u16 Vs[64*264];
  const u16* ap = Ab + ((size_t)bg<<20);
  const u16* vp = vT + (size_t)bg*65536;   // [d][t]
  f32x4 acc = {0.f,0.f,0.f,0.f};
  const int nc = tb/4 + 1;            // causal: only chunks with s0 <= t|63
  const int row = tid>>4, col = (tid&15)*16;
  for (int c=0;c<nc;c++){
    if (c) __syncthreads();
    int s0 = c*256;
    *(uint4*)&As[row*264+col]   = *(const uint4*)(ap + (((size_t)(t0b+row))<<10) + s0+col);
    *(uint4*)&As[row*264+col+8] = *(const uint4*)(ap + (((size_t)(t0b+row))<<10) + s0+col+8);
    *(uint4*)&Vs[row*264+col]   = *(const uint4*)(vp + (size_t)row*1024 + s0+col);
    *(uint4*)&Vs[row*264+col+8] = *(const uint4*)(vp + (size_t)row*1024 + s0+col+8);
    __syncthreads();
    #pragma unroll
    for (int ks=0;ks<8;ks++){
      bf16x8 af  = *(const bf16x8*)&As[(wt*16+l16)*264 + ks*32 + quad*8];
      bf16x8 bfv = *(const bf16x8*)&Vs[(wd*16+l16)*264 + ks*32 + quad*8];
      acc = MFMA(af, bfv, acc);
    }
  }
  #pragma unroll
  for (int r=0;r<4;r++){
    int t = t0b + wt*16 + quad*4 + r;
    y[(size_t)(b*1024+t)*1024 + g*64 + wd*16 + l16] = f2b(acc[r]);
  }
}

__global__ void k_fail(float* out){ if (threadIdx.x==0) out[0] = 1e30f; } // ws-too-small marker

extern "C" void kernel_launch(void* const* d_in, const int* in_sizes, int n_in,
                              void* d_out, int out_size, void* d_ws, size_t ws_size,
                              hipStream_t stream)
{
  const float* x     = (const float*)d_in[0];
  const float* tw    = (const float*)d_in[1];
  const float* alpha = (const float*)d_in[2];
  const float* beta  = (const float*)d_in[3];
  const float* gamma = (const float*)d_in[4];
  const float* Wq    = (const float*)d_in[5];
  const float* bq    = (const float*)d_in[6];
  const float* Wk    = (const float*)d_in[7];
  const float* bk    = (const float*)d_in[8];
  const float* Wv    = (const float*)d_in[9];
  const float* bv    = (const float*)d_in[10];
  const float* Wmix  = (const float*)d_in[11];
  const float* Wo    = (const float*)d_in[12];
  const float* bo    = (const float*)d_in[13];
  float* out = (float*)d_out;

  char* ws = (char*)d_ws;
  size_t off = 0;
  auto take = [&](size_t bytes)->char*{
    char* p = ws + off; off += (bytes + 255) & ~(size_t)255; return p;
  };
  u16*   xs  = (u16*)take((size_t)2097152*2);   // xs (B*T, C) bf16
  u16*   WT  = (u16*)take((size_t)3145728*2);   // [3072][1024] = Wq^T|Wk^T|Wv^T bf16
  u16*   WoT = (u16*)take((size_t)1048576*2);
  u16*   qb  = (u16*)take((size_t)2097152*2);   // (b,h,t,d) rope'd, x1/8
  u16*   kb  = (u16*)take((size_t)2097152*2);   // (b,h,t,d) rope'd
  u16*   vTb = (u16*)take((size_t)2097152*2);   // (b,h,d,t)
  u16*   yb  = (u16*)take((size_t)2097152*2);   // (b,t,g,d)
  u16*   P   = (u16*)take((size_t)33554432*2);  // [b][h][t][s]
  u16*   A   = (u16*)take((size_t)33554432*2);  // [b][g][t][s]
  if (off > ws_size){
    hipLaunchKernelGGL(k_fail, dim3(1), dim3(64), 0, stream, out);
    return;
  }

  hipLaunchKernelGGL(k_pre, dim3(2048), dim3(256), 0, stream,
                     x, Wq, Wk, Wv, Wo, xs, WT, WoT);
  hipLaunchKernelGGL(k_gemm_qkv, dim3(24,16), dim3(256), 0, stream,
                     xs, WT, bq, bk, bv, qb, kb, vTb);
  hipLaunchKernelGGL(k_sm, dim3(16,16,2), dim3(1024), 0, stream,
                     qb, kb, tw, alpha, beta, P);
  hipLaunchKernelGGL(k_mix, dim3(256,4,2), dim3(256), 0, stream, P, Wmix, A);
  hipLaunchKernelGGL(k_pv, dim3(16,32), dim3(1024), 0, stream, A, vTb, yb);
  hipLaunchKernelGGL(k_gemm_out, dim3(8,16), dim3(256), 0, stream, yb, WoT, bo, gamma, out);
}

// Round 7
// 228.348 us; speedup vs baseline: 1.9261x; 1.0645x over previous
//
#include <hip/hip_runtime.h>

typedef unsigned short u16;
typedef __attribute__((ext_vector_type(8))) short bf16x8;
typedef __attribute__((ext_vector_type(4))) float f32x4;

#define MFMA(a,b,c) __builtin_amdgcn_mfma_f32_16x16x32_bf16(a,b,c,0,0,0)

__device__ __forceinline__ float b2f(u16 u){
  union { unsigned int i; float f; } v; v.i = ((unsigned int)u)<<16; return v.f;
}
__device__ __forceinline__ u16 f2b(float f){
  union { float f; unsigned int i; } v; v.f = f;
  unsigned int r = (v.i + 0x7FFFu + ((v.i>>16)&1u))>>16;
  return (u16)r;
}

// ---------------- combined: time-shift prep (blocks 0..1023) + 4 weight transposes ----------------
__global__ __launch_bounds__(256) void k_pre(
    const float* __restrict__ x,
    const float* __restrict__ Wq, const float* __restrict__ Wk,
    const float* __restrict__ Wv, const float* __restrict__ Wo,
    u16* __restrict__ xs, u16* __restrict__ WT, u16* __restrict__ WoT)
{
  int bid = blockIdx.x;
  int tid = threadIdx.x;
  if (bid < 1024){
    int idx = bid*256 + tid;                 // one thread per 8 elements
    size_t e = (size_t)idx*8;
    int c = (int)(e & 1023);
    int t = (int)((e>>10)&1023);
    float4 f0 = {0.f,0.f,0.f,0.f}, f1 = {0.f,0.f,0.f,0.f};
    const float* src = nullptr;
    if (c < 512){ if (t > 0) src = x + e - 1024; }
    else        { src = x + e; }
    if (src){ f0 = *(const float4*)src; f1 = *(const float4*)(src+4); }
    u16 o[8];
    o[0]=f2b(f0.x); o[1]=f2b(f0.y); o[2]=f2b(f0.z); o[3]=f2b(f0.w);
    o[4]=f2b(f1.x); o[5]=f2b(f1.y); o[6]=f2b(f1.z); o[7]=f2b(f1.w);
    *(uint4*)(xs + e) = *(const uint4*)o;
    return;
  }
  int z  = (bid-1024)>>8;                    // 0..3 : Wq,Wk,Wv,Wo
  int rc = (bid-1024)&255;
  const float* src = (z==0)?Wq:((z==1)?Wk:((z==2)?Wv:Wo));
  u16* dst = (z==3)? WoT : (WT + (size_t)z*1048576);
  int c0 = (rc&15)*64, r0 = (rc>>4)*64;
  __shared__ u16 tile[64][72];
  int r = tid>>2, cc = (tid&3)*16;
  const float* sp = src + (size_t)(r0+r)*1024 + c0+cc;
  float4 a0 = *(const float4*)(sp);
  float4 a1 = *(const float4*)(sp+4);
  float4 a2 = *(const float4*)(sp+8);
  float4 a3 = *(const float4*)(sp+12);
  tile[r][cc+0]=f2b(a0.x); tile[r][cc+1]=f2b(a0.y); tile[r][cc+2]=f2b(a0.z); tile[r][cc+3]=f2b(a0.w);
  tile[r][cc+4]=f2b(a1.x); tile[r][cc+5]=f2b(a1.y); tile[r][cc+6]=f2b(a1.z); tile[r][cc+7]=f2b(a1.w);
  tile[r][cc+8]=f2b(a2.x); tile[r][cc+9]=f2b(a2.y); tile[r][cc+10]=f2b(a2.z); tile[r][cc+11]=f2b(a2.w);
  tile[r][cc+12]=f2b(a3.x); tile[r][cc+13]=f2b(a3.y); tile[r][cc+14]=f2b(a3.z); tile[r][cc+15]=f2b(a3.w);
  __syncthreads();
  int c = tid>>2, rr = (tid&3)*16;
  uint4 o0,o1; u16* p0=(u16*)&o0; u16* p1=(u16*)&o1;
  #pragma unroll
  for (int i=0;i<8;i++){ p0[i]=tile[rr+i][c]; p1[i]=tile[rr+8+i][c]; }
  *(uint4*)(dst + (size_t)(c0+c)*1024 + r0+rr)   = o0;
  *(uint4*)(dst + (size_t)(c0+c)*1024 + r0+rr+8) = o1;
}

// ---------------- QKV GEMM + fused RoPE; v written transposed (b,h,d,t) ----------------
__global__ __launch_bounds__(256) void k_gemm_qkv(
    const u16* __restrict__ A, const u16* __restrict__ Bt,
    const float* __restrict__ bq, const float* __restrict__ bk, const float* __restrict__ bv,
    u16* __restrict__ qb, u16* __restrict__ kb, u16* __restrict__ vT)
{
  __shared__ u16 As[128*40];
  __shared__ u16 Bs[128*40];
  const int n0 = blockIdx.x*128, m0 = blockIdx.y*128;
  const int tid = threadIdx.x, lane = tid&63, wave = tid>>6;
  const int quad = lane>>4, l16 = lane&15;
  const int wm = (wave>>1)*64, wn = (wave&1)*64;
  f32x4 zero = {0.f,0.f,0.f,0.f};
  f32x4 acc[4][4];
  #pragma unroll
  for (int i=0;i<4;i++)
    #pragma unroll
    for (int j=0;j<4;j++) acc[i][j] = zero;
  const int row = tid>>1, kk = (tid&1)*16;
  const u16* pa = A  + (size_t)(m0+row)*1024 + kk;
  const u16* pb = Bt + (size_t)(n0+row)*1024 + kk;
  for (int k0=0;k0<1024;k0+=32){
    __syncthreads();
    uint4 a0 = *(const uint4*)(pa); uint4 a1 = *(const uint4*)(pa+8);
    uint4 b0 = *(const uint4*)(pb); uint4 b1 = *(const uint4*)(pb+8);
    pa += 32; pb += 32;
    *(uint4*)&As[row*40+kk] = a0; *(uint4*)&As[row*40+kk+8] = a1;
    *(uint4*)&Bs[row*40+kk] = b0; *(uint4*)&Bs[row*40+kk+8] = b1;
    __syncthreads();
    bf16x8 af[4], bfr[4];
    #pragma unroll
    for (int mt=0;mt<4;mt++) af[mt]  = *(const bf16x8*)&As[(wm+mt*16+l16)*40 + quad*8];
    #pragma unroll
    for (int nt=0;nt<4;nt++) bfr[nt] = *(const bf16x8*)&Bs[(wn+nt*16+l16)*40 + quad*8];
    #pragma unroll
    for (int mt=0;mt<4;mt++)
      #pragma unroll
      for (int nt=0;nt<4;nt++)
        acc[mt][nt] = MFMA(af[mt], bfr[nt], acc[mt][nt]);
  }
  const int colbase = n0 + wn;          // 64-aligned -> which,h uniform per wave
  const int which = colbase>>10;
  const int nn0 = colbase & 1023;
  const int h = nn0>>6;
  const float* barr = (which==0)?bq:((which==1)?bk:bv);
  float bias[4];
  #pragma unroll
  for (int nt=0;nt<4;nt++) bias[nt] = barr[nn0 + nt*16 + l16];
  if (which == 2){
    // v: write transposed (b,h,d,t): vT[bh*65536 + d*1024 + t]
    #pragma unroll
    for (int mt=0;mt<4;mt++)
      #pragma unroll
      for (int r=0;r<4;r++){
        int m = m0 + wm + mt*16 + quad*4 + r;
        int bb = m>>10, t = m&1023;
        size_t base = (size_t)(bb*16+h)*65536 + t;
        #pragma unroll
        for (int nt=0;nt<4;nt++){
          int d = nt*16 + l16;
          vT[base + (size_t)d*1024] = f2b(acc[mt][nt][r] + bias[nt]);
        }
      }
  } else {
    const float scale = (which==0)?0.125f:1.0f;
    u16* dst = (which==0)? qb : kb;
    const float e = exp2f(-0.625f*(float)l16);
    #pragma unroll
    for (int mt=0;mt<4;mt++)
      #pragma unroll
      for (int r=0;r<4;r++){
        int m = m0 + wm + mt*16 + quad*4 + r;
        int bb = m>>10, t = m&1023;
        float f = (float)t * e;
        float cs = cosf(f), sn = sinf(f);
        float x0 = acc[mt][0][r] + bias[0];
        float x1 = acc[mt][1][r] + bias[1];
        float v0 = (x0*cs - x1*sn)*scale;
        float v1 = (x1*cs + x0*sn)*scale;
        float v2 = (acc[mt][2][r] + bias[2])*scale;
        float v3 = (acc[mt][3][r] + bias[3])*scale;
        size_t ob = (((size_t)(bb*16+h))*1024 + (size_t)t)*64 + l16;
        dst[ob]    = f2b(v0);
        dst[ob+16] = f2b(v1);
        dst[ob+32] = f2b(v2);
        dst[ob+48] = f2b(v3);
      }
  }
}

// ---------------- output GEMM: y[2048x1024] @ WoT^T + bo, x gamma[t], f32 out ----------------
__global__ __launch_bounds__(256) void k_gemm_out(
    const u16* __restrict__ A, const u16* __restrict__ Bt,
    const float* __restrict__ bo, const float* __restrict__ gamma, float* __restrict__ out)
{
  __shared__ u16 As[128*40];
  __shared__ u16 Bs[128*40];
  const int n0 = blockIdx.x*128, m0 = blockIdx.y*128;
  const int tid = threadIdx.x, lane = tid&63, wave = tid>>6;
  const int quad = lane>>4, l16 = lane&15;
  const int wm = (wave>>1)*64, wn = (wave&1)*64;
  f32x4 zero = {0.f,0.f,0.f,0.f};
  f32x4 acc[4][4];
  #pragma unroll
  for (int i=0;i<4;i++)
    #pragma unroll
    for (int j=0;j<4;j++) acc[i][j] = zero;
  const int row = tid>>1, kk = (tid&1)*16;
  const u16* pa = A  + (size_t)(m0+row)*1024 + kk;
  const u16* pb = Bt + (size_t)(n0+row)*1024 + kk;
  for (int k0=0;k0<1024;k0+=32){
    __syncthreads();
    uint4 a0 = *(const uint4*)(pa); uint4 a1 = *(const uint4*)(pa+8);
    uint4 b0 = *(const uint4*)(pb); uint4 b1 = *(const uint4*)(pb+8);
    pa += 32; pb += 32;
    *(uint4*)&As[row*40+kk] = a0; *(uint4*)&As[row*40+kk+8] = a1;
    *(uint4*)&Bs[row*40+kk] = b0; *(uint4*)&Bs[row*40+kk+8] = b1;
    __syncthreads();
    bf16x8 af[4], bfr[4];
    #pragma unroll
    for (int mt=0;mt<4;mt++) af[mt]  = *(const bf16x8*)&As[(wm+mt*16+l16)*40 + quad*8];
    #pragma unroll
    for (int nt=0;nt<4;nt++) bfr[nt] = *(const bf16x8*)&Bs[(wn+nt*16+l16)*40 + quad*8];
    #pragma unroll
    for (int mt=0;mt<4;mt++)
      #pragma unroll
      for (int nt=0;nt<4;nt++)
        acc[mt][nt] = MFMA(af[mt], bfr[nt], acc[mt][nt]);
  }
  #pragma unroll
  for (int mt=0;mt<4;mt++)
    #pragma unroll
    for (int nt=0;nt<4;nt++){
      int colg = n0 + wn + nt*16 + l16;
      float bias = bo[colg];
      #pragma unroll
      for (int r=0;r<4;r++){
        int m = m0 + wm + mt*16 + quad*4 + r;
        int t = m&1023;
        float val = (acc[mt][nt][r] + bias)*gamma[t];
        out[(size_t)m*1024 + colg] = val;
      }
    }
}

// ---------------- fused softmax+weight: S in registers, stats in LDS, write P ----------------
// grid (tb=16, h=16, b=2); 1024 threads = 16 waves = 4 wt x 4 ws; full 64t x 1024s S tile in regs
// P layout: [b][t][h][s]
__global__ __launch_bounds__(1024) void k_sm(
    const u16* __restrict__ q, const u16* __restrict__ k,
    const float* __restrict__ tw, const float* __restrict__ alpha, const float* __restrict__ beta,
    u16* __restrict__ P)
{
  const int tb = blockIdx.x, h = blockIdx.y, b = blockIdx.z;
  const int t0b = tb*64;
  const int tid = threadIdx.x;
  const int wave = tid>>6, lane = tid&63, quad = lane>>4, l16 = lane&15;
  const int wt = wave>>2, ws = wave&3;

  __shared__ u16 qs[64*76];      // q tile, padded rows
  __shared__ u16 ks[256*76];     // K chunk, padded rows
  __shared__ float tws[1024];
  __shared__ float als[1024];
  __shared__ float pm[4][64];
  __shared__ float pl[4][64];
  __shared__ float fm[64];
  __shared__ float fr[64];

  const size_t bh = (size_t)(b*16+h)*65536;
  const u16* qp = q + bh;
  const u16* kp = k + bh;

  if (tid < 512){
    int row = tid>>3, g = tid&7;
    *(uint4*)&qs[row*76 + g*8] = *(const uint4*)(qp + (size_t)(t0b+row)*64 + g*8);
  }
  tws[tid] = tw[h*1024 + tid];
  als[tid] = alpha[h*1024 + tid];
  __syncthreads();

  bf16x8 qf0 = *(const bf16x8*)&qs[(wt*16+l16)*76 + quad*8];
  bf16x8 qf1 = *(const bf16x8*)&qs[(wt*16+l16)*76 + quad*8 + 32];

  f32x4 acc[16];
  #pragma unroll
  for (int i=0;i<16;i++){ acc[i][0]=0.f; acc[i][1]=0.f; acc[i][2]=0.f; acc[i][3]=0.f; }

  #pragma unroll
  for (int c=0;c<4;c++){
    if (c) __syncthreads();
    {
      int row = tid>>3, g = tid&7;
      *(uint4*)&ks[row*76 + g*8]       = *(const uint4*)(kp + (size_t)(c*256+row)*64 + g*8);
      *(uint4*)&ks[(row+128)*76 + g*8] = *(const uint4*)(kp + (size_t)(c*256+row+128)*64 + g*8);
    }
    __syncthreads();
    #pragma unroll
    for (int j=0;j<4;j++){
      int lt = j*4 + ws;
      bf16x8 kf0 = *(const bf16x8*)&ks[(lt*16+l16)*76 + quad*8];
      bf16x8 kf1 = *(const bf16x8*)&ks[(lt*16+l16)*76 + quad*8 + 32];
      acc[c*4+j] = MFMA(qf0, kf0, acc[c*4+j]);
      acc[c*4+j] = MFMA(qf1, kf1, acc[c*4+j]);
    }
  }

  // per-wave partial stats over its 256 s-columns
  float mrow[4], lrow[4];
  #pragma unroll
  for (int r=0;r<4;r++){
    float m = acc[0][r];
    #pragma unroll
    for (int a=1;a<16;a++) m = fmaxf(m, acc[a][r]);
    #pragma unroll
    for (int off=1; off<16; off<<=1) m = fmaxf(m, __shfl_xor(m, off));
    float l = 0.f;
    #pragma unroll
    for (int a=0;a<16;a++) l += __expf(acc[a][r]-m);
    #pragma unroll
    for (int off=1; off<16; off<<=1) l += __shfl_xor(l, off);
    mrow[r]=m; lrow[r]=l;
  }
  if (l16==0){
    #pragma unroll
    for (int r=0;r<4;r++){
      pm[ws][wt*16+quad*4+r] = mrow[r];
      pl[ws][wt*16+quad*4+r] = lrow[r];
    }
  }
  __syncthreads();
  if (tid < 64){
    float m0s = pm[0][tid], m1s = pm[1][tid], m2s = pm[2][tid], m3s = pm[3][tid];
    float m = fmaxf(fmaxf(m0s,m1s), fmaxf(m2s,m3s));
    float l = pl[0][tid]*__expf(m0s-m) + pl[1][tid]*__expf(m1s-m)
            + pl[2][tid]*__expf(m2s-m) + pl[3][tid]*__expf(m3s-m);
    fm[tid] = m;
    fr[tid] = beta[h*1024 + t0b + tid] / l;
  }
  __syncthreads();

  u16* Pp = P + (((size_t)b)<<24) + (((size_t)h)<<10);   // [b][t][h][s]
  float m_f[4], r_f[4]; int trow[4];
  #pragma unroll
  for (int r=0;r<4;r++){
    int rg = wt*16+quad*4+r;
    m_f[r] = fm[rg]; r_f[r] = fr[rg]; trow[r] = t0b + rg;
  }
  const int slim = tb*4 + wt;   // last s-tile with any s<=t
  #pragma unroll
  for (int c=0;c<4;c++)
    #pragma unroll
    for (int j=0;j<4;j++){
      int st = c*16 + j*4 + ws;
      if (st > slim) continue;
      int s = st*16 + l16;
      float av = als[s];
      #pragma unroll
      for (int r=0;r<4;r++){
        int t = trow[r];
        float p = 0.f;
        if (s <= t)
          p = __expf(acc[c*4+j][r]-m_f[r])*r_f[r]*tws[1023+s-t]*av;
        Pp[((size_t)t<<14) + s] = f2b(p);
      }
    }
}

// ---------------- head-mix: A[b][t][g][s] = sum_h Wmix[g][h] P[b][t][h][s] ----------------
// grid (1024 t, 2 b); 256 thr; per-t P slab staged by 256-col chunks into LDS
__global__ __launch_bounds__(256) void k_mix(const u16* __restrict__ P, const float* __restrict__ Wm,
                                             u16* __restrict__ Ab)
{
  const int t = blockIdx.x, b = blockIdx.y;
  const int tid = threadIdx.x;
  const int g = tid>>4, sg = tid&15;
  __shared__ u16 Ps[16*264];
  float w[16];
  #pragma unroll
  for (int h=0;h<16;h++) w[h] = Wm[g*16+h];
  const int tmaxr = t|15;             // P defined for s <= tmaxr
  const int ncw = (t>>8) + 1;         // write chunks cover k_pv's read range (s <= t|255)
  const size_t slab = (((size_t)b)<<24) + (((size_t)t)<<14);
  const u16* pp = P + slab;
  u16* ap = Ab + slab;
  for (int c=0;c<ncw;c++){
    int s0 = c*256;
    if (s0 <= tmaxr){
      if (c) __syncthreads();
      int colg = sg*16;
      uint4 z = {0u,0u,0u,0u};
      uint4 v0 = z, v1 = z;
      if (s0+colg <= tmaxr){
        v0 = *(const uint4*)(pp + ((size_t)g<<10) + s0+colg);
        v1 = *(const uint4*)(pp + ((size_t)g<<10) + s0+colg+8);
      }
      *(uint4*)&Ps[g*264+colg]   = v0;
      *(uint4*)&Ps[g*264+colg+8] = v1;
      __syncthreads();
      float acc[16];
      #pragma unroll
      for (int i=0;i<16;i++) acc[i]=0.f;
      #pragma unroll
      for (int h=0;h<16;h++){
        float wh = w[h];
        #pragma unroll
        for (int j=0;j<4;j++){
          ushort4 u = *(const ushort4*)&Ps[h*264 + sg*16 + j*4];
          acc[j*4+0] += wh*b2f(u.x);
          acc[j*4+1] += wh*b2f(u.y);
          acc[j*4+2] += wh*b2f(u.z);
          acc[j*4+3] += wh*b2f(u.w);
        }
      }
      u16 o[16];
      #pragma unroll
      for (int i=0;i<16;i++) o[i] = f2b(acc[i]);
      *(uint4*)(ap + ((size_t)g<<10) + s0 + sg*16)     = *(uint4*)&o[0];
      *(uint4*)(ap + ((size_t)g<<10) + s0 + sg*16 + 8) = *(uint4*)&o[8];
    } else {
      uint4 z = {0u,0u,0u,0u};
      *(uint4*)(ap + ((size_t)g<<10) + s0 + sg*16)     = z;
      *(uint4*)(ap + ((size_t)g<<10) + s0 + sg*16 + 8) = z;
    }
  }
}

// ---------------- PV: grid (tb=16, bg=32); 16 waves = 4 wt x 4 wd; LDS-staged s-chunks ----------------
__global__ __launch_bounds__(1024) void k_pv(const u16* __restrict__ Ab, const u16* __restrict__ vT,
                                             u16* __restrict__ y)
{
  const int tb = blockIdx.x;          // 0..15
  const int bg = blockIdx.y;          // 0..31 = b*16+g
  const int b = bg>>4, g = bg&15;
  const int t0b = tb*64;
  const int tid = threadIdx.x;
  const int wave = tid>>6, lane = tid&63, quad = lane>>4, l16 = lane&15;
  const int wt = wave>>2, wd = wave&3;
  __shared__ u16 As[64*264];
  __shared__ u16 Vs[64*264];
  const u16* ap = Ab + (((size_t)b)<<24) + ((size_t)g<<10);   // [b][t][g][s]
  const u16* vp = vT + (size_t)bg*65536;   // [d][t]
  f32x4 acc = {0.f,0.f,0.f,0.f};
  const int nc = tb/4 + 1;            // causal: only chunks with s0 <= t|63
  const int row = tid>>4, col = (tid&15)*16;
  for (int c=0;c<nc;c++){
    if (c) __syncthreads();
    int s0 = c*256;
    *(uint4*)&As[row*264+col]   = *(const uint4*)(ap + ((size_t)(t0b+row)<<14) + s0+col);
    *(uint4*)&As[row*264+col+8] = *(const uint4*)(ap + ((size_t)(t0b+row)<<14) + s0+col+8);
    *(uint4*)&Vs[row*264+col]   = *(const uint4*)(vp + (size_t)row*1024 + s0+col);
    *(uint4*)&Vs[row*264+col+8] = *(const uint4*)(vp + (size_t)row*1024 + s0+col+8);
    __syncthreads();
    #pragma unroll
    for (int ks=0;ks<8;ks++){
      bf16x8 af  = *(const bf16x8*)&As[(wt*16+l16)*264 + ks*32 + quad*8];
      bf16x8 bfv = *(const bf16x8*)&Vs[(wd*16+l16)*264 + ks*32 + quad*8];
      acc = MFMA(af, bfv, acc);
    }
  }
  #pragma unroll
  for (int r=0;r<4;r++){
    int t = t0b + wt*16 + quad*4 + r;
    y[(size_t)(b*1024+t)*1024 + g*64 + wd*16 + l16] = f2b(acc[r]);
  }
}

__global__ void k_fail(float* out){ if (threadIdx.x==0) out[0] = 1e30f; } // ws-too-small marker

extern "C" void kernel_launch(void* const* d_in, const int* in_sizes, int n_in,
                              void* d_out, int out_size, void* d_ws, size_t ws_size,
                              hipStream_t stream)
{
  const float* x     = (const float*)d_in[0];
  const float* tw    = (const float*)d_in[1];
  const float* alpha = (const float*)d_in[2];
  const float* beta  = (const float*)d_in[3];
  const float* gamma = (const float*)d_in[4];
  const float* Wq    = (const float*)d_in[5];
  const float* bq    = (const float*)d_in[6];
  const float* Wk    = (const float*)d_in[7];
  const float* bk    = (const float*)d_in[8];
  const float* Wv    = (const float*)d_in[9];
  const float* bv    = (const float*)d_in[10];
  const float* Wmix  = (const float*)d_in[11];
  const float* Wo    = (const float*)d_in[12];
  const float* bo    = (const float*)d_in[13];
  float* out = (float*)d_out;

  char* ws = (char*)d_ws;
  size_t off = 0;
  auto take = [&](size_t bytes)->char*{
    char* p = ws + off; off += (bytes + 255) & ~(size_t)255; return p;
  };
  u16*   xs  = (u16*)take((size_t)2097152*2);   // xs (B*T, C) bf16
  u16*   WT  = (u16*)take((size_t)3145728*2);   // [3072][1024] = Wq^T|Wk^T|Wv^T bf16
  u16*   WoT = (u16*)take((size_t)1048576*2);
  u16*   qb  = (u16*)take((size_t)2097152*2);   // (b,h,t,d) rope'd, x1/8
  u16*   kb  = (u16*)take((size_t)2097152*2);   // (b,h,t,d) rope'd
  u16*   vTb = (u16*)take((size_t)2097152*2);   // (b,h,d,t)
  u16*   yb  = (u16*)take((size_t)2097152*2);   // (b,t,g,d)
  u16*   P   = (u16*)take((size_t)33554432*2);  // [b][t][h][s]
  u16*   A   = (u16*)take((size_t)33554432*2);  // [b][t][g][s]
  if (off > ws_size){
    hipLaunchKernelGGL(k_fail, dim3(1), dim3(64), 0, stream, out);
    return;
  }

  hipLaunchKernelGGL(k_pre, dim3(2048), dim3(256), 0, stream,
                     x, Wq, Wk, Wv, Wo, xs, WT, WoT);
  hipLaunchKernelGGL(k_gemm_qkv, dim3(24,16), dim3(256), 0, stream,
                     xs, WT, bq, bk, bv, qb, kb, vTb);
  hipLaunchKernelGGL(k_sm, dim3(16,16,2), dim3(1024), 0, stream,
                     qb, kb, tw, alpha, beta, P);
  hipLaunchKernelGGL(k_mix, dim3(1024,2), dim3(256), 0, stream, P, Wmix, A);
  hipLaunchKernelGGL(k_pv, dim3(16,32), dim3(1024), 0, stream, A, vTb, yb);
  hipLaunchKernelGGL(k_gemm_out, dim3(8,16), dim3(256), 0, stream, yb, WoT, bo, gamma, out);
}

// Round 8
// 218.564 us; speedup vs baseline: 2.0123x; 1.0448x over previous
//
#include <hip/hip_runtime.h>

typedef unsigned short u16;
typedef unsigned int u32;
typedef __attribute__((ext_vector_type(8))) short bf16x8;
typedef __attribute__((ext_vector_type(4))) float f32x4;

#define MFMA(a,b,c) __builtin_amdgcn_mfma_f32_16x16x32_bf16(a,b,c,0,0,0)

__device__ __forceinline__ float b2f(u16 u){
  union { unsigned int i; float f; } v; v.i = ((unsigned int)u)<<16; return v.f;
}
__device__ __forceinline__ u16 f2b(float f){
  union { float f; unsigned int i; } v; v.f = f;
  unsigned int r = (v.i + 0x7FFFu + ((v.i>>16)&1u))>>16;
  return (u16)r;
}
// async global->LDS, 16B per lane; lds dest must be wave-uniform base (HW adds lane*16)
__device__ __forceinline__ void gld16(const u16* g, u16* l){
  __builtin_amdgcn_global_load_lds((const __attribute__((address_space(1))) u32*)g,
                                   (__attribute__((address_space(3))) u32*)l, 16, 0, 0);
}

// ---------------- combined: time-shift prep (blocks 0..1023) + 4 weight transposes ----------------
__global__ __launch_bounds__(256) void k_pre(
    const float* __restrict__ x,
    const float* __restrict__ Wq, const float* __restrict__ Wk,
    const float* __restrict__ Wv, const float* __restrict__ Wo,
    u16* __restrict__ xs, u16* __restrict__ WT, u16* __restrict__ WoT)
{
  int bid = blockIdx.x;
  int tid = threadIdx.x;
  if (bid < 1024){
    int idx = bid*256 + tid;                 // one thread per 8 elements
    size_t e = (size_t)idx*8;
    int c = (int)(e & 1023);
    int t = (int)((e>>10)&1023);
    float4 f0 = {0.f,0.f,0.f,0.f}, f1 = {0.f,0.f,0.f,0.f};
    const float* src = nullptr;
    if (c < 512){ if (t > 0) src = x + e - 1024; }
    else        { src = x + e; }
    if (src){ f0 = *(const float4*)src; f1 = *(const float4*)(src+4); }
    u16 o[8];
    o[0]=f2b(f0.x); o[1]=f2b(f0.y); o[2]=f2b(f0.z); o[3]=f2b(f0.w);
    o[4]=f2b(f1.x); o[5]=f2b(f1.y); o[6]=f2b(f1.z); o[7]=f2b(f1.w);
    *(uint4*)(xs + e) = *(const uint4*)o;
    return;
  }
  int z  = (bid-1024)>>8;                    // 0..3 : Wq,Wk,Wv,Wo
  int rc = (bid-1024)&255;
  const float* src = (z==0)?Wq:((z==1)?Wk:((z==2)?Wv:Wo));
  u16* dst = (z==3)? WoT : (WT + (size_t)z*1048576);
  int c0 = (rc&15)*64, r0 = (rc>>4)*64;
  __shared__ u16 tile[64][72];
  int r = tid>>2, cc = (tid&3)*16;
  const float* sp = src + (size_t)(r0+r)*1024 + c0+cc;
  float4 a0 = *(const float4*)(sp);
  float4 a1 = *(const float4*)(sp+4);
  float4 a2 = *(const float4*)(sp+8);
  float4 a3 = *(const float4*)(sp+12);
  tile[r][cc+0]=f2b(a0.x); tile[r][cc+1]=f2b(a0.y); tile[r][cc+2]=f2b(a0.z); tile[r][cc+3]=f2b(a0.w);
  tile[r][cc+4]=f2b(a1.x); tile[r][cc+5]=f2b(a1.y); tile[r][cc+6]=f2b(a1.z); tile[r][cc+7]=f2b(a1.w);
  tile[r][cc+8]=f2b(a2.x); tile[r][cc+9]=f2b(a2.y); tile[r][cc+10]=f2b(a2.z); tile[r][cc+11]=f2b(a2.w);
  tile[r][cc+12]=f2b(a3.x); tile[r][cc+13]=f2b(a3.y); tile[r][cc+14]=f2b(a3.z); tile[r][cc+15]=f2b(a3.w);
  __syncthreads();
  int c = tid>>2, rr = (tid&3)*16;
  uint4 o0,o1; u16* p0=(u16*)&o0; u16* p1=(u16*)&o1;
  #pragma unroll
  for (int i=0;i<8;i++){ p0[i]=tile[rr+i][c]; p1[i]=tile[rr+8+i][c]; }
  *(uint4*)(dst + (size_t)(c0+c)*1024 + r0+rr)   = o0;
  *(uint4*)(dst + (size_t)(c0+c)*1024 + r0+rr+8) = o1;
}

// ---------------- QKV GEMM (global_load_lds staging) + fused RoPE; v -> (b,h,d,t) ----------------
__global__ __launch_bounds__(256) void k_gemm_qkv(
    const u16* __restrict__ A, const u16* __restrict__ Bt,
    const float* __restrict__ bq, const float* __restrict__ bk, const float* __restrict__ bv,
    u16* __restrict__ qb, u16* __restrict__ kb, u16* __restrict__ vT)
{
  __shared__ u16 As[128*32];     // unpadded: required by global_load_lds lane order
  __shared__ u16 Bs[128*32];
  const int n0 = blockIdx.x*128, m0 = blockIdx.y*128;
  const int tid = threadIdx.x, lane = tid&63, wave = tid>>6;
  const int quad = lane>>4, l16 = lane&15;
  const int wm = (wave>>1)*64, wn = (wave&1)*64;
  f32x4 zero = {0.f,0.f,0.f,0.f};
  f32x4 acc[4][4];
  #pragma unroll
  for (int i=0;i<4;i++)
    #pragma unroll
    for (int j=0;j<4;j++) acc[i][j] = zero;
  // staging addresses: instr i covers rows [i*64 + wave*16, +16); lane -> row wave*16+(lane>>2), k-off (lane&3)*8
  const int srow = (lane>>2), scol = (lane&3)*8;
  const u16* pa0 = A  + (size_t)(m0 + wave*16 + srow)*1024 + scol;
  const u16* pb0 = Bt + (size_t)(n0 + wave*16 + srow)*1024 + scol;
  u16* lA0 = &As[(wave*16)*32];
  u16* lA1 = &As[(64 + wave*16)*32];
  u16* lB0 = &Bs[(wave*16)*32];
  u16* lB1 = &Bs[(64 + wave*16)*32];
  for (int k0=0;k0<1024;k0+=32){
    __syncthreads();
    gld16(pa0 + k0,          lA0);
    gld16(pa0 + 64*1024 + k0, lA1);
    gld16(pb0 + k0,          lB0);
    gld16(pb0 + 64*1024 + k0, lB1);
    __syncthreads();
    bf16x8 af[4], bfr[4];
    #pragma unroll
    for (int mt=0;mt<4;mt++) af[mt]  = *(const bf16x8*)&As[(wm+mt*16+l16)*32 + quad*8];
    #pragma unroll
    for (int nt=0;nt<4;nt++) bfr[nt] = *(const bf16x8*)&Bs[(wn+nt*16+l16)*32 + quad*8];
    #pragma unroll
    for (int mt=0;mt<4;mt++)
      #pragma unroll
      for (int nt=0;nt<4;nt++)
        acc[mt][nt] = MFMA(af[mt], bfr[nt], acc[mt][nt]);
  }
  const int colbase = n0 + wn;          // 64-aligned -> which,h uniform per wave
  const int which = colbase>>10;
  const int nn0 = colbase & 1023;
  const int h = nn0>>6;
  const float* barr = (which==0)?bq:((which==1)?bk:bv);
  float bias[4];
  #pragma unroll
  for (int nt=0;nt<4;nt++) bias[nt] = barr[nn0 + nt*16 + l16];
  if (which == 2){
    // v: write transposed (b,h,d,t): vT[bh*65536 + d*1024 + t]
    #pragma unroll
    for (int mt=0;mt<4;mt++)
      #pragma unroll
      for (int r=0;r<4;r++){
        int m = m0 + wm + mt*16 + quad*4 + r;
        int bb = m>>10, t = m&1023;
        size_t base = (size_t)(bb*16+h)*65536 + t;
        #pragma unroll
        for (int nt=0;nt<4;nt++){
          int d = nt*16 + l16;
          vT[base + (size_t)d*1024] = f2b(acc[mt][nt][r] + bias[nt]);
        }
      }
  } else {
    const float scale = (which==0)?0.125f:1.0f;
    u16* dst = (which==0)? qb : kb;
    const float e = exp2f(-0.625f*(float)l16);
    #pragma unroll
    for (int mt=0;mt<4;mt++)
      #pragma unroll
      for (int r=0;r<4;r++){
        int m = m0 + wm + mt*16 + quad*4 + r;
        int bb = m>>10, t = m&1023;
        float f = (float)t * e;
        float cs = cosf(f), sn = sinf(f);
        float x0 = acc[mt][0][r] + bias[0];
        float x1 = acc[mt][1][r] + bias[1];
        float v0 = (x0*cs - x1*sn)*scale;
        float v1 = (x1*cs + x0*sn)*scale;
        float v2 = (acc[mt][2][r] + bias[2])*scale;
        float v3 = (acc[mt][3][r] + bias[3])*scale;
        size_t ob = (((size_t)(bb*16+h))*1024 + (size_t)t)*64 + l16;
        dst[ob]    = f2b(v0);
        dst[ob+16] = f2b(v1);
        dst[ob+32] = f2b(v2);
        dst[ob+48] = f2b(v3);
      }
  }
}

// ---------------- output GEMM (global_load_lds staging): + bo, x gamma[t], f32 out ----------------
__global__ __launch_bounds__(256) void k_gemm_out(
    const u16* __restrict__ A, const u16* __restrict__ Bt,
    const float* __restrict__ bo, const float* __restrict__ gamma, float* __restrict__ out)
{
  __shared__ u16 As[128*32];
  __shared__ u16 Bs[128*32];
  const int n0 = blockIdx.x*128, m0 = blockIdx.y*128;
  const int tid = threadIdx.x, lane = tid&63, wave = tid>>6;
  const int quad = lane>>4, l16 = lane&15;
  const int wm = (wave>>1)*64, wn = (wave&1)*64;
  f32x4 zero = {0.f,0.f,0.f,0.f};
  f32x4 acc[4][4];
  #pragma unroll
  for (int i=0;i<4;i++)
    #pragma unroll
    for (int j=0;j<4;j++) acc[i][j] = zero;
  const int srow = (lane>>2), scol = (lane&3)*8;
  const u16* pa0 = A  + (size_t)(m0 + wave*16 + srow)*1024 + scol;
  const u16* pb0 = Bt + (size_t)(n0 + wave*16 + srow)*1024 + scol;
  u16* lA0 = &As[(wave*16)*32];
  u16* lA1 = &As[(64 + wave*16)*32];
  u16* lB0 = &Bs[(wave*16)*32];
  u16* lB1 = &Bs[(64 + wave*16)*32];
  for (int k0=0;k0<1024;k0+=32){
    __syncthreads();
    gld16(pa0 + k0,           lA0);
    gld16(pa0 + 64*1024 + k0, lA1);
    gld16(pb0 + k0,           lB0);
    gld16(pb0 + 64*1024 + k0, lB1);
    __syncthreads();
    bf16x8 af[4], bfr[4];
    #pragma unroll
    for (int mt=0;mt<4;mt++) af[mt]  = *(const bf16x8*)&As[(wm+mt*16+l16)*32 + quad*8];
    #pragma unroll
    for (int nt=0;nt<4;nt++) bfr[nt] = *(const bf16x8*)&Bs[(wn+nt*16+l16)*32 + quad*8];
    #pragma unroll
    for (int mt=0;mt<4;mt++)
      #pragma unroll
      for (int nt=0;nt<4;nt++)
        acc[mt][nt] = MFMA(af[mt], bfr[nt], acc[mt][nt]);
  }
  #pragma unroll
  for (int mt=0;mt<4;mt++)
    #pragma unroll
    for (int nt=0;nt<4;nt++){
      int colg = n0 + wn + nt*16 + l16;
      float bias = bo[colg];
      #pragma unroll
      for (int r=0;r<4;r++){
        int m = m0 + wm + mt*16 + quad*4 + r;
        int t = m&1023;
        float val = (acc[mt][nt][r] + bias)*gamma[t];
        out[(size_t)m*1024 + colg] = val;
      }
    }
}

// ---------------- fused softmax+weight: S in registers, stats in LDS, write P ----------------
// grid (tb=16, h=16, b=2); 1024 threads = 16 waves = 4 wt x 4 ws; full 64t x 1024s S tile in regs
// P layout: [b][t][h][s]
__global__ __launch_bounds__(1024) void k_sm(
    const u16* __restrict__ q, const u16* __restrict__ k,
    const float* __restrict__ tw, const float* __restrict__ alpha, const float* __restrict__ beta,
    u16* __restrict__ P)
{
  const int tb = blockIdx.x, h = blockIdx.y, b = blockIdx.z;
  const int t0b = tb*64;
  const int tid = threadIdx.x;
  const int wave = tid>>6, lane = tid&63, quad = lane>>4, l16 = lane&15;
  const int wt = wave>>2, ws = wave&3;

  __shared__ u16 qs[64*76];      // q tile, padded rows
  __shared__ u16 ks[256*76];     // K chunk, padded rows
  __shared__ float tws[1024];
  __shared__ float als[1024];
  __shared__ float pm[4][64];
  __shared__ float pl[4][64];
  __shared__ float fm[64];
  __shared__ float fr[64];

  const size_t bh = (size_t)(b*16+h)*65536;
  const u16* qp = q + bh;
  const u16* kp = k + bh;

  if (tid < 512){
    int row = tid>>3, g = tid&7;
    *(uint4*)&qs[row*76 + g*8] = *(const uint4*)(qp + (size_t)(t0b+row)*64 + g*8);
  }
  tws[tid] = tw[h*1024 + tid];
  als[tid] = alpha[h*1024 + tid];
  __syncthreads();

  bf16x8 qf0 = *(const bf16x8*)&qs[(wt*16+l16)*76 + quad*8];
  bf16x8 qf1 = *(const bf16x8*)&qs[(wt*16+l16)*76 + quad*8 + 32];

  f32x4 acc[16];
  #pragma unroll
  for (int i=0;i<16;i++){ acc[i][0]=0.f; acc[i][1]=0.f; acc[i][2]=0.f; acc[i][3]=0.f; }

  #pragma unroll
  for (int c=0;c<4;c++){
    if (c) __syncthreads();
    {
      int row = tid>>3, g = tid&7;
      *(uint4*)&ks[row*76 + g*8]       = *(const uint4*)(kp + (size_t)(c*256+row)*64 + g*8);
      *(uint4*)&ks[(row+128)*76 + g*8] = *(const uint4*)(kp + (size_t)(c*256+row+128)*64 + g*8);
    }
    __syncthreads();
    #pragma unroll
    for (int j=0;j<4;j++){
      int lt = j*4 + ws;
      bf16x8 kf0 = *(const bf16x8*)&ks[(lt*16+l16)*76 + quad*8];
      bf16x8 kf1 = *(const bf16x8*)&ks[(lt*16+l16)*76 + quad*8 + 32];
      acc[c*4+j] = MFMA(qf0, kf0, acc[c*4+j]);
      acc[c*4+j] = MFMA(qf1, kf1, acc[c*4+j]);
    }
  }

  // per-wave partial stats over its 256 s-columns
  float mrow[4], lrow[4];
  #pragma unroll
  for (int r=0;r<4;r++){
    float m = acc[0][r];
    #pragma unroll
    for (int a=1;a<16;a++) m = fmaxf(m, acc[a][r]);
    #pragma unroll
    for (int off=1; off<16; off<<=1) m = fmaxf(m, __shfl_xor(m, off));
    float l = 0.f;
    #pragma unroll
    for (int a=0;a<16;a++) l += __expf(acc[a][r]-m);
    #pragma unroll
    for (int off=1; off<16; off<<=1) l += __shfl_xor(l, off);
    mrow[r]=m; lrow[r]=l;
  }
  if (l16==0){
    #pragma unroll
    for (int r=0;r<4;r++){
      pm[ws][wt*16+quad*4+r] = mrow[r];
      pl[ws][wt*16+quad*4+r] = lrow[r];
    }
  }
  __syncthreads();
  if (tid < 64){
    float m0s = pm[0][tid], m1s = pm[1][tid], m2s = pm[2][tid], m3s = pm[3][tid];
    float m = fmaxf(fmaxf(m0s,m1s), fmaxf(m2s,m3s));
    float l = pl[0][tid]*__expf(m0s-m) + pl[1][tid]*__expf(m1s-m)
            + pl[2][tid]*__expf(m2s-m) + pl[3][tid]*__expf(m3s-m);
    fm[tid] = m;
    fr[tid] = beta[h*1024 + t0b + tid] / l;
  }
  __syncthreads();

  u16* Pp = P + (((size_t)b)<<24) + (((size_t)h)<<10);   // [b][t][h][s]
  float m_f[4], r_f[4]; int trow[4];
  #pragma unroll
  for (int r=0;r<4;r++){
    int rg = wt*16+quad*4+r;
    m_f[r] = fm[rg]; r_f[r] = fr[rg]; trow[r] = t0b + rg;
  }
  const int slim = tb*4 + wt;   // last s-tile with any s<=t
  #pragma unroll
  for (int c=0;c<4;c++)
    #pragma unroll
    for (int j=0;j<4;j++){
      int st = c*16 + j*4 + ws;
      if (st > slim) continue;
      int s = st*16 + l16;
      float av = als[s];
      #pragma unroll
      for (int r=0;r<4;r++){
        int t = trow[r];
        float p = 0.f;
        if (s <= t)
          p = __expf(acc[c*4+j][r]-m_f[r])*r_f[r]*tws[1023+s-t]*av;
        Pp[((size_t)t<<14) + s] = f2b(p);
      }
    }
}

// ---------------- head-mix: A[b][t][g][s] = sum_h Wmix[g][h] P[b][t][h][s] ----------------
// grid (1024 t, 2 b); 256 thr; per-t P slab staged by 256-col chunks into LDS
__global__ __launch_bounds__(256) void k_mix(const u16* __restrict__ P, const float* __restrict__ Wm,
                                             u16* __restrict__ Ab)
{
  const int t = blockIdx.x, b = blockIdx.y;
  const int tid = threadIdx.x;
  const int g = tid>>4, sg = tid&15;
  __shared__ u16 Ps[16*264];
  float w[16];
  #pragma unroll
  for (int h=0;h<16;h++) w[h] = Wm[g*16+h];
  const int tmaxr = t|15;             // P defined for s <= tmaxr
  const int ncw = (t>>8) + 1;         // write chunks cover k_pv's read range (s <= t|255)
  const size_t slab = (((size_t)b)<<24) + (((size_t)t)<<14);
  const u16* pp = P + slab;
  u16* ap = Ab + slab;
  for (int c=0;c<ncw;c++){
    int s0 = c*256;
    if (s0 <= tmaxr){
      if (c) __syncthreads();
      int colg = sg*16;
      uint4 z = {0u,0u,0u,0u};
      uint4 v0 = z, v1 = z;
      if (s0+colg <= tmaxr){
        v0 = *(const uint4*)(pp + ((size_t)g<<10) + s0+colg);
        v1 = *(const uint4*)(pp + ((size_t)g<<10) + s0+colg+8);
      }
      *(uint4*)&Ps[g*264+colg]   = v0;
      *(uint4*)&Ps[g*264+colg+8] = v1;
      __syncthreads();
      float acc[16];
      #pragma unroll
      for (int i=0;i<16;i++) acc[i]=0.f;
      #pragma unroll
      for (int h=0;h<16;h++){
        float wh = w[h];
        #pragma unroll
        for (int j=0;j<4;j++){
          ushort4 u = *(const ushort4*)&Ps[h*264 + sg*16 + j*4];
          acc[j*4+0] += wh*b2f(u.x);
          acc[j*4+1] += wh*b2f(u.y);
          acc[j*4+2] += wh*b2f(u.z);
          acc[j*4+3] += wh*b2f(u.w);
        }
      }
      u16 o[16];
      #pragma unroll
      for (int i=0;i<16;i++) o[i] = f2b(acc[i]);
      *(uint4*)(ap + ((size_t)g<<10) + s0 + sg*16)     = *(uint4*)&o[0];
      *(uint4*)(ap + ((size_t)g<<10) + s0 + sg*16 + 8) = *(uint4*)&o[8];
    } else {
      uint4 z = {0u,0u,0u,0u};
      *(uint4*)(ap + ((size_t)g<<10) + s0 + sg*16)     = z;
      *(uint4*)(ap + ((size_t)g<<10) + s0 + sg*16 + 8) = z;
    }
  }
}

// ---------------- PV: grid (tb=16, bg=32); 16 waves = 4 wt x 4 wd; LDS-staged s-chunks ----------------
__global__ __launch_bounds__(1024) void k_pv(const u16* __restrict__ Ab, const u16* __restrict__ vT,
                                             u16* __restrict__ y)
{
  const int tb = blockIdx.x;          // 0..15
  const int bg = blockIdx.y;          // 0..31 = b*16+g
  const int b = bg>>4, g = bg&15;
  const int t0b = tb*64;
  const int tid = threadIdx.x;
  const int wave = tid>>6, lane = tid&63, quad = lane>>4, l16 = lane&15;
  const int wt = wave>>2, wd = wave&3;
  __shared__ u16 As[64*264];
  __shared__ u16 Vs[64*264];
  const u16* ap = Ab + (((size_t)b)<<24) + ((size_t)g<<10);   // [b][t][g][s]
  const u16* vp = vT + (size_t)bg*65536;   // [d][t]
  f32x4 acc = {0.f,0.f,0.f,0.f};
  const int nc = tb/4 + 1;            // causal: only chunks with s0 <= t|63
  const int row = tid>>4, col = (tid&15)*16;
  for (int c=0;c<nc;c++){
    if (c) __syncthreads();
    int s0 = c*256;
    *(uint4*)&As[row*264+col]   = *(const uint4*)(ap + ((size_t)(t0b+row)<<14) + s0+col);
    *(uint4*)&As[row*264+col+8] = *(const uint4*)(ap + ((size_t)(t0b+row)<<14) + s0+col+8);
    *(uint4*)&Vs[row*264+col]   = *(const uint4*)(vp + (size_t)row*1024 + s0+col);
    *(uint4*)&Vs[row*264+col+8] = *(const uint4*)(vp + (size_t)row*1024 + s0+col+8);
    __syncthreads();
    #pragma unroll
    for (int ks=0;ks<8;ks++){
      bf16x8 af  = *(const bf16x8*)&As[(wt*16+l16)*264 + ks*32 + quad*8];
      bf16x8 bfv = *(const bf16x8*)&Vs[(wd*16+l16)*264 + ks*32 + quad*8];
      acc = MFMA(af, bfv, acc);
    }
  }
  #pragma unroll
  for (int r=0;r<4;r++){
    int t = t0b + wt*16 + quad*4 + r;
    y[(size_t)(b*1024+t)*1024 + g*64 + wd*16 + l16] = f2b(acc[r]);
  }
}

__global__ void k_fail(float* out){ if (threadIdx.x==0) out[0] = 1e30f; } // ws-too-small marker

extern "C" void kernel_launch(void* const* d_in, const int* in_sizes, int n_in,
                              void* d_out, int out_size, void* d_ws, size_t ws_size,
                              hipStream_t stream)
{
  const float* x     = (const float*)d_in[0];
  const float* tw    = (const float*)d_in[1];
  const float* alpha = (const float*)d_in[2];
  const float* beta  = (const float*)d_in[3];
  const float* gamma = (const float*)d_in[4];
  const float* Wq    = (const float*)d_in[5];
  const float* bq    = (const float*)d_in[6];
  const float* Wk    = (const float*)d_in[7];
  const float* bk    = (const float*)d_in[8];
  const float* Wv    = (const float*)d_in[9];
  const float* bv    = (const float*)d_in[10];
  const float* Wmix  = (const float*)d_in[11];
  const float* Wo    = (const float*)d_in[12];
  const float* bo    = (const float*)d_in[13];
  float* out = (float*)d_out;

  char* ws = (char*)d_ws;
  size_t off = 0;
  auto take = [&](size_t bytes)->char*{
    char* p = ws + off; off += (bytes + 255) & ~(size_t)255; return p;
  };
  u16*   xs  = (u16*)take((size_t)2097152*2);   // xs (B*T, C) bf16
  u16*   WT  = (u16*)take((size_t)3145728*2);   // [3072][1024] = Wq^T|Wk^T|Wv^T bf16
  u16*   WoT = (u16*)take((size_t)1048576*2);
  u16*   qb  = (u16*)take((size_t)2097152*2);   // (b,h,t,d) rope'd, x1/8
  u16*   kb  = (u16*)take((size_t)2097152*2);   // (b,h,t,d) rope'd
  u16*   vTb = (u16*)take((size_t)2097152*2);   // (b,h,d,t)
  u16*   yb  = (u16*)take((size_t)2097152*2);   // (b,t,g,d)
  u16*   P   = (u16*)take((size_t)33554432*2);  // [b][t][h][s]
  u16*   A   = (u16*)take((size_t)33554432*2);  // [b][t][g][s]
  if (off > ws_size){
    hipLaunchKernelGGL(k_fail, dim3(1), dim3(64), 0, stream, out);
    return;
  }

  hipLaunchKernelGGL(k_pre, dim3(2048), dim3(256), 0, stream,
                     x, Wq, Wk, Wv, Wo, xs, WT, WoT);
  hipLaunchKernelGGL(k_gemm_qkv, dim3(24,16), dim3(256), 0, stream,
                     xs, WT, bq, bk, bv, qb, kb, vTb);
  hipLaunchKernelGGL(k_sm, dim3(16,16,2), dim3(1024), 0, stream,
                     qb, kb, tw, alpha, beta, P);
  hipLaunchKernelGGL(k_mix, dim3(1024,2), dim3(256), 0, stream, P, Wmix, A);
  hipLaunchKernelGGL(k_pv, dim3(16,32), dim3(1024), 0, stream, A, vTb, yb);
  hipLaunchKernelGGL(k_gemm_out, dim3(8,16), dim3(256), 0, stream, yb, WoT, bo, gamma, out);
}

// Round 9
// 211.672 us; speedup vs baseline: 2.0778x; 1.0326x over previous
//
#include <hip/hip_runtime.h>

typedef unsigned short u16;
typedef unsigned int u32;
typedef __attribute__((ext_vector_type(8))) short bf16x8;
typedef __attribute__((ext_vector_type(4))) float f32x4;

#define MFMA(a,b,c) __builtin_amdgcn_mfma_f32_16x16x32_bf16(a,b,c,0,0,0)

__device__ __forceinline__ float b2f(u16 u){
  union { unsigned int i; float f; } v; v.i = ((unsigned int)u)<<16; return v.f;
}
__device__ __forceinline__ u16 f2b(float f){
  union { float f; unsigned int i; } v; v.f = f;
  unsigned int r = (v.i + 0x7FFFu + ((v.i>>16)&1u))>>16;
  return (u16)r;
}
// async global->LDS, 16B per lane; lds dest must be wave-uniform base (HW adds lane*16)
__device__ __forceinline__ void gld16(const u16* g, u16* l){
  __builtin_amdgcn_global_load_lds((const __attribute__((address_space(1))) u32*)g,
                                   (__attribute__((address_space(3))) u32*)l, 16, 0, 0);
}

// ---------------- combined: time-shift prep (blocks 0..1023) + 4 weight transposes ----------------
__global__ __launch_bounds__(256) void k_pre(
    const float* __restrict__ x,
    const float* __restrict__ Wq, const float* __restrict__ Wk,
    const float* __restrict__ Wv, const float* __restrict__ Wo,
    u16* __restrict__ xs, u16* __restrict__ WT, u16* __restrict__ WoT)
{
  int bid = blockIdx.x;
  int tid = threadIdx.x;
  if (bid < 1024){
    int idx = bid*256 + tid;                 // one thread per 8 elements
    size_t e = (size_t)idx*8;
    int c = (int)(e & 1023);
    int t = (int)((e>>10)&1023);
    float4 f0 = {0.f,0.f,0.f,0.f}, f1 = {0.f,0.f,0.f,0.f};
    const float* src = nullptr;
    if (c < 512){ if (t > 0) src = x + e - 1024; }
    else        { src = x + e; }
    if (src){ f0 = *(const float4*)src; f1 = *(const float4*)(src+4); }
    u16 o[8];
    o[0]=f2b(f0.x); o[1]=f2b(f0.y); o[2]=f2b(f0.z); o[3]=f2b(f0.w);
    o[4]=f2b(f1.x); o[5]=f2b(f1.y); o[6]=f2b(f1.z); o[7]=f2b(f1.w);
    *(uint4*)(xs + e) = *(const uint4*)o;
    return;
  }
  int z  = (bid-1024)>>8;                    // 0..3 : Wq,Wk,Wv,Wo
  int rc = (bid-1024)&255;
  const float* src = (z==0)?Wq:((z==1)?Wk:((z==2)?Wv:Wo));
  u16* dst = (z==3)? WoT : (WT + (size_t)z*1048576);
  int c0 = (rc&15)*64, r0 = (rc>>4)*64;
  __shared__ u16 tile[64][72];
  int r = tid>>2, cc = (tid&3)*16;
  const float* sp = src + (size_t)(r0+r)*1024 + c0+cc;
  float4 a0 = *(const float4*)(sp);
  float4 a1 = *(const float4*)(sp+4);
  float4 a2 = *(const float4*)(sp+8);
  float4 a3 = *(const float4*)(sp+12);
  tile[r][cc+0]=f2b(a0.x); tile[r][cc+1]=f2b(a0.y); tile[r][cc+2]=f2b(a0.z); tile[r][cc+3]=f2b(a0.w);
  tile[r][cc+4]=f2b(a1.x); tile[r][cc+5]=f2b(a1.y); tile[r][cc+6]=f2b(a1.z); tile[r][cc+7]=f2b(a1.w);
  tile[r][cc+8]=f2b(a2.x); tile[r][cc+9]=f2b(a2.y); tile[r][cc+10]=f2b(a2.z); tile[r][cc+11]=f2b(a2.w);
  tile[r][cc+12]=f2b(a3.x); tile[r][cc+13]=f2b(a3.y); tile[r][cc+14]=f2b(a3.z); tile[r][cc+15]=f2b(a3.w);
  __syncthreads();
  int c = tid>>2, rr = (tid&3)*16;
  uint4 o0,o1; u16* p0=(u16*)&o0; u16* p1=(u16*)&o1;
  #pragma unroll
  for (int i=0;i<8;i++){ p0[i]=tile[rr+i][c]; p1[i]=tile[rr+8+i][c]; }
  *(uint4*)(dst + (size_t)(c0+c)*1024 + r0+rr)   = o0;
  *(uint4*)(dst + (size_t)(c0+c)*1024 + r0+rr+8) = o1;
}

// ---------------- QKV GEMM 128x64 tiles (global_load_lds) + fused RoPE; v -> (b,h,d,t) ----------------
// grid (48, 16): n0=bx*64 (64-aligned => which,h uniform per block)
__global__ __launch_bounds__(256) void k_gemm_qkv(
    const u16* __restrict__ A, const u16* __restrict__ Bt,
    const float* __restrict__ bq, const float* __restrict__ bk, const float* __restrict__ bv,
    u16* __restrict__ qb, u16* __restrict__ kb, u16* __restrict__ vT)
{
  __shared__ u16 As[128*32];     // unpadded: required by global_load_lds lane order
  __shared__ u16 Bs[64*32];
  const int n0 = blockIdx.x*64, m0 = blockIdx.y*128;
  const int tid = threadIdx.x, lane = tid&63, wave = tid>>6;
  const int quad = lane>>4, l16 = lane&15;
  const int wm = (wave>>1)*64, wn = (wave&1)*32;
  f32x4 zero = {0.f,0.f,0.f,0.f};
  f32x4 acc[4][2];
  #pragma unroll
  for (int i=0;i<4;i++){ acc[i][0]=zero; acc[i][1]=zero; }
  const int srow = (lane>>2), scol = (lane&3)*8;
  const u16* pa0 = A  + (size_t)(m0 + wave*16 + srow)*1024 + scol;
  const u16* pb0 = Bt + (size_t)(n0 + wave*16 + srow)*1024 + scol;
  u16* lA0 = &As[(wave*16)*32];
  u16* lA1 = &As[(64 + wave*16)*32];
  u16* lB0 = &Bs[(wave*16)*32];
  for (int k0=0;k0<1024;k0+=32){
    __syncthreads();
    gld16(pa0 + k0,           lA0);
    gld16(pa0 + 64*1024 + k0, lA1);
    gld16(pb0 + k0,           lB0);
    __syncthreads();
    bf16x8 af[4], bfr[2];
    #pragma unroll
    for (int mt=0;mt<4;mt++) af[mt]  = *(const bf16x8*)&As[(wm+mt*16+l16)*32 + quad*8];
    #pragma unroll
    for (int nt=0;nt<2;nt++) bfr[nt] = *(const bf16x8*)&Bs[(wn+nt*16+l16)*32 + quad*8];
    #pragma unroll
    for (int mt=0;mt<4;mt++){
      acc[mt][0] = MFMA(af[mt], bfr[0], acc[mt][0]);
      acc[mt][1] = MFMA(af[mt], bfr[1], acc[mt][1]);
    }
  }
  const int which = n0>>10;            // uniform per block
  const int nn0 = (n0 & 1023) + wn;
  const int h = (n0 & 1023)>>6;
  const float* barr = (which==0)?bq:((which==1)?bk:bv);
  float bias0 = barr[nn0 + l16];
  float bias1 = barr[nn0 + 16 + l16];
  if (which == 2){
    // v: write transposed (b,h,d,t): vT[bh*65536 + d*1024 + t]
    #pragma unroll
    for (int mt=0;mt<4;mt++)
      #pragma unroll
      for (int r=0;r<4;r++){
        int m = m0 + wm + mt*16 + quad*4 + r;
        int bb = m>>10, t = m&1023;
        size_t base = (size_t)(bb*16+h)*65536 + t;
        int d0 = wn + l16;
        vT[base + (size_t)d0*1024]      = f2b(acc[mt][0][r] + bias0);
        vT[base + (size_t)(d0+16)*1024] = f2b(acc[mt][1][r] + bias1);
      }
  } else {
    const float scale = (which==0)?0.125f:1.0f;
    u16* dst = (which==0)? qb : kb;
    if (wn == 0){
      const float e = exp2f(-0.625f*(float)l16);
      #pragma unroll
      for (int mt=0;mt<4;mt++)
        #pragma unroll
        for (int r=0;r<4;r++){
          int m = m0 + wm + mt*16 + quad*4 + r;
          int bb = m>>10, t = m&1023;
          float f = (float)t * e;
          float cs = cosf(f), sn = sinf(f);
          float x0 = acc[mt][0][r] + bias0;
          float x1 = acc[mt][1][r] + bias1;
          float v0 = (x0*cs - x1*sn)*scale;
          float v1 = (x1*cs + x0*sn)*scale;
          size_t ob = (((size_t)(bb*16+h))*1024 + (size_t)t)*64 + l16;
          dst[ob]    = f2b(v0);
          dst[ob+16] = f2b(v1);
        }
    } else {
      #pragma unroll
      for (int mt=0;mt<4;mt++)
        #pragma unroll
        for (int r=0;r<4;r++){
          int m = m0 + wm + mt*16 + quad*4 + r;
          int bb = m>>10, t = m&1023;
          float v2 = (acc[mt][0][r] + bias0)*scale;
          float v3 = (acc[mt][1][r] + bias1)*scale;
          size_t ob = (((size_t)(bb*16+h))*1024 + (size_t)t)*64 + 32 + l16;
          dst[ob]    = f2b(v2);
          dst[ob+16] = f2b(v3);
        }
    }
  }
}

// ---------------- output GEMM 128x64 tiles: + bo, x gamma[t], f32 out ----------------
// grid (16, 16) = 256 blocks
__global__ __launch_bounds__(256) void k_gemm_out(
    const u16* __restrict__ A, const u16* __restrict__ Bt,
    const float* __restrict__ bo, const float* __restrict__ gamma, float* __restrict__ out)
{
  __shared__ u16 As[128*32];
  __shared__ u16 Bs[64*32];
  const int n0 = blockIdx.x*64, m0 = blockIdx.y*128;
  const int tid = threadIdx.x, lane = tid&63, wave = tid>>6;
  const int quad = lane>>4, l16 = lane&15;
  const int wm = (wave>>1)*64, wn = (wave&1)*32;
  f32x4 zero = {0.f,0.f,0.f,0.f};
  f32x4 acc[4][2];
  #pragma unroll
  for (int i=0;i<4;i++){ acc[i][0]=zero; acc[i][1]=zero; }
  const int srow = (lane>>2), scol = (lane&3)*8;
  const u16* pa0 = A  + (size_t)(m0 + wave*16 + srow)*1024 + scol;
  const u16* pb0 = Bt + (size_t)(n0 + wave*16 + srow)*1024 + scol;
  u16* lA0 = &As[(wave*16)*32];
  u16* lA1 = &As[(64 + wave*16)*32];
  u16* lB0 = &Bs[(wave*16)*32];
  for (int k0=0;k0<1024;k0+=32){
    __syncthreads();
    gld16(pa0 + k0,           lA0);
    gld16(pa0 + 64*1024 + k0, lA1);
    gld16(pb0 + k0,           lB0);
    __syncthreads();
    bf16x8 af[4], bfr[2];
    #pragma unroll
    for (int mt=0;mt<4;mt++) af[mt]  = *(const bf16x8*)&As[(wm+mt*16+l16)*32 + quad*8];
    #pragma unroll
    for (int nt=0;nt<2;nt++) bfr[nt] = *(const bf16x8*)&Bs[(wn+nt*16+l16)*32 + quad*8];
    #pragma unroll
    for (int mt=0;mt<4;mt++){
      acc[mt][0] = MFMA(af[mt], bfr[0], acc[mt][0]);
      acc[mt][1] = MFMA(af[mt], bfr[1], acc[mt][1]);
    }
  }
  #pragma unroll
  for (int nt=0;nt<2;nt++){
    int colg = n0 + wn + nt*16 + l16;
    float bias = bo[colg];
    #pragma unroll
    for (int mt=0;mt<4;mt++)
      #pragma unroll
      for (int r=0;r<4;r++){
        int m = m0 + wm + mt*16 + quad*4 + r;
        int t = m&1023;
        float val = (acc[mt][nt][r] + bias)*gamma[t];
        out[(size_t)m*1024 + colg] = val;
      }
  }
}

// ---------------- fused softmax+weight: S in registers, stats in LDS, write P ----------------
// grid (tb=16, h=16, b=2); 1024 threads = 16 waves = 4 wt x 4 ws; full 64t x 1024s S tile in regs
// P layout: [b][t][h][s]
__global__ __launch_bounds__(1024) void k_sm(
    const u16* __restrict__ q, const u16* __restrict__ k,
    const float* __restrict__ tw, const float* __restrict__ alpha, const float* __restrict__ beta,
    u16* __restrict__ P)
{
  const int tb = blockIdx.x, h = blockIdx.y, b = blockIdx.z;
  const int t0b = tb*64;
  const int tid = threadIdx.x;
  const int wave = tid>>6, lane = tid&63, quad = lane>>4, l16 = lane&15;
  const int wt = wave>>2, ws = wave&3;

  __shared__ u16 qs[64*76];      // q tile, padded rows
  __shared__ u16 ks[256*76];     // K chunk, padded rows
  __shared__ float tws[1024];
  __shared__ float als[1024];
  __shared__ float pm[4][64];
  __shared__ float pl[4][64];
  __shared__ float fm[64];
  __shared__ float fr[64];

  const size_t bh = (size_t)(b*16+h)*65536;
  const u16* qp = q + bh;
  const u16* kp = k + bh;

  if (tid < 512){
    int row = tid>>3, g = tid&7;
    *(uint4*)&qs[row*76 + g*8] = *(const uint4*)(qp + (size_t)(t0b+row)*64 + g*8);
  }
  tws[tid] = tw[h*1024 + tid];
  als[tid] = alpha[h*1024 + tid];
  __syncthreads();

  bf16x8 qf0 = *(const bf16x8*)&qs[(wt*16+l16)*76 + quad*8];
  bf16x8 qf1 = *(const bf16x8*)&qs[(wt*16+l16)*76 + quad*8 + 32];

  f32x4 acc[16];
  #pragma unroll
  for (int i=0;i<16;i++){ acc[i][0]=0.f; acc[i][1]=0.f; acc[i][2]=0.f; acc[i][3]=0.f; }

  #pragma unroll
  for (int c=0;c<4;c++){
    if (c) __syncthreads();
    {
      int row = tid>>3, g = tid&7;
      *(uint4*)&ks[row*76 + g*8]       = *(const uint4*)(kp + (size_t)(c*256+row)*64 + g*8);
      *(uint4*)&ks[(row+128)*76 + g*8] = *(const uint4*)(kp + (size_t)(c*256+row+128)*64 + g*8);
    }
    __syncthreads();
    #pragma unroll
    for (int j=0;j<4;j++){
      int lt = j*4 + ws;
      bf16x8 kf0 = *(const bf16x8*)&ks[(lt*16+l16)*76 + quad*8];
      bf16x8 kf1 = *(const bf16x8*)&ks[(lt*16+l16)*76 + quad*8 + 32];
      acc[c*4+j] = MFMA(qf0, kf0, acc[c*4+j]);
      acc[c*4+j] = MFMA(qf1, kf1, acc[c*4+j]);
    }
  }

  // per-wave partial stats over its 256 s-columns
  float mrow[4], lrow[4];
  #pragma unroll
  for (int r=0;r<4;r++){
    float m = acc[0][r];
    #pragma unroll
    for (int a=1;a<16;a++) m = fmaxf(m, acc[a][r]);
    #pragma unroll
    for (int off=1; off<16; off<<=1) m = fmaxf(m, __shfl_xor(m, off));
    float l = 0.f;
    #pragma unroll
    for (int a=0;a<16;a++) l += __expf(acc[a][r]-m);
    #pragma unroll
    for (int off=1; off<16; off<<=1) l += __shfl_xor(l, off);
    mrow[r]=m; lrow[r]=l;
  }
  if (l16==0){
    #pragma unroll
    for (int r=0;r<4;r++){
      pm[ws][wt*16+quad*4+r] = mrow[r];
      pl[ws][wt*16+quad*4+r] = lrow[r];
    }
  }
  __syncthreads();
  if (tid < 64){
    float m0s = pm[0][tid], m1s = pm[1][tid], m2s = pm[2][tid], m3s = pm[3][tid];
    float m = fmaxf(fmaxf(m0s,m1s), fmaxf(m2s,m3s));
    float l = pl[0][tid]*__expf(m0s-m) + pl[1][tid]*__expf(m1s-m)
            + pl[2][tid]*__expf(m2s-m) + pl[3][tid]*__expf(m3s-m);
    fm[tid] = m;
    fr[tid] = beta[h*1024 + t0b + tid] / l;
  }
  __syncthreads();

  u16* Pp = P + (((size_t)b)<<24) + (((size_t)h)<<10);   // [b][t][h][s]
  float m_f[4], r_f[4]; int trow[4];
  #pragma unroll
  for (int r=0;r<4;r++){
    int rg = wt*16+quad*4+r;
    m_f[r] = fm[rg]; r_f[r] = fr[rg]; trow[r] = t0b + rg;
  }
  const int slim = tb*4 + wt;   // last s-tile with any s<=t
  #pragma unroll
  for (int c=0;c<4;c++)
    #pragma unroll
    for (int j=0;j<4;j++){
      int st = c*16 + j*4 + ws;
      if (st > slim) continue;
      int s = st*16 + l16;
      float av = als[s];
      #pragma unroll
      for (int r=0;r<4;r++){
        int t = trow[r];
        float p = 0.f;
        if (s <= t)
          p = __expf(acc[c*4+j][r]-m_f[r])*r_f[r]*tws[1023+s-t]*av;
        Pp[((size_t)t<<14) + s] = f2b(p);
      }
    }
}

// ---------------- head-mix: A[b][t][g][s] = sum_h Wmix[g][h] P[b][t][h][s] ----------------
// grid (1024 t, 2 b); 256 thr; per-t P slab staged by 256-col chunks into LDS
__global__ __launch_bounds__(256) void k_mix(const u16* __restrict__ P, const float* __restrict__ Wm,
                                             u16* __restrict__ Ab)
{
  const int t = blockIdx.x, b = blockIdx.y;
  const int tid = threadIdx.x;
  const int g = tid>>4, sg = tid&15;
  __shared__ u16 Ps[16*264];
  float w[16];
  #pragma unroll
  for (int h=0;h<16;h++) w[h] = Wm[g*16+h];
  const int tmaxr = t|15;             // P defined for s <= tmaxr
  const int ncw = (t>>8) + 1;         // write chunks cover k_pv's read range (s <= t|255)
  const size_t slab = (((size_t)b)<<24) + (((size_t)t)<<14);
  const u16* pp = P + slab;
  u16* ap = Ab + slab;
  for (int c=0;c<ncw;c++){
    int s0 = c*256;
    if (s0 <= tmaxr){
      if (c) __syncthreads();
      int colg = sg*16;
      uint4 z = {0u,0u,0u,0u};
      uint4 v0 = z, v1 = z;
      if (s0+colg <= tmaxr){
        v0 = *(const uint4*)(pp + ((size_t)g<<10) + s0+colg);
        v1 = *(const uint4*)(pp + ((size_t)g<<10) + s0+colg+8);
      }
      *(uint4*)&Ps[g*264+colg]   = v0;
      *(uint4*)&Ps[g*264+colg+8] = v1;
      __syncthreads();
      float acc[16];
      #pragma unroll
      for (int i=0;i<16;i++) acc[i]=0.f;
      #pragma unroll
      for (int h=0;h<16;h++){
        float wh = w[h];
        #pragma unroll
        for (int j=0;j<4;j++){
          ushort4 u = *(const ushort4*)&Ps[h*264 + sg*16 + j*4];
          acc[j*4+0] += wh*b2f(u.x);
          acc[j*4+1] += wh*b2f(u.y);
          acc[j*4+2] += wh*b2f(u.z);
          acc[j*4+3] += wh*b2f(u.w);
        }
      }
      u16 o[16];
      #pragma unroll
      for (int i=0;i<16;i++) o[i] = f2b(acc[i]);
      *(uint4*)(ap + ((size_t)g<<10) + s0 + sg*16)     = *(uint4*)&o[0];
      *(uint4*)(ap + ((size_t)g<<10) + s0 + sg*16 + 8) = *(uint4*)&o[8];
    } else {
      uint4 z = {0u,0u,0u,0u};
      *(uint4*)(ap + ((size_t)g<<10) + s0 + sg*16)     = z;
      *(uint4*)(ap + ((size_t)g<<10) + s0 + sg*16 + 8) = z;
    }
  }
}

// ---------------- PV: grid (tb=16, bg=32); 16 waves = 4 wt x 4 wd; LDS-staged s-chunks ----------------
__global__ __launch_bounds__(1024) void k_pv(const u16* __restrict__ Ab, const u16* __restrict__ vT,
                                             u16* __restrict__ y)
{
  const int tb = blockIdx.x;          // 0..15
  const int bg = blockIdx.y;          // 0..31 = b*16+g
  const int b = bg>>4, g = bg&15;
  const int t0b = tb*64;
  const int tid = threadIdx.x;
  const int wave = tid>>6, lane = tid&63, quad = lane>>4, l16 = lane&15;
  const int wt = wave>>2, wd = wave&3;
  __shared__ u16 As[64*264];
  __shared__ u16 Vs[64*264];
  const u16* ap = Ab + (((size_t)b)<<24) + ((size_t)g<<10);   // [b][t][g][s]
  const u16* vp = vT + (size_t)bg*65536;   // [d][t]
  f32x4 acc = {0.f,0.f,0.f,0.f};
  const int nc = tb/4 + 1;            // causal: only chunks with s0 <= t|63
  const int row = tid>>4, col = (tid&15)*16;
  for (int c=0;c<nc;c++){
    if (c) __syncthreads();
    int s0 = c*256;
    *(uint4*)&As[row*264+col]   = *(const uint4*)(ap + ((size_t)(t0b+row)<<14) + s0+col);
    *(uint4*)&As[row*264+col+8] = *(const uint4*)(ap + ((size_t)(t0b+row)<<14) + s0+col+8);
    *(uint4*)&Vs[row*264+col]   = *(const uint4*)(vp + (size_t)row*1024 + s0+col);
    *(uint4*)&Vs[row*264+col+8] = *(const uint4*)(vp + (size_t)row*1024 + s0+col+8);
    __syncthreads();
    #pragma unroll
    for (int ks=0;ks<8;ks++){
      bf16x8 af  = *(const bf16x8*)&As[(wt*16+l16)*264 + ks*32 + quad*8];
      bf16x8 bfv = *(const bf16x8*)&Vs[(wd*16+l16)*264 + ks*32 + quad*8];
      acc = MFMA(af, bfv, acc);
    }
  }
  #pragma unroll
  for (int r=0;r<4;r++){
    int t = t0b + wt*16 + quad*4 + r;
    y[(size_t)(b*1024+t)*1024 + g*64 + wd*16 + l16] = f2b(acc[r]);
  }
}

__global__ void k_fail(float* out){ if (threadIdx.x==0) out[0] = 1e30f; } // ws-too-small marker

extern "C" void kernel_launch(void* const* d_in, const int* in_sizes, int n_in,
                              void* d_out, int out_size, void* d_ws, size_t ws_size,
                              hipStream_t stream)
{
  const float* x     = (const float*)d_in[0];
  const float* tw    = (const float*)d_in[1];
  const float* alpha = (const float*)d_in[2];
  const float* beta  = (const float*)d_in[3];
  const float* gamma = (const float*)d_in[4];
  const float* Wq    = (const float*)d_in[5];
  const float* bq    = (const float*)d_in[6];
  const float* Wk    = (const float*)d_in[7];
  const float* bk    = (const float*)d_in[8];
  const float* Wv    = (const float*)d_in[9];
  const float* bv    = (const float*)d_in[10];
  const float* Wmix  = (const float*)d_in[11];
  const float* Wo    = (const float*)d_in[12];
  const float* bo    = (const float*)d_in[13];
  float* out = (float*)d_out;

  char* ws = (char*)d_ws;
  size_t off = 0;
  auto take = [&](size_t bytes)->char*{
    char* p = ws + off; off += (bytes + 255) & ~(size_t)255; return p;
  };
  u16*   xs  = (u16*)take((size_t)2097152*2);   // xs (B*T, C) bf16
  u16*   WT  = (u16*)take((size_t)3145728*2);   // [3072][1024] = Wq^T|Wk^T|Wv^T bf16
  u16*   WoT = (u16*)take((size_t)1048576*2);
  u16*   qb  = (u16*)take((size_t)2097152*2);   // (b,h,t,d) rope'd, x1/8
  u16*   kb  = (u16*)take((size_t)2097152*2);   // (b,h,t,d) rope'd
  u16*   vTb = (u16*)take((size_t)2097152*2);   // (b,h,d,t)
  u16*   yb  = (u16*)take((size_t)2097152*2);   // (b,t,g,d)
  u16*   P   = (u16*)take((size_t)33554432*2);  // [b][t][h][s]
  u16*   A   = (u16*)take((size_t)33554432*2);  // [b][t][g][s]
  if (off > ws_size){
    hipLaunchKernelGGL(k_fail, dim3(1), dim3(64), 0, stream, out);
    return;
  }

  hipLaunchKernelGGL(k_pre, dim3(2048), dim3(256), 0, stream,
                     x, Wq, Wk, Wv, Wo, xs, WT, WoT);
  hipLaunchKernelGGL(k_gemm_qkv, dim3(48,16), dim3(256), 0, stream,
                     xs, WT, bq, bk, bv, qb, kb, vTb);
  hipLaunchKernelGGL(k_sm, dim3(16,16,2), dim3(1024), 0, stream,
                     qb, kb, tw, alpha, beta, P);
  hipLaunchKernelGGL(k_mix, dim3(1024,2), dim3(256), 0, stream, P, Wmix, A);
  hipLaunchKernelGGL(k_pv, dim3(16,32), dim3(1024), 0, stream, A, vTb, yb);
  hipLaunchKernelGGL(k_gemm_out, dim3(16,16), dim3(256), 0, stream, yb, WoT, bo, gamma, out);
}